// Round 1
// baseline (3108.628 us; speedup 1.0000x reference)
//
#include <hip/hip_runtime.h>

#define N_NODES_C 50000
#define N_EDGES_C 800000
#define E_TOT (N_EDGES_C + N_NODES_C)
#define NUM_GRAPHS_C 1000
#define EPS_C 1e-5f

// ---------- helpers ----------
static __device__ __forceinline__ unsigned enc_f32(float f) {
  unsigned u = __float_as_uint(f);
  return (u & 0x80000000u) ? ~u : (u | 0x80000000u);
}
static __device__ __forceinline__ float dec_f32(unsigned u) {
  return (u & 0x80000000u) ? __uint_as_float(u ^ 0x80000000u) : __uint_as_float(~u);
}
static __device__ __forceinline__ void edge_sd(const int* __restrict__ ei, int i, int& s, int& d) {
  if (i < N_EDGES_C) { s = ei[i]; d = ei[N_EDGES_C + i]; }
  else { s = d = i - N_EDGES_C; }
}
static __device__ __forceinline__ float lrelu(float v, float slope) {
  return v >= 0.f ? v : slope * v;
}

// ---------- node GEMM: h = x @ W ----------
template<int CIN, int COUT>
__global__ void gemm_node(const float* __restrict__ x, const float* __restrict__ W,
                          float* __restrict__ h, int n_nodes) {
  constexpr int NPB = 256 / COUT;  // nodes per block
  __shared__ float sW[CIN * COUT];
  __shared__ float sx[NPB * CIN];
  for (int i = threadIdx.x; i < CIN * COUT; i += 256) sW[i] = W[i];
  int node0 = blockIdx.x * NPB;
  for (int i = threadIdx.x; i < NPB * CIN; i += 256) {
    int n = node0 + i / CIN;
    sx[i] = (n < n_nodes) ? x[(size_t)n * CIN + (i % CIN)] : 0.f;
  }
  __syncthreads();
  int oc = threadIdx.x % COUT;
  int ln = threadIdx.x / COUT;
  int n = node0 + ln;
  if (n >= n_nodes) return;
  float acc = 0.f;
#pragma unroll
  for (int k = 0; k < CIN; ++k) acc += sx[ln * CIN + k] * sW[k * COUT + oc];
  h[(size_t)n * COUT + oc] = acc;
}

// ---------- per-node attention logits: es = h.as, ed = h.ad ----------
template<int C>
__global__ void attn_logits(const float* __restrict__ h, const float* __restrict__ a_s,
                            const float* __restrict__ a_d, float* __restrict__ es,
                            float* __restrict__ ed, int n_nodes) {
  int wave = (blockIdx.x * blockDim.x + threadIdx.x) >> 6;
  int lane = threadIdx.x & 63;
  if (wave >= n_nodes) return;
  float s1 = 0.f, s2 = 0.f;
  for (int c = lane; c < C; c += 64) {
    float v = h[(size_t)wave * C + c];
    s1 += v * a_s[c];
    s2 += v * a_d[c];
  }
#pragma unroll
  for (int off = 32; off; off >>= 1) {
    s1 += __shfl_down(s1, off, 64);
    s2 += __shfl_down(s2, off, 64);
  }
  if (lane == 0) { es[wave] = s1; ed[wave] = s2; }
}

// ---------- edge pass A: logits + segment max ----------
__global__ void edge_logits(const int* __restrict__ ei, const float* __restrict__ es,
                            const float* __restrict__ ed, float* __restrict__ e_buf,
                            unsigned* __restrict__ emax) {
  int i = blockIdx.x * 256 + threadIdx.x;
  if (i >= E_TOT) return;
  int s, d; edge_sd(ei, i, s, d);
  float v = lrelu(es[s] + ed[d], 0.2f);
  e_buf[i] = v;
  atomicMax(&emax[d], enc_f32(v));
}

// ---------- edge pass B: exp + segment sum ----------
__global__ void edge_exp(const int* __restrict__ ei, float* __restrict__ e_buf,
                         const unsigned* __restrict__ emax, float* __restrict__ denom) {
  int i = blockIdx.x * 256 + threadIdx.x;
  if (i >= E_TOT) return;
  int s, d; edge_sd(ei, i, s, d);
  float ee = expf(e_buf[i] - dec_f32(emax[d]));
  e_buf[i] = ee;
  unsafeAtomicAdd(&denom[d], ee);
}

// ---------- edge pass B2: alpha = ee / denom ----------
__global__ void edge_alpha(const int* __restrict__ ei, float* __restrict__ e_buf,
                           const float* __restrict__ denom) {
  int i = blockIdx.x * 256 + threadIdx.x;
  if (i >= E_TOT) return;
  int s, d; edge_sd(ei, i, s, d);
  e_buf[i] = e_buf[i] / (denom[d] + 1e-16f);
}

// ---------- edge pass C: agg[dst] += alpha * h[src] ----------
template<int C>
__global__ void edge_scatter(const int* __restrict__ ei, const float* __restrict__ e_buf,
                             const float* __restrict__ h, float* __restrict__ agg) {
  constexpr int CG = C / 4;
  int tid = blockIdx.x * 256 + threadIdx.x;
  int i = tid / CG;
  int cg = tid % CG;
  if (i >= E_TOT) return;
  int s, d; edge_sd(ei, i, s, d);
  float alpha = e_buf[i];
  const float4 hv = *reinterpret_cast<const float4*>(&h[(size_t)s * C + cg * 4]);
  float* out = &agg[(size_t)d * C + cg * 4];
  unsafeAtomicAdd(out + 0, alpha * hv.x);
  unsafeAtomicAdd(out + 1, alpha * hv.y);
  unsafeAtomicAdd(out + 2, alpha * hv.z);
  unsafeAtomicAdd(out + 3, alpha * hv.w);
}

// ---------- BN stats (f64 accumulation) ----------
template<int C>
__global__ void bn_stats(const float* __restrict__ x, double* __restrict__ sums, int n_nodes) {
  constexpr int TPC = 256 / C;   // threads (rows in flight) per channel
  constexpr int ROWS = 128;      // rows per block
  int c = threadIdx.x % C;
  int rs = threadIdx.x / C;
  int r0 = blockIdx.x * ROWS;
  int rend = min(r0 + ROWS, n_nodes);
  double s = 0.0, q = 0.0;
  for (int r = r0 + rs; r < rend; r += TPC) {
    float v = x[(size_t)r * C + c];
    s += v; q += (double)v * (double)v;
  }
  __shared__ double ss[256], sq[256];
  ss[threadIdx.x] = s; sq[threadIdx.x] = q;
  __syncthreads();
#pragma unroll
  for (int off = 128; off >= C; off >>= 1) {
    if (threadIdx.x < off) {
      ss[threadIdx.x] += ss[threadIdx.x + off];
      sq[threadIdx.x] += sq[threadIdx.x + off];
    }
    __syncthreads();
  }
  if (threadIdx.x < C) {
    unsafeAtomicAdd(&sums[c], ss[threadIdx.x]);
    unsafeAtomicAdd(&sums[C + c], sq[threadIdx.x]);
  }
}

// ---------- BN apply + leaky_relu(0.01), in place ----------
template<int C>
__global__ void bn_apply(float* __restrict__ x, const double* __restrict__ sums,
                         const float* __restrict__ gamma, const float* __restrict__ beta,
                         int n_nodes) {
  int idx = blockIdx.x * 256 + threadIdx.x;
  if (idx >= n_nodes * C) return;
  int c = idx % C;
  double mu = sums[c] / n_nodes;
  double var = sums[C + c] / n_nodes - mu * mu;
  float rs = rsqrtf((float)var + EPS_C);
  float v = ((float)(x[idx] - mu)) * rs * gamma[c] + beta[c];
  x[idx] = lrelu(v, 0.01f);
}

// ---------- global add pool over sorted batch ----------
__global__ void pool_kernel(const float* __restrict__ x, const int* __restrict__ batch,
                            float* __restrict__ pool) {
  int tid = blockIdx.x * 256 + threadIdx.x;
  int n = tid >> 5;        // 32 groups of 4 channels (C=128)
  int cg = tid & 31;
  if (n >= N_NODES_C) return;
  int g = batch[n];
  const float4 v = *reinterpret_cast<const float4*>(&x[(size_t)n * 128 + cg * 4]);
  float* o = &pool[(size_t)g * 128 + cg * 4];
  unsafeAtomicAdd(o + 0, v.x);
  unsafeAtomicAdd(o + 1, v.y);
  unsafeAtomicAdd(o + 2, v.z);
  unsafeAtomicAdd(o + 3, v.w);
}

// ---------- small FC: out = lrelu(in @ W + b, 0.01) ----------
template<int CIN, int COUT>
__global__ void fc_kernel(const float* __restrict__ in, const float* __restrict__ W,
                          const float* __restrict__ b, float* __restrict__ out, int rows) {
  int tid = blockIdx.x * 256 + threadIdx.x;
  int r = tid / COUT;
  int oc = tid % COUT;
  if (r >= rows) return;
  float acc = b[oc];
#pragma unroll 8
  for (int k = 0; k < CIN; ++k) acc += in[(size_t)r * CIN + k] * W[k * COUT + oc];
  out[(size_t)r * COUT + oc] = lrelu(acc, 0.01f);
}

// ---------- host-side per-layer driver ----------
template<int CIN, int COUT>
static void run_gat_layer(const float* xin, const float* W, const float* a_s, const float* a_d,
                          const float* gamma, const float* beta, const int* ei,
                          float* hbuf, float* e_buf, float* es, float* ed,
                          unsigned* emax, float* denom, float* agg, double* sums,
                          hipStream_t stream) {
  constexpr int NPB = 256 / COUT;
  gemm_node<CIN, COUT><<<(N_NODES_C + NPB - 1) / NPB, 256, 0, stream>>>(xin, W, hbuf, N_NODES_C);
  attn_logits<COUT><<<(N_NODES_C * 64 + 255) / 256, 256, 0, stream>>>(hbuf, a_s, a_d, es, ed, N_NODES_C);
  edge_logits<<<(E_TOT + 255) / 256, 256, 0, stream>>>(ei, es, ed, e_buf, emax);
  edge_exp<<<(E_TOT + 255) / 256, 256, 0, stream>>>(ei, e_buf, emax, denom);
  edge_alpha<<<(E_TOT + 255) / 256, 256, 0, stream>>>(ei, e_buf, denom);
  {
    long long tot = (long long)E_TOT * (COUT / 4);
    edge_scatter<COUT><<<(unsigned)((tot + 255) / 256), 256, 0, stream>>>(ei, e_buf, hbuf, agg);
  }
  bn_stats<COUT><<<(N_NODES_C + 127) / 128, 256, 0, stream>>>(agg, sums, N_NODES_C);
  bn_apply<COUT><<<(N_NODES_C * COUT + 255) / 256, 256, 0, stream>>>(agg, sums, gamma, beta, N_NODES_C);
}

extern "C" void kernel_launch(void* const* d_in, const int* in_sizes, int n_in,
                              void* d_out, int out_size, void* d_ws, size_t ws_size,
                              hipStream_t stream) {
  const float* x    = (const float*)d_in[0];
  // d_in[1] = edge_weigth (unused by reference)
  const int* ei     = (const int*)d_in[2];
  const int* batch  = (const int*)d_in[3];
  const float* W1   = (const float*)d_in[4];
  const float* as1  = (const float*)d_in[5];
  const float* ad1  = (const float*)d_in[6];
  const float* W2   = (const float*)d_in[8];
  const float* as2  = (const float*)d_in[9];
  const float* ad2  = (const float*)d_in[10];
  const float* W3   = (const float*)d_in[12];
  const float* as3  = (const float*)d_in[13];
  const float* ad3  = (const float*)d_in[14];
  const float* g1   = (const float*)d_in[16];
  const float* be1  = (const float*)d_in[17];
  const float* g2   = (const float*)d_in[18];
  const float* be2  = (const float*)d_in[19];
  const float* g3   = (const float*)d_in[20];
  const float* be3  = (const float*)d_in[21];
  const float* fc1w = (const float*)d_in[22];
  const float* fc1b = (const float*)d_in[23];
  const float* fc2w = (const float*)d_in[24];
  const float* fc2b = (const float*)d_in[25];
  const float* fc3w = (const float*)d_in[26];
  const float* fc3b = (const float*)d_in[27];
  float* out = (float*)d_out;

  char* ws = (char*)d_ws;
  size_t off = 0;
  auto alloc = [&](size_t bytes) { size_t o = off; off += (bytes + 255) & ~(size_t)255; return o; };

  // --- zero-init region (one memset per launch) ---
  size_t o_agg1  = alloc((size_t)N_NODES_C * 32 * 4);
  size_t o_agg2  = alloc((size_t)N_NODES_C * 64 * 4);
  size_t o_agg3  = alloc((size_t)N_NODES_C * 128 * 4);
  size_t o_den1  = alloc((size_t)N_NODES_C * 4);
  size_t o_den2  = alloc((size_t)N_NODES_C * 4);
  size_t o_den3  = alloc((size_t)N_NODES_C * 4);
  size_t o_emx1  = alloc((size_t)N_NODES_C * 4);
  size_t o_emx2  = alloc((size_t)N_NODES_C * 4);
  size_t o_emx3  = alloc((size_t)N_NODES_C * 4);
  size_t o_sum1  = alloc(2 * 32 * 8);
  size_t o_sum2  = alloc(2 * 64 * 8);
  size_t o_sum3  = alloc(2 * 128 * 8);
  size_t o_pool  = alloc((size_t)NUM_GRAPHS_C * 128 * 4);
  size_t zero_end = off;
  // --- written-before-read region ---
  size_t o_hbuf  = alloc((size_t)N_NODES_C * 128 * 4);
  size_t o_ebuf  = alloc((size_t)E_TOT * 4);
  size_t o_es    = alloc((size_t)N_NODES_C * 4);
  size_t o_ed    = alloc((size_t)N_NODES_C * 4);
  size_t o_fc1o  = alloc((size_t)NUM_GRAPHS_C * 128 * 4);
  size_t o_fc2o  = alloc((size_t)NUM_GRAPHS_C * 64 * 4);

  hipMemsetAsync(ws, 0, zero_end, stream);

  float*    hbuf  = (float*)(ws + o_hbuf);
  float*    e_buf = (float*)(ws + o_ebuf);
  float*    es    = (float*)(ws + o_es);
  float*    ed    = (float*)(ws + o_ed);
  float*    pool  = (float*)(ws + o_pool);
  float*    fc1o  = (float*)(ws + o_fc1o);
  float*    fc2o  = (float*)(ws + o_fc2o);

  // layer 1: x[50000,128] -> agg1[50000,32]
  run_gat_layer<128, 32>(x, W1, as1, ad1, g1, be1, ei,
                         hbuf, e_buf, es, ed,
                         (unsigned*)(ws + o_emx1), (float*)(ws + o_den1),
                         (float*)(ws + o_agg1), (double*)(ws + o_sum1), stream);
  // layer 2: agg1 -> agg2[50000,64]
  run_gat_layer<32, 64>((const float*)(ws + o_agg1), W2, as2, ad2, g2, be2, ei,
                        hbuf, e_buf, es, ed,
                        (unsigned*)(ws + o_emx2), (float*)(ws + o_den2),
                        (float*)(ws + o_agg2), (double*)(ws + o_sum2), stream);
  // layer 3: agg2 -> agg3[50000,128]
  run_gat_layer<64, 128>((const float*)(ws + o_agg2), W3, as3, ad3, g3, be3, ei,
                         hbuf, e_buf, es, ed,
                         (unsigned*)(ws + o_emx3), (float*)(ws + o_den3),
                         (float*)(ws + o_agg3), (double*)(ws + o_sum3), stream);

  // pool over batch (sorted) -> [1000,128]
  pool_kernel<<<(N_NODES_C * 32 + 255) / 256, 256, 0, stream>>>((const float*)(ws + o_agg3), batch, pool);

  // FC stack
  fc_kernel<128, 128><<<(NUM_GRAPHS_C * 128 + 255) / 256, 256, 0, stream>>>(pool, fc1w, fc1b, fc1o, NUM_GRAPHS_C);
  fc_kernel<128, 64><<<(NUM_GRAPHS_C * 64 + 255) / 256, 256, 0, stream>>>(fc1o, fc2w, fc2b, fc2o, NUM_GRAPHS_C);
  fc_kernel<64, 2><<<(NUM_GRAPHS_C * 2 + 255) / 256, 256, 0, stream>>>(fc2o, fc3w, fc3b, out, NUM_GRAPHS_C);
}

// Round 2
// 601.704 us; speedup vs baseline: 5.1664x; 5.1664x over previous
//
#include <hip/hip_runtime.h>

#define N_NODES_C 50000
#define N_EDGES_C 800000
#define E_TOT (N_EDGES_C + N_NODES_C)
#define NUM_GRAPHS_C 1000
#define EPS_C 1e-5f

// ---------- helpers ----------
static __device__ __forceinline__ void edge_sd(const int* __restrict__ ei, int i, int& s, int& d) {
  if (i < N_EDGES_C) { s = ei[i]; d = ei[N_EDGES_C + i]; }
  else { s = d = i - N_EDGES_C; }
}
static __device__ __forceinline__ float lrelu(float v, float slope) {
  return v >= 0.f ? v : slope * v;
}

// ---------- CSR build ----------
__global__ void deg_count(const int* __restrict__ ei, int* __restrict__ deg) {
  int i = blockIdx.x * 256 + threadIdx.x;
  if (i >= E_TOT) return;
  int d = (i < N_EDGES_C) ? ei[N_EDGES_C + i] : i - N_EDGES_C;
  atomicAdd(&deg[d], 1);
}

// single-block exclusive scan, writes out[0..n] (out[n] = total)
__global__ void scan_excl(const int* __restrict__ in, int* __restrict__ out, int n) {
  __shared__ int wsum[16];
  __shared__ int carry_s;
  int lane = threadIdx.x & 63, wid = threadIdx.x >> 6;
  if (threadIdx.x == 0) carry_s = 0;
  __syncthreads();
  for (int base = 0; base < n; base += 1024) {
    int i = base + threadIdx.x;
    int v = (i < n) ? in[i] : 0;
    int x = v;
#pragma unroll
    for (int off = 1; off < 64; off <<= 1) {
      int y = __shfl_up(x, off, 64);
      if (lane >= off) x += y;
    }
    if (lane == 63) wsum[wid] = x;
    __syncthreads();
    if (threadIdx.x < 16) {
      int w = wsum[threadIdx.x];
#pragma unroll
      for (int off = 1; off < 16; off <<= 1) {
        int y = __shfl_up(w, off, 64);
        if ((int)threadIdx.x >= off) w += y;
      }
      wsum[threadIdx.x] = w;
    }
    __syncthreads();
    int carry = carry_s;
    int excl = carry + (wid ? wsum[wid - 1] : 0) + (x - v);
    if (i < n) out[i] = excl;
    __syncthreads();
    if (threadIdx.x == 0) carry_s = carry + wsum[15];
    __syncthreads();
  }
  if (threadIdx.x == 0) out[n] = carry_s;
}

__global__ void fill_csr(const int* __restrict__ ei, const int* __restrict__ rowptr,
                         int* __restrict__ cursor, int* __restrict__ csr_src) {
  int i = blockIdx.x * 256 + threadIdx.x;
  if (i >= E_TOT) return;
  int s, d; edge_sd(ei, i, s, d);
  int pos = rowptr[d] + atomicAdd(&cursor[d], 1);
  csr_src[pos] = s;
}

__global__ void graph_count(const int* __restrict__ batch, int* __restrict__ gdeg) {
  int i = blockIdx.x * 256 + threadIdx.x;
  if (i >= N_NODES_C) return;
  atomicAdd(&gdeg[batch[i]], 1);
}

// ---------- node GEMM: h = x @ W ----------
template<int CIN, int COUT>
__global__ void gemm_node(const float* __restrict__ x, const float* __restrict__ W,
                          float* __restrict__ h, int n_nodes) {
  constexpr int NPB = 256 / COUT;  // nodes per block
  __shared__ float sW[CIN * COUT];
  __shared__ float sx[NPB * CIN];
  for (int i = threadIdx.x; i < CIN * COUT; i += 256) sW[i] = W[i];
  int node0 = blockIdx.x * NPB;
  for (int i = threadIdx.x; i < NPB * CIN; i += 256) {
    int n = node0 + i / CIN;
    sx[i] = (n < n_nodes) ? x[(size_t)n * CIN + (i % CIN)] : 0.f;
  }
  __syncthreads();
  int oc = threadIdx.x % COUT;
  int ln = threadIdx.x / COUT;
  int n = node0 + ln;
  if (n >= n_nodes) return;
  float acc = 0.f;
#pragma unroll
  for (int k = 0; k < CIN; ++k) acc += sx[ln * CIN + k] * sW[k * COUT + oc];
  h[(size_t)n * COUT + oc] = acc;
}

// ---------- per-node attention logits: es = h.as, ed = h.ad ----------
template<int C>
__global__ void attn_logits(const float* __restrict__ h, const float* __restrict__ a_s,
                            const float* __restrict__ a_d, float* __restrict__ es,
                            float* __restrict__ ed, int n_nodes) {
  int wave = (blockIdx.x * blockDim.x + threadIdx.x) >> 6;
  int lane = threadIdx.x & 63;
  if (wave >= n_nodes) return;
  float s1 = 0.f, s2 = 0.f;
  for (int c = lane; c < C; c += 64) {
    float v = h[(size_t)wave * C + c];
    s1 += v * a_s[c];
    s2 += v * a_d[c];
  }
#pragma unroll
  for (int off = 32; off; off >>= 1) {
    s1 += __shfl_down(s1, off, 64);
    s2 += __shfl_down(s2, off, 64);
  }
  if (lane == 0) { es[wave] = s1; ed[wave] = s2; }
}

// ---------- fused per-node GAT aggregation (softmax + weighted gather) ----------
template<int C>
__global__ void gat_aggregate(const int* __restrict__ rowptr, const int* __restrict__ csr_src,
                              const float* __restrict__ es, const float* __restrict__ ed,
                              const float* __restrict__ h, float* __restrict__ agg) {
  int node = (blockIdx.x * blockDim.x + threadIdx.x) >> 6;
  int lane = threadIdx.x & 63;
  if (node >= N_NODES_C) return;
  int r0 = rowptr[node], r1 = rowptr[node + 1];
  int deg = r1 - r0;
  float edv = ed[node];

  float acc0 = 0.f, acc1 = 0.f;

  if (deg <= 64) {
    // fast path: one edge per lane
    int srcj = 0; float e = -1e30f;
    if (lane < deg) { srcj = csr_src[r0 + lane]; e = lrelu(es[srcj] + edv, 0.2f); }
    float m = e;
#pragma unroll
    for (int off = 32; off; off >>= 1) m = fmaxf(m, __shfl_xor(m, off, 64));
    float ee = (lane < deg) ? __expf(e - m) : 0.f;
    float ssum = ee;
#pragma unroll
    for (int off = 32; off; off >>= 1) ssum += __shfl_xor(ssum, off, 64);
    float alpha = ee / (ssum + 1e-16f);
    for (int t = 0; t < deg; ++t) {
      int sj = __shfl(srcj, t, 64);
      float al = __shfl(alpha, t, 64);
      if constexpr (C == 128) {
        const float2 hv = *reinterpret_cast<const float2*>(&h[(size_t)sj * 128 + lane * 2]);
        acc0 += al * hv.x; acc1 += al * hv.y;
      } else if constexpr (C == 64) {
        acc0 += al * h[(size_t)sj * 64 + lane];
      } else {
        if (lane < C) acc0 += al * h[(size_t)sj * C + lane];
      }
    }
  } else {
    // general fallback (deg > 64): recompute logits per pass
    float m = -1e30f;
    for (int j = lane; j < deg; j += 64)
      m = fmaxf(m, lrelu(es[csr_src[r0 + j]] + edv, 0.2f));
#pragma unroll
    for (int off = 32; off; off >>= 1) m = fmaxf(m, __shfl_xor(m, off, 64));
    float ssum = 0.f;
    for (int j = lane; j < deg; j += 64)
      ssum += __expf(lrelu(es[csr_src[r0 + j]] + edv, 0.2f) - m);
#pragma unroll
    for (int off = 32; off; off >>= 1) ssum += __shfl_xor(ssum, off, 64);
    float inv = 1.f / (ssum + 1e-16f);
    for (int base = 0; base < deg; base += 64) {
      int j = base + lane; int srcj = 0; float al = 0.f;
      if (j < deg) { srcj = csr_src[r0 + j]; al = __expf(lrelu(es[srcj] + edv, 0.2f) - m) * inv; }
      int cnt = min(64, deg - base);
      for (int t = 0; t < cnt; ++t) {
        int sj = __shfl(srcj, t, 64);
        float al_t = __shfl(al, t, 64);
        if constexpr (C == 128) {
          const float2 hv = *reinterpret_cast<const float2*>(&h[(size_t)sj * 128 + lane * 2]);
          acc0 += al_t * hv.x; acc1 += al_t * hv.y;
        } else if constexpr (C == 64) {
          acc0 += al_t * h[(size_t)sj * 64 + lane];
        } else {
          if (lane < C) acc0 += al_t * h[(size_t)sj * C + lane];
        }
      }
    }
  }

  if constexpr (C == 128) {
    float2 o; o.x = acc0; o.y = acc1;
    *reinterpret_cast<float2*>(&agg[(size_t)node * 128 + lane * 2]) = o;
  } else if constexpr (C == 64) {
    agg[(size_t)node * 64 + lane] = acc0;
  } else {
    if (lane < C) agg[(size_t)node * C + lane] = acc0;
  }
}

// ---------- BN stats (f64 accumulation) ----------
template<int C>
__global__ void bn_stats(const float* __restrict__ x, double* __restrict__ sums, int n_nodes) {
  constexpr int TPC = 256 / C;
  constexpr int ROWS = 128;
  int c = threadIdx.x % C;
  int rs = threadIdx.x / C;
  int r0 = blockIdx.x * ROWS;
  int rend = min(r0 + ROWS, n_nodes);
  double s = 0.0, q = 0.0;
  for (int r = r0 + rs; r < rend; r += TPC) {
    float v = x[(size_t)r * C + c];
    s += v; q += (double)v * (double)v;
  }
  __shared__ double ss[256], sq[256];
  ss[threadIdx.x] = s; sq[threadIdx.x] = q;
  __syncthreads();
#pragma unroll
  for (int off = 128; off >= C; off >>= 1) {
    if (threadIdx.x < off) {
      ss[threadIdx.x] += ss[threadIdx.x + off];
      sq[threadIdx.x] += sq[threadIdx.x + off];
    }
    __syncthreads();
  }
  if (threadIdx.x < C) {
    unsafeAtomicAdd(&sums[c], ss[threadIdx.x]);
    unsafeAtomicAdd(&sums[C + c], sq[threadIdx.x]);
  }
}

// ---------- BN finalize: per-channel scale/shift ----------
template<int C>
__global__ void bn_finalize(const double* __restrict__ sums, const float* __restrict__ gamma,
                            const float* __restrict__ beta, float* __restrict__ sb) {
  int c = threadIdx.x;
  if (c >= C) return;
  double mu = sums[c] / N_NODES_C;
  double var = sums[C + c] / N_NODES_C - mu * mu;
  float scale = gamma[c] * rsqrtf((float)var + EPS_C);
  sb[c] = scale;
  sb[C + c] = beta[c] - (float)mu * scale;
}

// ---------- BN apply + leaky_relu(0.01), in place ----------
template<int C>
__global__ void bn_apply(float* __restrict__ x, const float* __restrict__ sb, int n_elem) {
  int idx = blockIdx.x * 256 + threadIdx.x;
  if (idx >= n_elem) return;
  int c = idx & (C - 1);
  float v = x[idx] * sb[c] + sb[C + c];
  x[idx] = lrelu(v, 0.01f);
}

// ---------- pool: one wave per graph over sorted batch ranges ----------
__global__ void pool_gather(const float* __restrict__ x, const int* __restrict__ gptr,
                            float* __restrict__ pool) {
  int g = (blockIdx.x * blockDim.x + threadIdx.x) >> 6;
  int lane = threadIdx.x & 63;
  if (g >= NUM_GRAPHS_C) return;
  int n0 = gptr[g], n1 = gptr[g + 1];
  float ax = 0.f, ay = 0.f;
  for (int n = n0; n < n1; ++n) {
    const float2 v = *reinterpret_cast<const float2*>(&x[(size_t)n * 128 + lane * 2]);
    ax += v.x; ay += v.y;
  }
  float2 o; o.x = ax; o.y = ay;
  *reinterpret_cast<float2*>(&pool[(size_t)g * 128 + lane * 2]) = o;
}

// ---------- small FC: out = lrelu(in @ W + b, 0.01) ----------
template<int CIN, int COUT>
__global__ void fc_kernel(const float* __restrict__ in, const float* __restrict__ W,
                          const float* __restrict__ b, float* __restrict__ out, int rows) {
  int tid = blockIdx.x * 256 + threadIdx.x;
  int r = tid / COUT;
  int oc = tid % COUT;
  if (r >= rows) return;
  float acc = b[oc];
#pragma unroll 8
  for (int k = 0; k < CIN; ++k) acc += in[(size_t)r * CIN + k] * W[k * COUT + oc];
  out[(size_t)r * COUT + oc] = lrelu(acc, 0.01f);
}

// ---------- host-side per-layer driver ----------
template<int CIN, int COUT>
static void run_gat_layer(const float* xin, const float* W, const float* a_s, const float* a_d,
                          const float* gamma, const float* beta,
                          const int* rowptr, const int* csr_src,
                          float* hbuf, float* es, float* ed,
                          float* agg, double* sums, float* sb,
                          hipStream_t stream) {
  constexpr int NPB = 256 / COUT;
  gemm_node<CIN, COUT><<<(N_NODES_C + NPB - 1) / NPB, 256, 0, stream>>>(xin, W, hbuf, N_NODES_C);
  attn_logits<COUT><<<(N_NODES_C * 64 + 255) / 256, 256, 0, stream>>>(hbuf, a_s, a_d, es, ed, N_NODES_C);
  gat_aggregate<COUT><<<(N_NODES_C * 64 + 255) / 256, 256, 0, stream>>>(rowptr, csr_src, es, ed, hbuf, agg);
  bn_stats<COUT><<<(N_NODES_C + 127) / 128, 256, 0, stream>>>(agg, sums, N_NODES_C);
  bn_finalize<COUT><<<1, COUT, 0, stream>>>(sums, gamma, beta, sb);
  bn_apply<COUT><<<(N_NODES_C * COUT + 255) / 256, 256, 0, stream>>>(agg, sb, N_NODES_C * COUT);
}

extern "C" void kernel_launch(void* const* d_in, const int* in_sizes, int n_in,
                              void* d_out, int out_size, void* d_ws, size_t ws_size,
                              hipStream_t stream) {
  const float* x    = (const float*)d_in[0];
  const int* ei     = (const int*)d_in[2];
  const int* batch  = (const int*)d_in[3];
  const float* W1   = (const float*)d_in[4];
  const float* as1  = (const float*)d_in[5];
  const float* ad1  = (const float*)d_in[6];
  const float* W2   = (const float*)d_in[8];
  const float* as2  = (const float*)d_in[9];
  const float* ad2  = (const float*)d_in[10];
  const float* W3   = (const float*)d_in[12];
  const float* as3  = (const float*)d_in[13];
  const float* ad3  = (const float*)d_in[14];
  const float* g1   = (const float*)d_in[16];
  const float* be1  = (const float*)d_in[17];
  const float* g2   = (const float*)d_in[18];
  const float* be2  = (const float*)d_in[19];
  const float* g3   = (const float*)d_in[20];
  const float* be3  = (const float*)d_in[21];
  const float* fc1w = (const float*)d_in[22];
  const float* fc1b = (const float*)d_in[23];
  const float* fc2w = (const float*)d_in[24];
  const float* fc2b = (const float*)d_in[25];
  const float* fc3w = (const float*)d_in[26];
  const float* fc3b = (const float*)d_in[27];
  float* out = (float*)d_out;

  char* ws = (char*)d_ws;
  size_t off = 0;
  auto alloc = [&](size_t bytes) { size_t o = off; off += (bytes + 255) & ~(size_t)255; return o; };

  // --- zero-init region (one memset per launch) ---
  size_t o_deg   = alloc((size_t)N_NODES_C * 4);
  size_t o_cur   = alloc((size_t)N_NODES_C * 4);
  size_t o_gdeg  = alloc((size_t)NUM_GRAPHS_C * 4);
  size_t o_sum1  = alloc(2 * 32 * 8);
  size_t o_sum2  = alloc(2 * 64 * 8);
  size_t o_sum3  = alloc(2 * 128 * 8);
  size_t zero_end = off;
  // --- written-before-read region ---
  size_t o_rowp  = alloc((size_t)(N_NODES_C + 1) * 4);
  size_t o_gptr  = alloc((size_t)(NUM_GRAPHS_C + 1) * 4);
  size_t o_csr   = alloc((size_t)E_TOT * 4);
  size_t o_hbuf  = alloc((size_t)N_NODES_C * 128 * 4);
  size_t o_es    = alloc((size_t)N_NODES_C * 4);
  size_t o_ed    = alloc((size_t)N_NODES_C * 4);
  size_t o_agg1  = alloc((size_t)N_NODES_C * 32 * 4);
  size_t o_agg2  = alloc((size_t)N_NODES_C * 64 * 4);
  size_t o_agg3  = alloc((size_t)N_NODES_C * 128 * 4);
  size_t o_sb1   = alloc(2 * 32 * 4);
  size_t o_sb2   = alloc(2 * 64 * 4);
  size_t o_sb3   = alloc(2 * 128 * 4);
  size_t o_pool  = alloc((size_t)NUM_GRAPHS_C * 128 * 4);
  size_t o_fc1o  = alloc((size_t)NUM_GRAPHS_C * 128 * 4);
  size_t o_fc2o  = alloc((size_t)NUM_GRAPHS_C * 64 * 4);

  hipMemsetAsync(ws, 0, zero_end, stream);

  int*    deg    = (int*)(ws + o_deg);
  int*    cursor = (int*)(ws + o_cur);
  int*    gdeg   = (int*)(ws + o_gdeg);
  int*    rowptr = (int*)(ws + o_rowp);
  int*    gptr   = (int*)(ws + o_gptr);
  int*    csr    = (int*)(ws + o_csr);
  float*  hbuf   = (float*)(ws + o_hbuf);
  float*  es     = (float*)(ws + o_es);
  float*  ed     = (float*)(ws + o_ed);
  float*  pool   = (float*)(ws + o_pool);
  float*  fc1o   = (float*)(ws + o_fc1o);
  float*  fc2o   = (float*)(ws + o_fc2o);

  // CSR build (shared by all 3 layers)
  deg_count<<<(E_TOT + 255) / 256, 256, 0, stream>>>(ei, deg);
  scan_excl<<<1, 1024, 0, stream>>>(deg, rowptr, N_NODES_C);
  fill_csr<<<(E_TOT + 255) / 256, 256, 0, stream>>>(ei, rowptr, cursor, csr);
  // graph ranges (batch is sorted)
  graph_count<<<(N_NODES_C + 255) / 256, 256, 0, stream>>>(batch, gdeg);
  scan_excl<<<1, 1024, 0, stream>>>(gdeg, gptr, NUM_GRAPHS_C);

  // layer 1: x[50000,128] -> agg1[50000,32]
  run_gat_layer<128, 32>(x, W1, as1, ad1, g1, be1, rowptr, csr,
                         hbuf, es, ed, (float*)(ws + o_agg1), (double*)(ws + o_sum1),
                         (float*)(ws + o_sb1), stream);
  // layer 2
  run_gat_layer<32, 64>((const float*)(ws + o_agg1), W2, as2, ad2, g2, be2, rowptr, csr,
                        hbuf, es, ed, (float*)(ws + o_agg2), (double*)(ws + o_sum2),
                        (float*)(ws + o_sb2), stream);
  // layer 3
  run_gat_layer<64, 128>((const float*)(ws + o_agg2), W3, as3, ad3, g3, be3, rowptr, csr,
                         hbuf, es, ed, (float*)(ws + o_agg3), (double*)(ws + o_sum3),
                         (float*)(ws + o_sb3), stream);

  // pool over batch ranges -> [1000,128]
  pool_gather<<<(NUM_GRAPHS_C * 64 + 255) / 256, 256, 0, stream>>>((const float*)(ws + o_agg3), gptr, pool);

  // FC stack
  fc_kernel<128, 128><<<(NUM_GRAPHS_C * 128 + 255) / 256, 256, 0, stream>>>(pool, fc1w, fc1b, fc1o, NUM_GRAPHS_C);
  fc_kernel<128, 64><<<(NUM_GRAPHS_C * 64 + 255) / 256, 256, 0, stream>>>(fc1o, fc2w, fc2b, fc2o, NUM_GRAPHS_C);
  fc_kernel<64, 2><<<(NUM_GRAPHS_C * 2 + 255) / 256, 256, 0, stream>>>(fc2o, fc3w, fc3b, out, NUM_GRAPHS_C);
}

// Round 3
// 537.436 us; speedup vs baseline: 5.7842x; 1.1196x over previous
//
#include <hip/hip_runtime.h>
#include <hip/hip_bf16.h>

#define N_NODES_C 50000
#define N_EDGES_C 800000
#define E_TOT (N_EDGES_C + N_NODES_C)
#define NUM_GRAPHS_C 1000
#define EPS_C 1e-5f
#define SCAN_TILE 1024
#define NB_SCAN ((N_NODES_C + SCAN_TILE - 1) / SCAN_TILE)  // 49
#define SH 8  // shadow copies for BN-sum atomics

static __device__ __forceinline__ float lrelu(float v, float slope) {
  return v >= 0.f ? v : slope * v;
}
static __device__ __forceinline__ float bf2f(unsigned short u) {
  return __uint_as_float((unsigned)u << 16);
}

// ---------- counts: in-degree histogram + graph histogram ----------
__global__ void counts_kernel(const int* __restrict__ ei, const int* __restrict__ batch,
                              int* __restrict__ deg, int* __restrict__ gdeg) {
  int i = blockIdx.x * 256 + threadIdx.x;
  if (i < E_TOT) {
    int d = (i < N_EDGES_C) ? ei[N_EDGES_C + i] : i - N_EDGES_C;
    atomicAdd(&deg[d], 1);
  }
  if (i < N_NODES_C) atomicAdd(&gdeg[batch[i]], 1);
}

// ---------- scan stage 1: per-tile sums ----------
__global__ void scan_partial(const int* __restrict__ in, int* __restrict__ bsum, int n) {
  __shared__ int red[256];
  int t = threadIdx.x;
  int base = blockIdx.x * SCAN_TILE;
  int s = 0;
  for (int j = t; j < SCAN_TILE; j += 256) {
    int i = base + j;
    s += (i < n) ? in[i] : 0;
  }
  red[t] = s;
  __syncthreads();
  for (int off = 128; off; off >>= 1) {
    if (t < off) red[t] += red[t + off];
    __syncthreads();
  }
  if (t == 0) bsum[blockIdx.x] = red[0];
}

// ---------- scan stage 2: scan tile sums + full graph scan ----------
__global__ void scan_mid(const int* __restrict__ bsum, const int* __restrict__ gdeg,
                         int* __restrict__ boff, int* __restrict__ gptr,
                         int* __restrict__ rowptr) {
  int t = threadIdx.x;
  int lane = t & 63;
  // phase A: exclusive scan of bsum[NB_SCAN] (fits one wave)
  if (t < 64) {
    int v = (t < NB_SCAN) ? bsum[t] : 0;
    int x = v;
#pragma unroll
    for (int off = 1; off < 64; off <<= 1) {
      int y = __shfl_up(x, off, 64);
      if (lane >= off) x += y;
    }
    if (t < NB_SCAN) boff[t] = x - v;
  }
  // phase B: exclusive scan of gdeg[1000]
  __shared__ int wsum[16];
  int v = (t < NUM_GRAPHS_C) ? gdeg[t] : 0;
  int x = v;
#pragma unroll
  for (int off = 1; off < 64; off <<= 1) {
    int y = __shfl_up(x, off, 64);
    if (lane >= off) x += y;
  }
  int wid = t >> 6;
  if (lane == 63) wsum[wid] = x;
  __syncthreads();
  if (t < 16) {
    int w = wsum[t];
#pragma unroll
    for (int off = 1; off < 16; off <<= 1) {
      int y = __shfl_up(w, off, 64);
      if (t >= off) w += y;
    }
    wsum[t] = w;
  }
  __syncthreads();
  int excl = (wid ? wsum[wid - 1] : 0) + (x - v);
  if (t < NUM_GRAPHS_C) gptr[t] = excl;
  if (t == 0) { gptr[NUM_GRAPHS_C] = N_NODES_C; rowptr[N_NODES_C] = E_TOT; }
}

// ---------- scan stage 3: per-tile exclusive scan + tile offset ----------
__global__ void scan_final(const int* __restrict__ in, const int* __restrict__ boff,
                           int* __restrict__ out, int n) {
  __shared__ int wsum[16];
  int t = threadIdx.x;  // 1024
  int i = blockIdx.x * SCAN_TILE + t;
  int lane = t & 63, wid = t >> 6;
  int v = (i < n) ? in[i] : 0;
  int x = v;
#pragma unroll
  for (int off = 1; off < 64; off <<= 1) {
    int y = __shfl_up(x, off, 64);
    if (lane >= off) x += y;
  }
  if (lane == 63) wsum[wid] = x;
  __syncthreads();
  if (t < 16) {
    int w = wsum[t];
#pragma unroll
    for (int off = 1; off < 16; off <<= 1) {
      int y = __shfl_up(w, off, 64);
      if (t >= off) w += y;
    }
    wsum[t] = w;
  }
  __syncthreads();
  int excl = boff[blockIdx.x] + (wid ? wsum[wid - 1] : 0) + (x - v);
  if (i < n) out[i] = excl;
}

// ---------- CSR fill ----------
__global__ void fill_csr(const int* __restrict__ ei, const int* __restrict__ rowptr,
                         int* __restrict__ cursor, int* __restrict__ csr_src) {
  int i = blockIdx.x * 256 + threadIdx.x;
  if (i >= E_TOT) return;
  int s, d;
  if (i < N_EDGES_C) { s = ei[i]; d = ei[N_EDGES_C + i]; }
  else { s = d = i - N_EDGES_C; }
  int pos = rowptr[d] + atomicAdd(&cursor[d], 1);
  csr_src[pos] = s;
}

// ---------- fused GEMM: (optional BN+lrelu of input) @ W -> bf16 h + attn logits ----------
template<int CIN, int COUT, bool BN>
__global__ void gemm_fused(const float* __restrict__ x, const float* __restrict__ W,
                           const float* __restrict__ a_s, const float* __restrict__ a_d,
                           const double* __restrict__ sums, const float* __restrict__ gamma,
                           const float* __restrict__ beta,
                           __hip_bfloat16* __restrict__ hb, float* __restrict__ es,
                           float* __restrict__ ed) {
  constexpr int NPB = 256 / COUT;
  __shared__ float sW[CIN * COUT];
  __shared__ float sx[NPB * CIN];
  __shared__ float sA[COUT], sD[COUT];
  __shared__ float sbn[BN ? 2 * CIN : 1];
  __shared__ float pls[8], pld[8];
  int t = threadIdx.x;
  if (BN && t < CIN) {
    double s = 0.0, q = 0.0;
    for (int k = 0; k < SH; ++k) { s += sums[k * 2 * CIN + t]; q += sums[k * 2 * CIN + CIN + t]; }
    double mu = s / N_NODES_C;
    double var = q / N_NODES_C - mu * mu;
    float sc = gamma[t] * rsqrtf((float)var + EPS_C);
    sbn[t] = sc;
    sbn[CIN + t] = beta[t] - (float)mu * sc;
  }
  if (t < COUT) { sA[t] = a_s[t]; sD[t] = a_d[t]; }
  for (int i = t; i < CIN * COUT; i += 256) sW[i] = W[i];
  __syncthreads();
  int node0 = blockIdx.x * NPB;
  for (int i = t; i < NPB * CIN; i += 256) {
    int n = node0 + i / CIN;
    int c = i % CIN;
    float v = (n < N_NODES_C) ? x[(size_t)n * CIN + c] : 0.f;
    if (BN) v = lrelu(v * sbn[c] + sbn[CIN + c], 0.01f);
    sx[i] = v;
  }
  __syncthreads();
  int oc = t % COUT;
  int ln = t / COUT;
  int n = node0 + ln;
  float acc = 0.f;
#pragma unroll
  for (int k = 0; k < CIN; ++k) acc += sx[ln * CIN + k] * sW[k * COUT + oc];
  bool act = (n < N_NODES_C);
  if (act) hb[(size_t)n * COUT + oc] = __float2bfloat16(acc);
  float ps = acc * sA[oc], pd = acc * sD[oc];
  if constexpr (COUT <= 64) {
#pragma unroll
    for (int off = COUT / 2; off; off >>= 1) {
      ps += __shfl_xor(ps, off, 64);
      pd += __shfl_xor(pd, off, 64);
    }
    if (act && oc == 0) { es[n] = ps; ed[n] = pd; }
  } else {  // COUT == 128: node spans 2 waves
#pragma unroll
    for (int off = 32; off; off >>= 1) {
      ps += __shfl_xor(ps, off, 64);
      pd += __shfl_xor(pd, off, 64);
    }
    int lane = t & 63, wid = t >> 6;
    if (lane == 0) { pls[wid] = ps; pld[wid] = pd; }
    __syncthreads();
    if (t < NPB) {
      int n2 = node0 + t;
      if (n2 < N_NODES_C) {
        es[n2] = pls[2 * t] + pls[2 * t + 1];
        ed[n2] = pld[2 * t] + pld[2 * t + 1];
      }
    }
  }
}

// ---------- fused aggregate: segment softmax + bf16 weighted gather + BN partial sums ----------
template<int C>
__global__ void gat_aggregate(const int* __restrict__ rowptr, const int* __restrict__ csr_src,
                              const float* __restrict__ es, const float* __restrict__ ed,
                              const unsigned short* __restrict__ hb, float* __restrict__ agg,
                              double* __restrict__ sums) {
  __shared__ float sbn[2 * C];
  int t = threadIdx.x;
  int lane = t & 63;
  int node = (blockIdx.x * 256 + t) >> 6;
  for (int i = t; i < 2 * C; i += 256) sbn[i] = 0.f;
  __syncthreads();
  float acc0 = 0.f, acc1 = 0.f;
  if (node < N_NODES_C) {
    int r0 = rowptr[node], r1 = rowptr[node + 1];
    int deg = r1 - r0;
    float edv = ed[node];
    if (deg <= 64) {
      int srcj = 0; float e = -1e30f;
      if (lane < deg) { srcj = csr_src[r0 + lane]; e = lrelu(es[srcj] + edv, 0.2f); }
      float m = e;
#pragma unroll
      for (int off = 32; off; off >>= 1) m = fmaxf(m, __shfl_xor(m, off, 64));
      float ee = (lane < deg) ? __expf(e - m) : 0.f;
      float ssum = ee;
#pragma unroll
      for (int off = 32; off; off >>= 1) ssum += __shfl_xor(ssum, off, 64);
      float alpha = ee / (ssum + 1e-16f);
#pragma unroll 4
      for (int tt = 0; tt < deg; ++tt) {
        int sj = __shfl(srcj, tt, 64);
        float al = __shfl(alpha, tt, 64);
        if constexpr (C == 128) {
          ushort2 u = *reinterpret_cast<const ushort2*>(&hb[(size_t)sj * 128 + lane * 2]);
          acc0 += al * bf2f(u.x);
          acc1 += al * bf2f(u.y);
        } else if constexpr (C == 64) {
          acc0 += al * bf2f(hb[(size_t)sj * 64 + lane]);
        } else {
          if (lane < C) acc0 += al * bf2f(hb[(size_t)sj * C + lane]);
        }
      }
    } else {
      float m = -1e30f;
      for (int j = lane; j < deg; j += 64)
        m = fmaxf(m, lrelu(es[csr_src[r0 + j]] + edv, 0.2f));
#pragma unroll
      for (int off = 32; off; off >>= 1) m = fmaxf(m, __shfl_xor(m, off, 64));
      float ssum = 0.f;
      for (int j = lane; j < deg; j += 64)
        ssum += __expf(lrelu(es[csr_src[r0 + j]] + edv, 0.2f) - m);
#pragma unroll
      for (int off = 32; off; off >>= 1) ssum += __shfl_xor(ssum, off, 64);
      float inv = 1.f / (ssum + 1e-16f);
      for (int base = 0; base < deg; base += 64) {
        int j = base + lane; int srcj = 0; float al = 0.f;
        if (j < deg) { srcj = csr_src[r0 + j]; al = __expf(lrelu(es[srcj] + edv, 0.2f) - m) * inv; }
        int cnt = min(64, deg - base);
        for (int tt = 0; tt < cnt; ++tt) {
          int sj = __shfl(srcj, tt, 64);
          float al_t = __shfl(al, tt, 64);
          if constexpr (C == 128) {
            ushort2 u = *reinterpret_cast<const ushort2*>(&hb[(size_t)sj * 128 + lane * 2]);
            acc0 += al_t * bf2f(u.x);
            acc1 += al_t * bf2f(u.y);
          } else if constexpr (C == 64) {
            acc0 += al_t * bf2f(hb[(size_t)sj * 64 + lane]);
          } else {
            if (lane < C) acc0 += al_t * bf2f(hb[(size_t)sj * C + lane]);
          }
        }
      }
    }
    // store agg (f32) + BN partials into LDS
    if constexpr (C == 128) {
      float2 o; o.x = acc0; o.y = acc1;
      *reinterpret_cast<float2*>(&agg[(size_t)node * 128 + lane * 2]) = o;
      atomicAdd(&sbn[lane * 2], acc0);
      atomicAdd(&sbn[lane * 2 + 1], acc1);
      atomicAdd(&sbn[C + lane * 2], acc0 * acc0);
      atomicAdd(&sbn[C + lane * 2 + 1], acc1 * acc1);
    } else if constexpr (C == 64) {
      agg[(size_t)node * 64 + lane] = acc0;
      atomicAdd(&sbn[lane], acc0);
      atomicAdd(&sbn[C + lane], acc0 * acc0);
    } else {
      if (lane < C) {
        agg[(size_t)node * C + lane] = acc0;
        atomicAdd(&sbn[lane], acc0);
        atomicAdd(&sbn[C + lane], acc0 * acc0);
      }
    }
  }
  __syncthreads();
  double* dst = sums + (size_t)(blockIdx.x & (SH - 1)) * (2 * C);
  for (int i = t; i < 2 * C; i += 256) unsafeAtomicAdd(&dst[i], (double)sbn[i]);
}

// ---------- fused pool (BN3+lrelu applied) + 3 FC layers: one block per graph ----------
__global__ void poolfc_kernel(const float* __restrict__ agg3, const int* __restrict__ gptr,
                              const double* __restrict__ sums, const float* __restrict__ gamma,
                              const float* __restrict__ beta,
                              const float* __restrict__ fc1w, const float* __restrict__ fc1b,
                              const float* __restrict__ fc2w, const float* __restrict__ fc2b,
                              const float* __restrict__ fc3w, const float* __restrict__ fc3b,
                              float* __restrict__ out) {
  __shared__ float sc[128], sh[128];
  __shared__ float row[128], buf[128];
  int t = threadIdx.x;  // 128
  {
    double s = 0.0, q = 0.0;
    for (int k = 0; k < SH; ++k) { s += sums[k * 256 + t]; q += sums[k * 256 + 128 + t]; }
    double mu = s / N_NODES_C;
    double var = q / N_NODES_C - mu * mu;
    float scale = gamma[t] * rsqrtf((float)var + EPS_C);
    sc[t] = scale;
    sh[t] = beta[t] - (float)mu * scale;
  }
  __syncthreads();
  int g = blockIdx.x;
  int n0 = gptr[g], n1 = gptr[g + 1];
  float acc = 0.f;
  float scale = sc[t], shift = sh[t];
  for (int n = n0; n < n1; ++n)
    acc += lrelu(agg3[(size_t)n * 128 + t] * scale + shift, 0.01f);
  row[t] = acc;
  __syncthreads();
  // fc1: 128 -> 128
  {
    float s = fc1b[t];
#pragma unroll 8
    for (int k = 0; k < 128; ++k) s += row[k] * fc1w[k * 128 + t];
    buf[t] = lrelu(s, 0.01f);
  }
  __syncthreads();
  // fc2: 128 -> 64
  if (t < 64) {
    float s = fc2b[t];
#pragma unroll 8
    for (int k = 0; k < 128; ++k) s += buf[k] * fc2w[k * 64 + t];
    row[t] = lrelu(s, 0.01f);
  }
  __syncthreads();
  // fc3: 64 -> 2
  if (t < 2) {
    float s = fc3b[t];
#pragma unroll 8
    for (int k = 0; k < 64; ++k) s += row[k] * fc3w[k * 2 + t];
    out[(size_t)g * 2 + t] = lrelu(s, 0.01f);
  }
}

extern "C" void kernel_launch(void* const* d_in, const int* in_sizes, int n_in,
                              void* d_out, int out_size, void* d_ws, size_t ws_size,
                              hipStream_t stream) {
  const float* x    = (const float*)d_in[0];
  const int* ei     = (const int*)d_in[2];
  const int* batch  = (const int*)d_in[3];
  const float* W1   = (const float*)d_in[4];
  const float* as1  = (const float*)d_in[5];
  const float* ad1  = (const float*)d_in[6];
  const float* W2   = (const float*)d_in[8];
  const float* as2  = (const float*)d_in[9];
  const float* ad2  = (const float*)d_in[10];
  const float* W3   = (const float*)d_in[12];
  const float* as3  = (const float*)d_in[13];
  const float* ad3  = (const float*)d_in[14];
  const float* g1   = (const float*)d_in[16];
  const float* be1  = (const float*)d_in[17];
  const float* g2   = (const float*)d_in[18];
  const float* be2  = (const float*)d_in[19];
  const float* g3   = (const float*)d_in[20];
  const float* be3  = (const float*)d_in[21];
  const float* fc1w = (const float*)d_in[22];
  const float* fc1b = (const float*)d_in[23];
  const float* fc2w = (const float*)d_in[24];
  const float* fc2b = (const float*)d_in[25];
  const float* fc3w = (const float*)d_in[26];
  const float* fc3b = (const float*)d_in[27];
  float* out = (float*)d_out;

  char* ws = (char*)d_ws;
  size_t off = 0;
  auto alloc = [&](size_t bytes) { size_t o = off; off += (bytes + 255) & ~(size_t)255; return o; };

  // --- zero-init region ---
  size_t o_deg   = alloc((size_t)N_NODES_C * 4);
  size_t o_cur   = alloc((size_t)N_NODES_C * 4);
  size_t o_gdeg  = alloc((size_t)NUM_GRAPHS_C * 4);
  size_t o_sum1  = alloc((size_t)SH * 2 * 32 * 8);
  size_t o_sum2  = alloc((size_t)SH * 2 * 64 * 8);
  size_t o_sum3  = alloc((size_t)SH * 2 * 128 * 8);
  size_t zero_end = off;
  // --- written-before-read region ---
  size_t o_rowp  = alloc((size_t)(N_NODES_C + 1) * 4);
  size_t o_gptr  = alloc((size_t)(NUM_GRAPHS_C + 1) * 4);
  size_t o_bsum  = alloc((size_t)NB_SCAN * 4);
  size_t o_boff  = alloc((size_t)NB_SCAN * 4);
  size_t o_csr   = alloc((size_t)E_TOT * 4);
  size_t o_hb    = alloc((size_t)N_NODES_C * 128 * 2);
  size_t o_es    = alloc((size_t)N_NODES_C * 4);
  size_t o_ed    = alloc((size_t)N_NODES_C * 4);
  size_t o_agg1  = alloc((size_t)N_NODES_C * 32 * 4);
  size_t o_agg2  = alloc((size_t)N_NODES_C * 64 * 4);
  size_t o_agg3  = alloc((size_t)N_NODES_C * 128 * 4);

  hipMemsetAsync(ws, 0, zero_end, stream);

  int* deg     = (int*)(ws + o_deg);
  int* cursor  = (int*)(ws + o_cur);
  int* gdeg    = (int*)(ws + o_gdeg);
  int* rowptr  = (int*)(ws + o_rowp);
  int* gptr    = (int*)(ws + o_gptr);
  int* bsum    = (int*)(ws + o_bsum);
  int* boff    = (int*)(ws + o_boff);
  int* csr     = (int*)(ws + o_csr);
  __hip_bfloat16* hb = (__hip_bfloat16*)(ws + o_hb);
  const unsigned short* hbu = (const unsigned short*)(ws + o_hb);
  float* es    = (float*)(ws + o_es);
  float* ed    = (float*)(ws + o_ed);
  float* agg1  = (float*)(ws + o_agg1);
  float* agg2  = (float*)(ws + o_agg2);
  float* agg3  = (float*)(ws + o_agg3);
  double* sum1 = (double*)(ws + o_sum1);
  double* sum2 = (double*)(ws + o_sum2);
  double* sum3 = (double*)(ws + o_sum3);

  // CSR + graph ranges
  counts_kernel<<<(E_TOT + 255) / 256, 256, 0, stream>>>(ei, batch, deg, gdeg);
  scan_partial<<<NB_SCAN, 256, 0, stream>>>(deg, bsum, N_NODES_C);
  scan_mid<<<1, 1024, 0, stream>>>(bsum, gdeg, boff, gptr, rowptr);
  scan_final<<<NB_SCAN, 1024, 0, stream>>>(deg, boff, rowptr, N_NODES_C);
  fill_csr<<<(E_TOT + 255) / 256, 256, 0, stream>>>(ei, rowptr, cursor, csr);

  // layer 1: x(f32,no BN) -> h1(bf16) + logits; aggregate -> agg1 + sum1
  gemm_fused<128, 32, false><<<N_NODES_C / 8, 256, 0, stream>>>(
      x, W1, as1, ad1, nullptr, nullptr, nullptr, hb, es, ed);
  gat_aggregate<32><<<N_NODES_C / 4, 256, 0, stream>>>(rowptr, csr, es, ed, hbu, agg1, sum1);

  // layer 2: bn1(agg1)+lrelu -> gemm -> h2 + logits; aggregate -> agg2 + sum2
  gemm_fused<32, 64, true><<<N_NODES_C / 4, 256, 0, stream>>>(
      agg1, W2, as2, ad2, sum1, g1, be1, hb, es, ed);
  gat_aggregate<64><<<N_NODES_C / 4, 256, 0, stream>>>(rowptr, csr, es, ed, hbu, agg2, sum2);

  // layer 3
  gemm_fused<64, 128, true><<<N_NODES_C / 2, 256, 0, stream>>>(
      agg2, W3, as3, ad3, sum2, g2, be2, hb, es, ed);
  gat_aggregate<128><<<N_NODES_C / 4, 256, 0, stream>>>(rowptr, csr, es, ed, hbu, agg3, sum3);

  // pool (bn3+lrelu fused) + fc1/fc2/fc3
  poolfc_kernel<<<NUM_GRAPHS_C, 128, 0, stream>>>(agg3, gptr, sum3, g3, be3,
                                                  fc1w, fc1b, fc2w, fc2b, fc3w, fc3b, out);
}

// Round 4
// 478.328 us; speedup vs baseline: 6.4989x; 1.1236x over previous
//
#include <hip/hip_runtime.h>
#include <hip/hip_bf16.h>

#define N_NODES_C 50000
#define N_EDGES_C 800000
#define E_TOT (N_EDGES_C + N_NODES_C)
#define NUM_GRAPHS_C 1000
#define EPS_C 1e-5f
#define SCAN_TILE 1024
#define NB_SCAN ((N_NODES_C + SCAN_TILE - 1) / SCAN_TILE)  // 49
#define SH 8  // shadow copies for BN-sum atomics

static __device__ __forceinline__ float lrelu(float v, float slope) {
  return v >= 0.f ? v : slope * v;
}
static __device__ __forceinline__ float bf2f(unsigned short u) {
  return __uint_as_float((unsigned)u << 16);
}

// ---------- counts: in-degree histogram + graph histogram ----------
__global__ void counts_kernel(const int* __restrict__ ei, const int* __restrict__ batch,
                              int* __restrict__ deg, int* __restrict__ gdeg) {
  int i = blockIdx.x * 256 + threadIdx.x;
  if (i < E_TOT) {
    int d = (i < N_EDGES_C) ? ei[N_EDGES_C + i] : i - N_EDGES_C;
    atomicAdd(&deg[d], 1);
  }
  if (i < N_NODES_C) atomicAdd(&gdeg[batch[i]], 1);
}

// ---------- scan stage 1: per-tile sums ----------
__global__ void scan_partial(const int* __restrict__ in, int* __restrict__ bsum, int n) {
  __shared__ int red[256];
  int t = threadIdx.x;
  int base = blockIdx.x * SCAN_TILE;
  int s = 0;
  for (int j = t; j < SCAN_TILE; j += 256) {
    int i = base + j;
    s += (i < n) ? in[i] : 0;
  }
  red[t] = s;
  __syncthreads();
  for (int off = 128; off; off >>= 1) {
    if (t < off) red[t] += red[t + off];
    __syncthreads();
  }
  if (t == 0) bsum[blockIdx.x] = red[0];
}

// ---------- scan stage 2: scan tile sums + full graph scan ----------
__global__ void scan_mid(const int* __restrict__ bsum, const int* __restrict__ gdeg,
                         int* __restrict__ boff, int* __restrict__ gptr,
                         int* __restrict__ rowptr) {
  int t = threadIdx.x;
  int lane = t & 63;
  if (t < 64) {
    int v = (t < NB_SCAN) ? bsum[t] : 0;
    int x = v;
#pragma unroll
    for (int off = 1; off < 64; off <<= 1) {
      int y = __shfl_up(x, off, 64);
      if (lane >= off) x += y;
    }
    if (t < NB_SCAN) boff[t] = x - v;
  }
  __shared__ int wsum[16];
  int v = (t < NUM_GRAPHS_C) ? gdeg[t] : 0;
  int x = v;
#pragma unroll
  for (int off = 1; off < 64; off <<= 1) {
    int y = __shfl_up(x, off, 64);
    if (lane >= off) x += y;
  }
  int wid = t >> 6;
  if (lane == 63) wsum[wid] = x;
  __syncthreads();
  if (t < 16) {
    int w = wsum[t];
#pragma unroll
    for (int off = 1; off < 16; off <<= 1) {
      int y = __shfl_up(w, off, 64);
      if (t >= off) w += y;
    }
    wsum[t] = w;
  }
  __syncthreads();
  int excl = (wid ? wsum[wid - 1] : 0) + (x - v);
  if (t < NUM_GRAPHS_C) gptr[t] = excl;
  if (t == 0) { gptr[NUM_GRAPHS_C] = N_NODES_C; rowptr[N_NODES_C] = E_TOT; }
}

// ---------- scan stage 3: per-tile exclusive scan + tile offset ----------
__global__ void scan_final(const int* __restrict__ in, const int* __restrict__ boff,
                           int* __restrict__ out, int n) {
  __shared__ int wsum[16];
  int t = threadIdx.x;  // 1024
  int i = blockIdx.x * SCAN_TILE + t;
  int lane = t & 63, wid = t >> 6;
  int v = (i < n) ? in[i] : 0;
  int x = v;
#pragma unroll
  for (int off = 1; off < 64; off <<= 1) {
    int y = __shfl_up(x, off, 64);
    if (lane >= off) x += y;
  }
  if (lane == 63) wsum[wid] = x;
  __syncthreads();
  if (t < 16) {
    int w = wsum[t];
#pragma unroll
    for (int off = 1; off < 16; off <<= 1) {
      int y = __shfl_up(w, off, 64);
      if (t >= off) w += y;
    }
    wsum[t] = w;
  }
  __syncthreads();
  int excl = boff[blockIdx.x] + (wid ? wsum[wid - 1] : 0) + (x - v);
  if (i < n) out[i] = excl;
}

// ---------- CSR fill ----------
__global__ void fill_csr(const int* __restrict__ ei, const int* __restrict__ rowptr,
                         int* __restrict__ cursor, int* __restrict__ csr_src) {
  int i = blockIdx.x * 256 + threadIdx.x;
  if (i >= E_TOT) return;
  int s, d;
  if (i < N_EDGES_C) { s = ei[i]; d = ei[N_EDGES_C + i]; }
  else { s = d = i - N_EDGES_C; }
  int pos = rowptr[d] + atomicAdd(&cursor[d], 1);
  csr_src[pos] = s;
}

// ---------- fused GEMM: (optional BN+lrelu of input) @ W -> bf16 h + attn logits ----------
template<int CIN, int COUT, bool BN>
__global__ void gemm_fused(const float* __restrict__ x, const float* __restrict__ W,
                           const float* __restrict__ a_s, const float* __restrict__ a_d,
                           const double* __restrict__ sums, const float* __restrict__ gamma,
                           const float* __restrict__ beta,
                           __hip_bfloat16* __restrict__ hb, float* __restrict__ es,
                           float* __restrict__ ed) {
  constexpr int NPB = 256 / COUT;
  __shared__ float sW[CIN * COUT];
  __shared__ float sx[NPB * CIN];
  __shared__ float sA[COUT], sD[COUT];
  __shared__ float sbn[BN ? 2 * CIN : 1];
  __shared__ float pls[8], pld[8];
  int t = threadIdx.x;
  if (BN && t < CIN) {
    double s = 0.0, q = 0.0;
    for (int k = 0; k < SH; ++k) { s += sums[k * 2 * CIN + t]; q += sums[k * 2 * CIN + CIN + t]; }
    double mu = s / N_NODES_C;
    double var = q / N_NODES_C - mu * mu;
    float sc = gamma[t] * rsqrtf((float)var + EPS_C);
    sbn[t] = sc;
    sbn[CIN + t] = beta[t] - (float)mu * sc;
  }
  if (t < COUT) { sA[t] = a_s[t]; sD[t] = a_d[t]; }
  for (int i = t; i < CIN * COUT; i += 256) sW[i] = W[i];
  __syncthreads();
  int node0 = blockIdx.x * NPB;
  for (int i = t; i < NPB * CIN; i += 256) {
    int n = node0 + i / CIN;
    int c = i % CIN;
    float v = (n < N_NODES_C) ? x[(size_t)n * CIN + c] : 0.f;
    if (BN) v = lrelu(v * sbn[c] + sbn[CIN + c], 0.01f);
    sx[i] = v;
  }
  __syncthreads();
  int oc = t % COUT;
  int ln = t / COUT;
  int n = node0 + ln;
  float acc = 0.f;
#pragma unroll
  for (int k = 0; k < CIN; ++k) acc += sx[ln * CIN + k] * sW[k * COUT + oc];
  bool act = (n < N_NODES_C);
  if (act) hb[(size_t)n * COUT + oc] = __float2bfloat16(acc);
  float ps = acc * sA[oc], pd = acc * sD[oc];
  if constexpr (COUT <= 64) {
#pragma unroll
    for (int off = COUT / 2; off; off >>= 1) {
      ps += __shfl_xor(ps, off, 64);
      pd += __shfl_xor(pd, off, 64);
    }
    if (act && oc == 0) { es[n] = ps; ed[n] = pd; }
  } else {  // COUT == 128: node spans 2 waves
#pragma unroll
    for (int off = 32; off; off >>= 1) {
      ps += __shfl_xor(ps, off, 64);
      pd += __shfl_xor(pd, off, 64);
    }
    int lane = t & 63, wid = t >> 6;
    if (lane == 0) { pls[wid] = ps; pld[wid] = pd; }
    __syncthreads();
    if (t < NPB) {
      int n2 = node0 + t;
      if (n2 < N_NODES_C) {
        es[n2] = pls[2 * t] + pls[2 * t + 1];
        ed[n2] = pld[2 * t] + pld[2 * t + 1];
      }
    }
  }
}

// ---------- aggregate: segment softmax + bf16 weighted gather (pure, no stats) ----------
template<int C>
__global__ void gat_aggregate(const int* __restrict__ rowptr, const int* __restrict__ csr_src,
                              const float* __restrict__ es, const float* __restrict__ ed,
                              const unsigned short* __restrict__ hb, float* __restrict__ agg) {
  int node = (blockIdx.x * blockDim.x + threadIdx.x) >> 6;
  int lane = threadIdx.x & 63;
  if (node >= N_NODES_C) return;
  int r0 = rowptr[node], r1 = rowptr[node + 1];
  int deg = r1 - r0;
  float edv = ed[node];
  float acc0 = 0.f, acc1 = 0.f;
  if (deg <= 64) {
    int srcj = 0; float e = -1e30f;
    if (lane < deg) { srcj = csr_src[r0 + lane]; e = lrelu(es[srcj] + edv, 0.2f); }
    float m = e;
#pragma unroll
    for (int off = 32; off; off >>= 1) m = fmaxf(m, __shfl_xor(m, off, 64));
    float ee = (lane < deg) ? __expf(e - m) : 0.f;
    float ssum = ee;
#pragma unroll
    for (int off = 32; off; off >>= 1) ssum += __shfl_xor(ssum, off, 64);
    float alpha = ee / (ssum + 1e-16f);
#pragma unroll 4
    for (int tt = 0; tt < deg; ++tt) {
      int sj = __shfl(srcj, tt, 64);
      float al = __shfl(alpha, tt, 64);
      if constexpr (C == 128) {
        ushort2 u = *reinterpret_cast<const ushort2*>(&hb[(size_t)sj * 128 + lane * 2]);
        acc0 += al * bf2f(u.x);
        acc1 += al * bf2f(u.y);
      } else if constexpr (C == 64) {
        acc0 += al * bf2f(hb[(size_t)sj * 64 + lane]);
      } else {
        if (lane < C) acc0 += al * bf2f(hb[(size_t)sj * C + lane]);
      }
    }
  } else {
    float m = -1e30f;
    for (int j = lane; j < deg; j += 64)
      m = fmaxf(m, lrelu(es[csr_src[r0 + j]] + edv, 0.2f));
#pragma unroll
    for (int off = 32; off; off >>= 1) m = fmaxf(m, __shfl_xor(m, off, 64));
    float ssum = 0.f;
    for (int j = lane; j < deg; j += 64)
      ssum += __expf(lrelu(es[csr_src[r0 + j]] + edv, 0.2f) - m);
#pragma unroll
    for (int off = 32; off; off >>= 1) ssum += __shfl_xor(ssum, off, 64);
    float inv = 1.f / (ssum + 1e-16f);
    for (int base = 0; base < deg; base += 64) {
      int j = base + lane; int srcj = 0; float al = 0.f;
      if (j < deg) { srcj = csr_src[r0 + j]; al = __expf(lrelu(es[srcj] + edv, 0.2f) - m) * inv; }
      int cnt = min(64, deg - base);
      for (int tt = 0; tt < cnt; ++tt) {
        int sj = __shfl(srcj, tt, 64);
        float al_t = __shfl(al, tt, 64);
        if constexpr (C == 128) {
          ushort2 u = *reinterpret_cast<const ushort2*>(&hb[(size_t)sj * 128 + lane * 2]);
          acc0 += al_t * bf2f(u.x);
          acc1 += al_t * bf2f(u.y);
        } else if constexpr (C == 64) {
          acc0 += al_t * bf2f(hb[(size_t)sj * 64 + lane]);
        } else {
          if (lane < C) acc0 += al_t * bf2f(hb[(size_t)sj * C + lane]);
        }
      }
    }
  }
  if constexpr (C == 128) {
    float2 o; o.x = acc0; o.y = acc1;
    *reinterpret_cast<float2*>(&agg[(size_t)node * 128 + lane * 2]) = o;
  } else if constexpr (C == 64) {
    agg[(size_t)node * 64 + lane] = acc0;
  } else {
    if (lane < C) agg[(size_t)node * C + lane] = acc0;
  }
}

// ---------- BN stats, standalone streaming (f64, SH shadows) ----------
template<int C>
__global__ void bn_stats(const float* __restrict__ x, double* __restrict__ sums, int n_nodes) {
  constexpr int TPC = 256 / C;
  constexpr int ROWS = 128;
  int c = threadIdx.x % C;
  int rs = threadIdx.x / C;
  int r0 = blockIdx.x * ROWS;
  int rend = min(r0 + ROWS, n_nodes);
  double s = 0.0, q = 0.0;
  for (int r = r0 + rs; r < rend; r += TPC) {
    float v = x[(size_t)r * C + c];
    s += v; q += (double)v * (double)v;
  }
  __shared__ double ss[256], sq[256];
  ss[threadIdx.x] = s; sq[threadIdx.x] = q;
  __syncthreads();
#pragma unroll
  for (int off = 128; off >= C; off >>= 1) {
    if (threadIdx.x < off) {
      ss[threadIdx.x] += ss[threadIdx.x + off];
      sq[threadIdx.x] += sq[threadIdx.x + off];
    }
    __syncthreads();
  }
  if (threadIdx.x < C) {
    double* dst = sums + (size_t)(blockIdx.x & (SH - 1)) * (2 * C);
    unsafeAtomicAdd(&dst[c], ss[threadIdx.x]);
    unsafeAtomicAdd(&dst[C + c], sq[threadIdx.x]);
  }
}

// ---------- fused pool (BN3+lrelu applied) + 3 FC layers: one block per graph ----------
__global__ void poolfc_kernel(const float* __restrict__ agg3, const int* __restrict__ gptr,
                              const double* __restrict__ sums, const float* __restrict__ gamma,
                              const float* __restrict__ beta,
                              const float* __restrict__ fc1w, const float* __restrict__ fc1b,
                              const float* __restrict__ fc2w, const float* __restrict__ fc2b,
                              const float* __restrict__ fc3w, const float* __restrict__ fc3b,
                              float* __restrict__ out) {
  __shared__ float sc[128], sh[128];
  __shared__ float row[128], buf[128];
  int t = threadIdx.x;  // 128
  {
    double s = 0.0, q = 0.0;
    for (int k = 0; k < SH; ++k) { s += sums[k * 256 + t]; q += sums[k * 256 + 128 + t]; }
    double mu = s / N_NODES_C;
    double var = q / N_NODES_C - mu * mu;
    float scale = gamma[t] * rsqrtf((float)var + EPS_C);
    sc[t] = scale;
    sh[t] = beta[t] - (float)mu * scale;
  }
  __syncthreads();
  int g = blockIdx.x;
  int n0 = gptr[g], n1 = gptr[g + 1];
  float acc = 0.f;
  float scale = sc[t], shift = sh[t];
  for (int n = n0; n < n1; ++n)
    acc += lrelu(agg3[(size_t)n * 128 + t] * scale + shift, 0.01f);
  row[t] = acc;
  __syncthreads();
  {
    float s = fc1b[t];
#pragma unroll 8
    for (int k = 0; k < 128; ++k) s += row[k] * fc1w[k * 128 + t];
    buf[t] = lrelu(s, 0.01f);
  }
  __syncthreads();
  if (t < 64) {
    float s = fc2b[t];
#pragma unroll 8
    for (int k = 0; k < 128; ++k) s += buf[k] * fc2w[k * 64 + t];
    row[t] = lrelu(s, 0.01f);
  }
  __syncthreads();
  if (t < 2) {
    float s = fc3b[t];
#pragma unroll 8
    for (int k = 0; k < 64; ++k) s += row[k] * fc3w[k * 2 + t];
    out[(size_t)g * 2 + t] = lrelu(s, 0.01f);
  }
}

extern "C" void kernel_launch(void* const* d_in, const int* in_sizes, int n_in,
                              void* d_out, int out_size, void* d_ws, size_t ws_size,
                              hipStream_t stream) {
  const float* x    = (const float*)d_in[0];
  const int* ei     = (const int*)d_in[2];
  const int* batch  = (const int*)d_in[3];
  const float* W1   = (const float*)d_in[4];
  const float* as1  = (const float*)d_in[5];
  const float* ad1  = (const float*)d_in[6];
  const float* W2   = (const float*)d_in[8];
  const float* as2  = (const float*)d_in[9];
  const float* ad2  = (const float*)d_in[10];
  const float* W3   = (const float*)d_in[12];
  const float* as3  = (const float*)d_in[13];
  const float* ad3  = (const float*)d_in[14];
  const float* g1   = (const float*)d_in[16];
  const float* be1  = (const float*)d_in[17];
  const float* g2   = (const float*)d_in[18];
  const float* be2  = (const float*)d_in[19];
  const float* g3   = (const float*)d_in[20];
  const float* be3  = (const float*)d_in[21];
  const float* fc1w = (const float*)d_in[22];
  const float* fc1b = (const float*)d_in[23];
  const float* fc2w = (const float*)d_in[24];
  const float* fc2b = (const float*)d_in[25];
  const float* fc3w = (const float*)d_in[26];
  const float* fc3b = (const float*)d_in[27];
  float* out = (float*)d_out;

  char* ws = (char*)d_ws;
  size_t off = 0;
  auto alloc = [&](size_t bytes) { size_t o = off; off += (bytes + 255) & ~(size_t)255; return o; };

  // --- zero-init region ---
  size_t o_deg   = alloc((size_t)N_NODES_C * 4);
  size_t o_cur   = alloc((size_t)N_NODES_C * 4);
  size_t o_gdeg  = alloc((size_t)NUM_GRAPHS_C * 4);
  size_t o_sum1  = alloc((size_t)SH * 2 * 32 * 8);
  size_t o_sum2  = alloc((size_t)SH * 2 * 64 * 8);
  size_t o_sum3  = alloc((size_t)SH * 2 * 128 * 8);
  size_t zero_end = off;
  // --- written-before-read region ---
  size_t o_rowp  = alloc((size_t)(N_NODES_C + 1) * 4);
  size_t o_gptr  = alloc((size_t)(NUM_GRAPHS_C + 1) * 4);
  size_t o_bsum  = alloc((size_t)NB_SCAN * 4);
  size_t o_boff  = alloc((size_t)NB_SCAN * 4);
  size_t o_csr   = alloc((size_t)E_TOT * 4);
  size_t o_hb    = alloc((size_t)N_NODES_C * 128 * 2);
  size_t o_es    = alloc((size_t)N_NODES_C * 4);
  size_t o_ed    = alloc((size_t)N_NODES_C * 4);
  size_t o_agg1  = alloc((size_t)N_NODES_C * 32 * 4);
  size_t o_agg2  = alloc((size_t)N_NODES_C * 64 * 4);
  size_t o_agg3  = alloc((size_t)N_NODES_C * 128 * 4);

  hipMemsetAsync(ws, 0, zero_end, stream);

  int* deg     = (int*)(ws + o_deg);
  int* cursor  = (int*)(ws + o_cur);
  int* gdeg    = (int*)(ws + o_gdeg);
  int* rowptr  = (int*)(ws + o_rowp);
  int* gptr    = (int*)(ws + o_gptr);
  int* bsum    = (int*)(ws + o_bsum);
  int* boff    = (int*)(ws + o_boff);
  int* csr     = (int*)(ws + o_csr);
  __hip_bfloat16* hb = (__hip_bfloat16*)(ws + o_hb);
  const unsigned short* hbu = (const unsigned short*)(ws + o_hb);
  float* es    = (float*)(ws + o_es);
  float* ed    = (float*)(ws + o_ed);
  float* agg1  = (float*)(ws + o_agg1);
  float* agg2  = (float*)(ws + o_agg2);
  float* agg3  = (float*)(ws + o_agg3);
  double* sum1 = (double*)(ws + o_sum1);
  double* sum2 = (double*)(ws + o_sum2);
  double* sum3 = (double*)(ws + o_sum3);

  // CSR + graph ranges
  counts_kernel<<<(E_TOT + 255) / 256, 256, 0, stream>>>(ei, batch, deg, gdeg);
  scan_partial<<<NB_SCAN, 256, 0, stream>>>(deg, bsum, N_NODES_C);
  scan_mid<<<1, 1024, 0, stream>>>(bsum, gdeg, boff, gptr, rowptr);
  scan_final<<<NB_SCAN, 1024, 0, stream>>>(deg, boff, rowptr, N_NODES_C);
  fill_csr<<<(E_TOT + 255) / 256, 256, 0, stream>>>(ei, rowptr, cursor, csr);

  // layer 1
  gemm_fused<128, 32, false><<<N_NODES_C / 8, 256, 0, stream>>>(
      x, W1, as1, ad1, nullptr, nullptr, nullptr, hb, es, ed);
  gat_aggregate<32><<<N_NODES_C / 4, 256, 0, stream>>>(rowptr, csr, es, ed, hbu, agg1);
  bn_stats<32><<<(N_NODES_C + 127) / 128, 256, 0, stream>>>(agg1, sum1, N_NODES_C);

  // layer 2
  gemm_fused<32, 64, true><<<N_NODES_C / 4, 256, 0, stream>>>(
      agg1, W2, as2, ad2, sum1, g1, be1, hb, es, ed);
  gat_aggregate<64><<<N_NODES_C / 4, 256, 0, stream>>>(rowptr, csr, es, ed, hbu, agg2);
  bn_stats<64><<<(N_NODES_C + 127) / 128, 256, 0, stream>>>(agg2, sum2, N_NODES_C);

  // layer 3
  gemm_fused<64, 128, true><<<N_NODES_C / 2, 256, 0, stream>>>(
      agg2, W3, as3, ad3, sum2, g2, be2, hb, es, ed);
  gat_aggregate<128><<<N_NODES_C / 4, 256, 0, stream>>>(rowptr, csr, es, ed, hbu, agg3);
  bn_stats<128><<<(N_NODES_C + 127) / 128, 256, 0, stream>>>(agg3, sum3, N_NODES_C);

  // pool (bn3+lrelu fused) + fc1/fc2/fc3
  poolfc_kernel<<<NUM_GRAPHS_C, 128, 0, stream>>>(agg3, gptr, sum3, g3, be3,
                                                  fc1w, fc1b, fc2w, fc2b, fc3w, fc3b, out);
}

// Round 5
// 417.481 us; speedup vs baseline: 7.4462x; 1.1457x over previous
//
#include <hip/hip_runtime.h>
#include <hip/hip_bf16.h>

#define N_NODES_C 50000
#define N_EDGES_C 800000
#define E_TOT (N_EDGES_C + N_NODES_C)
#define NUM_GRAPHS_C 1000
#define EPS_C 1e-5f
#define SCAN_TILE 1024
#define NB_SCAN ((N_NODES_C + SCAN_TILE - 1) / SCAN_TILE)  // 49
#define SH 8       // shadow copies for BN-sum atomics
#define TILE_M 128 // nodes per GEMM block
#define KC 32      // K-chunk staged in LDS

static __device__ __forceinline__ float lrelu(float v, float slope) {
  return v >= 0.f ? v : slope * v;
}
static __device__ __forceinline__ float bf2f(unsigned short u) {
  return __uint_as_float((unsigned)u << 16);
}
static __device__ __forceinline__ unsigned short f2bf(float f) {
  __hip_bfloat16 b = __float2bfloat16(f);
  return *reinterpret_cast<unsigned short*>(&b);
}

// ---------- counts: in-degree histogram + graph histogram ----------
__global__ void counts_kernel(const int* __restrict__ ei, const int* __restrict__ batch,
                              int* __restrict__ deg, int* __restrict__ gdeg) {
  int i = blockIdx.x * 256 + threadIdx.x;
  if (i < E_TOT) {
    int d = (i < N_EDGES_C) ? ei[N_EDGES_C + i] : i - N_EDGES_C;
    atomicAdd(&deg[d], 1);
  }
  if (i < N_NODES_C) atomicAdd(&gdeg[batch[i]], 1);
}

// ---------- scan stage 1: per-tile sums ----------
__global__ void scan_partial(const int* __restrict__ in, int* __restrict__ bsum, int n) {
  __shared__ int red[256];
  int t = threadIdx.x;
  int base = blockIdx.x * SCAN_TILE;
  int s = 0;
  for (int j = t; j < SCAN_TILE; j += 256) {
    int i = base + j;
    s += (i < n) ? in[i] : 0;
  }
  red[t] = s;
  __syncthreads();
  for (int off = 128; off; off >>= 1) {
    if (t < off) red[t] += red[t + off];
    __syncthreads();
  }
  if (t == 0) bsum[blockIdx.x] = red[0];
}

// ---------- scan stage 2: scan tile sums + full graph scan ----------
__global__ void scan_mid(const int* __restrict__ bsum, const int* __restrict__ gdeg,
                         int* __restrict__ boff, int* __restrict__ gptr,
                         int* __restrict__ rowptr) {
  int t = threadIdx.x;
  int lane = t & 63;
  if (t < 64) {
    int v = (t < NB_SCAN) ? bsum[t] : 0;
    int x = v;
#pragma unroll
    for (int off = 1; off < 64; off <<= 1) {
      int y = __shfl_up(x, off, 64);
      if (lane >= off) x += y;
    }
    if (t < NB_SCAN) boff[t] = x - v;
  }
  __shared__ int wsum[16];
  int v = (t < NUM_GRAPHS_C) ? gdeg[t] : 0;
  int x = v;
#pragma unroll
  for (int off = 1; off < 64; off <<= 1) {
    int y = __shfl_up(x, off, 64);
    if (lane >= off) x += y;
  }
  int wid = t >> 6;
  if (lane == 63) wsum[wid] = x;
  __syncthreads();
  if (t < 16) {
    int w = wsum[t];
#pragma unroll
    for (int off = 1; off < 16; off <<= 1) {
      int y = __shfl_up(w, off, 64);
      if (t >= off) w += y;
    }
    wsum[t] = w;
  }
  __syncthreads();
  int excl = (wid ? wsum[wid - 1] : 0) + (x - v);
  if (t < NUM_GRAPHS_C) gptr[t] = excl;
  if (t == 0) { gptr[NUM_GRAPHS_C] = N_NODES_C; rowptr[N_NODES_C] = E_TOT; }
}

// ---------- scan stage 3: per-tile exclusive scan + tile offset ----------
__global__ void scan_final(const int* __restrict__ in, const int* __restrict__ boff,
                           int* __restrict__ out, int n) {
  __shared__ int wsum[16];
  int t = threadIdx.x;  // 1024
  int i = blockIdx.x * SCAN_TILE + t;
  int lane = t & 63, wid = t >> 6;
  int v = (i < n) ? in[i] : 0;
  int x = v;
#pragma unroll
  for (int off = 1; off < 64; off <<= 1) {
    int y = __shfl_up(x, off, 64);
    if (lane >= off) x += y;
  }
  if (lane == 63) wsum[wid] = x;
  __syncthreads();
  if (t < 16) {
    int w = wsum[t];
#pragma unroll
    for (int off = 1; off < 16; off <<= 1) {
      int y = __shfl_up(w, off, 64);
      if (t >= off) w += y;
    }
    wsum[t] = w;
  }
  __syncthreads();
  int excl = boff[blockIdx.x] + (wid ? wsum[wid - 1] : 0) + (x - v);
  if (i < n) out[i] = excl;
}

// ---------- CSR fill ----------
__global__ void fill_csr(const int* __restrict__ ei, const int* __restrict__ rowptr,
                         int* __restrict__ cursor, int* __restrict__ csr_src) {
  int i = blockIdx.x * 256 + threadIdx.x;
  if (i >= E_TOT) return;
  int s, d;
  if (i < N_EDGES_C) { s = ei[i]; d = ei[N_EDGES_C + i]; }
  else { s = d = i - N_EDGES_C; }
  int pos = rowptr[d] + atomicAdd(&cursor[d], 1);
  csr_src[pos] = s;
}

// ---------- tiled register-blocked GEMM + BN-input + bf16 h + attn logits ----------
// Thread map: og = t % OCG (oc group), ng = t / OCG (node group).
// Nn = COUT/OCG ocs per thread, Mn = TILE_M/(256/OCG) nodes per thread.
template<int CIN, int COUT, int OCG, bool BN>
__global__ __launch_bounds__(256) void gemm_tiled(
    const float* __restrict__ x, const float* __restrict__ W,
    const float* __restrict__ a_s, const float* __restrict__ a_d,
    const double* __restrict__ sums, const float* __restrict__ gamma,
    const float* __restrict__ beta,
    __hip_bfloat16* __restrict__ hb, float* __restrict__ es, float* __restrict__ ed) {
  constexpr int NG = 256 / OCG;
  constexpr int Nn = COUT / OCG;
  constexpr int Mn = TILE_M / NG;
  constexpr int XPITCH = TILE_M + 4;
  static_assert(Mn == 4 || Mn == 8, "");
  static_assert(Nn == 4 || Nn == 8, "");

  __shared__ float sW[CIN * COUT];
  __shared__ float sxT[KC * XPITCH];
  __shared__ float sA[COUT], sD[COUT];
  __shared__ float sbn[BN ? 2 * CIN : 1];

  int t = threadIdx.x;
  if (BN && t < CIN) {
    double s = 0.0, q = 0.0;
    for (int k = 0; k < SH; ++k) { s += sums[k * 2 * CIN + t]; q += sums[k * 2 * CIN + CIN + t]; }
    double mu = s / N_NODES_C;
    double var = q / N_NODES_C - mu * mu;
    float sc = gamma[t] * rsqrtf((float)var + EPS_C);
    sbn[t] = sc;
    sbn[CIN + t] = beta[t] - (float)mu * sc;
  }
  if (t < COUT) { sA[t] = a_s[t]; sD[t] = a_d[t]; }
  for (int i = t; i < CIN * COUT; i += 256) sW[i] = W[i];

  int og = t % OCG;
  int ng = t / OCG;
  int node0 = blockIdx.x * TILE_M;

  float acc[Mn][Nn];
#pragma unroll
  for (int mi = 0; mi < Mn; ++mi)
#pragma unroll
    for (int ni = 0; ni < Nn; ++ni) acc[mi][ni] = 0.f;

  for (int kc0 = 0; kc0 < CIN; kc0 += KC) {
    __syncthreads();  // protects sxT from previous chunk (and sbn/sW on first iter)
    // stage x chunk transposed: sxT[c][n]
    for (int idx = t; idx < TILE_M * KC; idx += 256) {
      int nl = idx / KC, cl = idx % KC;
      int n = node0 + nl;
      float v = (n < N_NODES_C) ? x[(size_t)n * CIN + kc0 + cl] : 0.f;
      if (BN) { int c = kc0 + cl; v = lrelu(v * sbn[c] + sbn[CIN + c], 0.01f); }
      sxT[cl * XPITCH + nl] = v;
    }
    __syncthreads();
#pragma unroll 4
    for (int k = 0; k < KC; ++k) {
      float ax[Mn], bw[Nn];
      *reinterpret_cast<float4*>(&ax[0]) =
          *reinterpret_cast<const float4*>(&sxT[k * XPITCH + ng * Mn]);
      if constexpr (Mn == 8)
        *reinterpret_cast<float4*>(&ax[4]) =
            *reinterpret_cast<const float4*>(&sxT[k * XPITCH + ng * Mn + 4]);
      *reinterpret_cast<float4*>(&bw[0]) =
          *reinterpret_cast<const float4*>(&sW[(kc0 + k) * COUT + og * Nn]);
      if constexpr (Nn == 8)
        *reinterpret_cast<float4*>(&bw[4]) =
            *reinterpret_cast<const float4*>(&sW[(kc0 + k) * COUT + og * Nn + 4]);
#pragma unroll
      for (int mi = 0; mi < Mn; ++mi)
#pragma unroll
        for (int ni = 0; ni < Nn; ++ni) acc[mi][ni] += ax[mi] * bw[ni];
    }
  }

  // epilogue: bf16 h store + attention logits (shuffle-reduced over OCG lanes)
#pragma unroll
  for (int mi = 0; mi < Mn; ++mi) {
    int n = node0 + ng * Mn + mi;
    bool act = (n < N_NODES_C);
    if (act) {
      unsigned short hv[Nn];
#pragma unroll
      for (int ni = 0; ni < Nn; ++ni) hv[ni] = f2bf(acc[mi][ni]);
      if constexpr (Nn == 4) {
        uint2 u;
        u.x = (unsigned)hv[0] | ((unsigned)hv[1] << 16);
        u.y = (unsigned)hv[2] | ((unsigned)hv[3] << 16);
        *reinterpret_cast<uint2*>(&hb[(size_t)n * COUT + og * Nn]) = u;
      } else {
        uint4 u;
        u.x = (unsigned)hv[0] | ((unsigned)hv[1] << 16);
        u.y = (unsigned)hv[2] | ((unsigned)hv[3] << 16);
        u.z = (unsigned)hv[4] | ((unsigned)hv[5] << 16);
        u.w = (unsigned)hv[6] | ((unsigned)hv[7] << 16);
        *reinterpret_cast<uint4*>(&hb[(size_t)n * COUT + og * Nn]) = u;
      }
    }
    float ps = 0.f, pd = 0.f;
#pragma unroll
    for (int ni = 0; ni < Nn; ++ni) {
      int oc = og * Nn + ni;
      ps += acc[mi][ni] * sA[oc];
      pd += acc[mi][ni] * sD[oc];
    }
#pragma unroll
    for (int off = 1; off < OCG; off <<= 1) {
      ps += __shfl_xor(ps, off, 64);
      pd += __shfl_xor(pd, off, 64);
    }
    if (act && og == 0) { es[n] = ps; ed[n] = pd; }
  }
}

// ---------- aggregate: segment softmax + bf16 weighted gather ----------
template<int C>
__global__ void gat_aggregate(const int* __restrict__ rowptr, const int* __restrict__ csr_src,
                              const float* __restrict__ es, const float* __restrict__ ed,
                              const unsigned short* __restrict__ hb, float* __restrict__ agg) {
  int node = (blockIdx.x * blockDim.x + threadIdx.x) >> 6;
  int lane = threadIdx.x & 63;
  if (node >= N_NODES_C) return;
  int r0 = rowptr[node], r1 = rowptr[node + 1];
  int deg = r1 - r0;
  float edv = ed[node];
  float acc0 = 0.f, acc1 = 0.f;
  if (deg <= 64) {
    int srcj = 0; float e = -1e30f;
    if (lane < deg) { srcj = csr_src[r0 + lane]; e = lrelu(es[srcj] + edv, 0.2f); }
    float m = e;
#pragma unroll
    for (int off = 32; off; off >>= 1) m = fmaxf(m, __shfl_xor(m, off, 64));
    float ee = (lane < deg) ? __expf(e - m) : 0.f;
    float ssum = ee;
#pragma unroll
    for (int off = 32; off; off >>= 1) ssum += __shfl_xor(ssum, off, 64);
    float alpha = ee / (ssum + 1e-16f);
#pragma unroll 4
    for (int tt = 0; tt < deg; ++tt) {
      int sj = __shfl(srcj, tt, 64);
      float al = __shfl(alpha, tt, 64);
      if constexpr (C == 128) {
        ushort2 u = *reinterpret_cast<const ushort2*>(&hb[(size_t)sj * 128 + lane * 2]);
        acc0 += al * bf2f(u.x);
        acc1 += al * bf2f(u.y);
      } else if constexpr (C == 64) {
        acc0 += al * bf2f(hb[(size_t)sj * 64 + lane]);
      } else {
        if (lane < C) acc0 += al * bf2f(hb[(size_t)sj * C + lane]);
      }
    }
  } else {
    float m = -1e30f;
    for (int j = lane; j < deg; j += 64)
      m = fmaxf(m, lrelu(es[csr_src[r0 + j]] + edv, 0.2f));
#pragma unroll
    for (int off = 32; off; off >>= 1) m = fmaxf(m, __shfl_xor(m, off, 64));
    float ssum = 0.f;
    for (int j = lane; j < deg; j += 64)
      ssum += __expf(lrelu(es[csr_src[r0 + j]] + edv, 0.2f) - m);
#pragma unroll
    for (int off = 32; off; off >>= 1) ssum += __shfl_xor(ssum, off, 64);
    float inv = 1.f / (ssum + 1e-16f);
    for (int base = 0; base < deg; base += 64) {
      int j = base + lane; int srcj = 0; float al = 0.f;
      if (j < deg) { srcj = csr_src[r0 + j]; al = __expf(lrelu(es[srcj] + edv, 0.2f) - m) * inv; }
      int cnt = min(64, deg - base);
      for (int tt = 0; tt < cnt; ++tt) {
        int sj = __shfl(srcj, tt, 64);
        float al_t = __shfl(al, tt, 64);
        if constexpr (C == 128) {
          ushort2 u = *reinterpret_cast<const ushort2*>(&hb[(size_t)sj * 128 + lane * 2]);
          acc0 += al_t * bf2f(u.x);
          acc1 += al_t * bf2f(u.y);
        } else if constexpr (C == 64) {
          acc0 += al_t * bf2f(hb[(size_t)sj * 64 + lane]);
        } else {
          if (lane < C) acc0 += al_t * bf2f(hb[(size_t)sj * C + lane]);
        }
      }
    }
  }
  if constexpr (C == 128) {
    float2 o; o.x = acc0; o.y = acc1;
    *reinterpret_cast<float2*>(&agg[(size_t)node * 128 + lane * 2]) = o;
  } else if constexpr (C == 64) {
    agg[(size_t)node * 64 + lane] = acc0;
  } else {
    if (lane < C) agg[(size_t)node * C + lane] = acc0;
  }
}

// ---------- BN stats, standalone streaming (f64, SH shadows) ----------
template<int C>
__global__ void bn_stats(const float* __restrict__ x, double* __restrict__ sums, int n_nodes) {
  constexpr int TPC = 256 / C;
  constexpr int ROWS = 128;
  int c = threadIdx.x % C;
  int rs = threadIdx.x / C;
  int r0 = blockIdx.x * ROWS;
  int rend = min(r0 + ROWS, n_nodes);
  double s = 0.0, q = 0.0;
  for (int r = r0 + rs; r < rend; r += TPC) {
    float v = x[(size_t)r * C + c];
    s += v; q += (double)v * (double)v;
  }
  __shared__ double ss[256], sq[256];
  ss[threadIdx.x] = s; sq[threadIdx.x] = q;
  __syncthreads();
#pragma unroll
  for (int off = 128; off >= C; off >>= 1) {
    if (threadIdx.x < off) {
      ss[threadIdx.x] += ss[threadIdx.x + off];
      sq[threadIdx.x] += sq[threadIdx.x + off];
    }
    __syncthreads();
  }
  if (threadIdx.x < C) {
    double* dst = sums + (size_t)(blockIdx.x & (SH - 1)) * (2 * C);
    unsafeAtomicAdd(&dst[c], ss[threadIdx.x]);
    unsafeAtomicAdd(&dst[C + c], sq[threadIdx.x]);
  }
}

// ---------- fused pool (BN3+lrelu applied) + 3 FC layers: one block per graph ----------
__global__ void poolfc_kernel(const float* __restrict__ agg3, const int* __restrict__ gptr,
                              const double* __restrict__ sums, const float* __restrict__ gamma,
                              const float* __restrict__ beta,
                              const float* __restrict__ fc1w, const float* __restrict__ fc1b,
                              const float* __restrict__ fc2w, const float* __restrict__ fc2b,
                              const float* __restrict__ fc3w, const float* __restrict__ fc3b,
                              float* __restrict__ out) {
  __shared__ float sc[128], sh[128];
  __shared__ float row[128], buf[128];
  int t = threadIdx.x;  // 128
  {
    double s = 0.0, q = 0.0;
    for (int k = 0; k < SH; ++k) { s += sums[k * 256 + t]; q += sums[k * 256 + 128 + t]; }
    double mu = s / N_NODES_C;
    double var = q / N_NODES_C - mu * mu;
    float scale = gamma[t] * rsqrtf((float)var + EPS_C);
    sc[t] = scale;
    sh[t] = beta[t] - (float)mu * scale;
  }
  __syncthreads();
  int g = blockIdx.x;
  int n0 = gptr[g], n1 = gptr[g + 1];
  float acc = 0.f;
  float scale = sc[t], shift = sh[t];
  for (int n = n0; n < n1; ++n)
    acc += lrelu(agg3[(size_t)n * 128 + t] * scale + shift, 0.01f);
  row[t] = acc;
  __syncthreads();
  {
    float s = fc1b[t];
#pragma unroll 8
    for (int k = 0; k < 128; ++k) s += row[k] * fc1w[k * 128 + t];
    buf[t] = lrelu(s, 0.01f);
  }
  __syncthreads();
  if (t < 64) {
    float s = fc2b[t];
#pragma unroll 8
    for (int k = 0; k < 128; ++k) s += buf[k] * fc2w[k * 64 + t];
    row[t] = lrelu(s, 0.01f);
  }
  __syncthreads();
  if (t < 2) {
    float s = fc3b[t];
#pragma unroll 8
    for (int k = 0; k < 64; ++k) s += row[k] * fc3w[k * 2 + t];
    out[(size_t)g * 2 + t] = lrelu(s, 0.01f);
  }
}

extern "C" void kernel_launch(void* const* d_in, const int* in_sizes, int n_in,
                              void* d_out, int out_size, void* d_ws, size_t ws_size,
                              hipStream_t stream) {
  const float* x    = (const float*)d_in[0];
  const int* ei     = (const int*)d_in[2];
  const int* batch  = (const int*)d_in[3];
  const float* W1   = (const float*)d_in[4];
  const float* as1  = (const float*)d_in[5];
  const float* ad1  = (const float*)d_in[6];
  const float* W2   = (const float*)d_in[8];
  const float* as2  = (const float*)d_in[9];
  const float* ad2  = (const float*)d_in[10];
  const float* W3   = (const float*)d_in[12];
  const float* as3  = (const float*)d_in[13];
  const float* ad3  = (const float*)d_in[14];
  const float* g1   = (const float*)d_in[16];
  const float* be1  = (const float*)d_in[17];
  const float* g2   = (const float*)d_in[18];
  const float* be2  = (const float*)d_in[19];
  const float* g3   = (const float*)d_in[20];
  const float* be3  = (const float*)d_in[21];
  const float* fc1w = (const float*)d_in[22];
  const float* fc1b = (const float*)d_in[23];
  const float* fc2w = (const float*)d_in[24];
  const float* fc2b = (const float*)d_in[25];
  const float* fc3w = (const float*)d_in[26];
  const float* fc3b = (const float*)d_in[27];
  float* out = (float*)d_out;

  char* ws = (char*)d_ws;
  size_t off = 0;
  auto alloc = [&](size_t bytes) { size_t o = off; off += (bytes + 255) & ~(size_t)255; return o; };

  // --- zero-init region ---
  size_t o_deg   = alloc((size_t)N_NODES_C * 4);
  size_t o_cur   = alloc((size_t)N_NODES_C * 4);
  size_t o_gdeg  = alloc((size_t)NUM_GRAPHS_C * 4);
  size_t o_sum1  = alloc((size_t)SH * 2 * 32 * 8);
  size_t o_sum2  = alloc((size_t)SH * 2 * 64 * 8);
  size_t o_sum3  = alloc((size_t)SH * 2 * 128 * 8);
  size_t zero_end = off;
  // --- written-before-read region ---
  size_t o_rowp  = alloc((size_t)(N_NODES_C + 1) * 4);
  size_t o_gptr  = alloc((size_t)(NUM_GRAPHS_C + 1) * 4);
  size_t o_bsum  = alloc((size_t)NB_SCAN * 4);
  size_t o_boff  = alloc((size_t)NB_SCAN * 4);
  size_t o_csr   = alloc((size_t)E_TOT * 4);
  size_t o_hb    = alloc((size_t)N_NODES_C * 128 * 2);
  size_t o_es    = alloc((size_t)N_NODES_C * 4);
  size_t o_ed    = alloc((size_t)N_NODES_C * 4);
  size_t o_agg1  = alloc((size_t)N_NODES_C * 32 * 4);
  size_t o_agg2  = alloc((size_t)N_NODES_C * 64 * 4);
  size_t o_agg3  = alloc((size_t)N_NODES_C * 128 * 4);

  hipMemsetAsync(ws, 0, zero_end, stream);

  int* deg     = (int*)(ws + o_deg);
  int* cursor  = (int*)(ws + o_cur);
  int* gdeg    = (int*)(ws + o_gdeg);
  int* rowptr  = (int*)(ws + o_rowp);
  int* gptr    = (int*)(ws + o_gptr);
  int* bsum    = (int*)(ws + o_bsum);
  int* boff    = (int*)(ws + o_boff);
  int* csr     = (int*)(ws + o_csr);
  __hip_bfloat16* hb = (__hip_bfloat16*)(ws + o_hb);
  const unsigned short* hbu = (const unsigned short*)(ws + o_hb);
  float* es    = (float*)(ws + o_es);
  float* ed    = (float*)(ws + o_ed);
  float* agg1  = (float*)(ws + o_agg1);
  float* agg2  = (float*)(ws + o_agg2);
  float* agg3  = (float*)(ws + o_agg3);
  double* sum1 = (double*)(ws + o_sum1);
  double* sum2 = (double*)(ws + o_sum2);
  double* sum3 = (double*)(ws + o_sum3);

  const int GB = (N_NODES_C + TILE_M - 1) / TILE_M;  // 391

  // CSR + graph ranges
  counts_kernel<<<(E_TOT + 255) / 256, 256, 0, stream>>>(ei, batch, deg, gdeg);
  scan_partial<<<NB_SCAN, 256, 0, stream>>>(deg, bsum, N_NODES_C);
  scan_mid<<<1, 1024, 0, stream>>>(bsum, gdeg, boff, gptr, rowptr);
  scan_final<<<NB_SCAN, 1024, 0, stream>>>(deg, boff, rowptr, N_NODES_C);
  fill_csr<<<(E_TOT + 255) / 256, 256, 0, stream>>>(ei, rowptr, cursor, csr);

  // layer 1
  gemm_tiled<128, 32, 8, false><<<GB, 256, 0, stream>>>(
      x, W1, as1, ad1, nullptr, nullptr, nullptr, hb, es, ed);
  gat_aggregate<32><<<N_NODES_C / 4, 256, 0, stream>>>(rowptr, csr, es, ed, hbu, agg1);
  bn_stats<32><<<(N_NODES_C + 127) / 128, 256, 0, stream>>>(agg1, sum1, N_NODES_C);

  // layer 2
  gemm_tiled<32, 64, 16, true><<<GB, 256, 0, stream>>>(
      agg1, W2, as2, ad2, sum1, g1, be1, hb, es, ed);
  gat_aggregate<64><<<N_NODES_C / 4, 256, 0, stream>>>(rowptr, csr, es, ed, hbu, agg2);
  bn_stats<64><<<(N_NODES_C + 127) / 128, 256, 0, stream>>>(agg2, sum2, N_NODES_C);

  // layer 3
  gemm_tiled<64, 128, 16, true><<<GB, 256, 0, stream>>>(
      agg2, W3, as3, ad3, sum2, g2, be2, hb, es, ed);
  gat_aggregate<128><<<N_NODES_C / 4, 256, 0, stream>>>(rowptr, csr, es, ed, hbu, agg3);
  bn_stats<128><<<(N_NODES_C + 127) / 128, 256, 0, stream>>>(agg3, sum3, N_NODES_C);

  // pool (bn3+lrelu fused) + fc1/fc2/fc3
  poolfc_kernel<<<NUM_GRAPHS_C, 128, 0, stream>>>(agg3, gptr, sum3, g3, be3,
                                                  fc1w, fc1b, fc2w, fc2b, fc3w, fc3b, out);
}

// Round 6
// 318.765 us; speedup vs baseline: 9.7521x; 1.3097x over previous
//
#include <hip/hip_runtime.h>
#include <hip/hip_bf16.h>

#define N_NODES_C 50000
#define N_EDGES_C 800000
#define E_TOT (N_EDGES_C + N_NODES_C)
#define NUM_GRAPHS_C 1000
#define EPS_C 1e-5f
#define SCAN_TILE 1024
#define NB_SCAN ((N_NODES_C + SCAN_TILE - 1) / SCAN_TILE)  // 49
#define SH 8       // shadow copies for BN-sum atomics
#define TILE_M 128 // nodes per GEMM block
#define KC 32      // K-chunk staged in LDS

static __device__ __forceinline__ float lrelu(float v, float slope) {
  return v >= 0.f ? v : slope * v;
}
static __device__ __forceinline__ float bf2f(unsigned short u) {
  return __uint_as_float((unsigned)u << 16);
}
static __device__ __forceinline__ unsigned short f2bf(float f) {
  __hip_bfloat16 b = __float2bfloat16(f);
  return *reinterpret_cast<unsigned short*>(&b);
}

// ---------- counts: in-degree histogram + graph histogram ----------
__global__ void counts_kernel(const int* __restrict__ ei, const int* __restrict__ batch,
                              int* __restrict__ deg, int* __restrict__ gdeg) {
  int i = blockIdx.x * 256 + threadIdx.x;
  if (i < E_TOT) {
    int d = (i < N_EDGES_C) ? ei[N_EDGES_C + i] : i - N_EDGES_C;
    atomicAdd(&deg[d], 1);
  }
  if (i < N_NODES_C) atomicAdd(&gdeg[batch[i]], 1);
}

// ---------- scan stage 1: per-tile sums ----------
__global__ void scan_partial(const int* __restrict__ in, int* __restrict__ bsum, int n) {
  __shared__ int red[256];
  int t = threadIdx.x;
  int base = blockIdx.x * SCAN_TILE;
  int s = 0;
  for (int j = t; j < SCAN_TILE; j += 256) {
    int i = base + j;
    s += (i < n) ? in[i] : 0;
  }
  red[t] = s;
  __syncthreads();
  for (int off = 128; off; off >>= 1) {
    if (t < off) red[t] += red[t + off];
    __syncthreads();
  }
  if (t == 0) bsum[blockIdx.x] = red[0];
}

// ---------- scan stage 2: scan tile sums + full graph scan ----------
__global__ void scan_mid(const int* __restrict__ bsum, const int* __restrict__ gdeg,
                         int* __restrict__ boff, int* __restrict__ gptr,
                         int* __restrict__ rowptr) {
  int t = threadIdx.x;
  int lane = t & 63;
  if (t < 64) {
    int v = (t < NB_SCAN) ? bsum[t] : 0;
    int x = v;
#pragma unroll
    for (int off = 1; off < 64; off <<= 1) {
      int y = __shfl_up(x, off, 64);
      if (lane >= off) x += y;
    }
    if (t < NB_SCAN) boff[t] = x - v;
  }
  __shared__ int wsum[16];
  int v = (t < NUM_GRAPHS_C) ? gdeg[t] : 0;
  int x = v;
#pragma unroll
  for (int off = 1; off < 64; off <<= 1) {
    int y = __shfl_up(x, off, 64);
    if (lane >= off) x += y;
  }
  int wid = t >> 6;
  if (lane == 63) wsum[wid] = x;
  __syncthreads();
  if (t < 16) {
    int w = wsum[t];
#pragma unroll
    for (int off = 1; off < 16; off <<= 1) {
      int y = __shfl_up(w, off, 64);
      if (t >= off) w += y;
    }
    wsum[t] = w;
  }
  __syncthreads();
  int excl = (wid ? wsum[wid - 1] : 0) + (x - v);
  if (t < NUM_GRAPHS_C) gptr[t] = excl;
  if (t == 0) { gptr[NUM_GRAPHS_C] = N_NODES_C; rowptr[N_NODES_C] = E_TOT; }
}

// ---------- scan stage 3: per-tile exclusive scan + tile offset ----------
__global__ void scan_final(const int* __restrict__ in, const int* __restrict__ boff,
                           int* __restrict__ out, int n) {
  __shared__ int wsum[16];
  int t = threadIdx.x;  // 1024
  int i = blockIdx.x * SCAN_TILE + t;
  int lane = t & 63, wid = t >> 6;
  int v = (i < n) ? in[i] : 0;
  int x = v;
#pragma unroll
  for (int off = 1; off < 64; off <<= 1) {
    int y = __shfl_up(x, off, 64);
    if (lane >= off) x += y;
  }
  if (lane == 63) wsum[wid] = x;
  __syncthreads();
  if (t < 16) {
    int w = wsum[t];
#pragma unroll
    for (int off = 1; off < 16; off <<= 1) {
      int y = __shfl_up(w, off, 64);
      if (t >= off) w += y;
    }
    wsum[t] = w;
  }
  __syncthreads();
  int excl = boff[blockIdx.x] + (wid ? wsum[wid - 1] : 0) + (x - v);
  if (i < n) out[i] = excl;
}

// ---------- CSR fill ----------
__global__ void fill_csr(const int* __restrict__ ei, const int* __restrict__ rowptr,
                         int* __restrict__ cursor, int* __restrict__ csr_src) {
  int i = blockIdx.x * 256 + threadIdx.x;
  if (i >= E_TOT) return;
  int s, d;
  if (i < N_EDGES_C) { s = ei[i]; d = ei[N_EDGES_C + i]; }
  else { s = d = i - N_EDGES_C; }
  int pos = rowptr[d] + atomicAdd(&cursor[d], 1);
  csr_src[pos] = s;
}

// ---------- tiled register-blocked GEMM + BN-input + bf16 h + attn logits ----------
template<int CIN, int COUT, int OCG, bool BN>
__global__ __launch_bounds__(256) void gemm_tiled(
    const float* __restrict__ x, const float* __restrict__ W,
    const float* __restrict__ a_s, const float* __restrict__ a_d,
    const double* __restrict__ sums, const float* __restrict__ gamma,
    const float* __restrict__ beta,
    __hip_bfloat16* __restrict__ hb, float* __restrict__ es, float* __restrict__ ed) {
  constexpr int NG = 256 / OCG;
  constexpr int Nn = COUT / OCG;
  constexpr int Mn = TILE_M / NG;
  constexpr int XPITCH = TILE_M + 4;
  static_assert(Mn == 4 || Mn == 8, "");
  static_assert(Nn == 4 || Nn == 8, "");

  __shared__ float sW[CIN * COUT];
  __shared__ float sxT[KC * XPITCH];
  __shared__ float sA[COUT], sD[COUT];
  __shared__ float sbn[BN ? 2 * CIN : 1];

  int t = threadIdx.x;
  if (BN && t < CIN) {
    double s = 0.0, q = 0.0;
    for (int k = 0; k < SH; ++k) { s += sums[k * 2 * CIN + t]; q += sums[k * 2 * CIN + CIN + t]; }
    double mu = s / N_NODES_C;
    double var = q / N_NODES_C - mu * mu;
    float sc = gamma[t] * rsqrtf((float)var + EPS_C);
    sbn[t] = sc;
    sbn[CIN + t] = beta[t] - (float)mu * sc;
  }
  if (t < COUT) { sA[t] = a_s[t]; sD[t] = a_d[t]; }
  for (int i = t; i < CIN * COUT; i += 256) sW[i] = W[i];

  int og = t % OCG;
  int ng = t / OCG;
  int node0 = blockIdx.x * TILE_M;

  float acc[Mn][Nn];
#pragma unroll
  for (int mi = 0; mi < Mn; ++mi)
#pragma unroll
    for (int ni = 0; ni < Nn; ++ni) acc[mi][ni] = 0.f;

  for (int kc0 = 0; kc0 < CIN; kc0 += KC) {
    __syncthreads();
    for (int idx = t; idx < TILE_M * KC; idx += 256) {
      int nl = idx / KC, cl = idx % KC;
      int n = node0 + nl;
      float v = (n < N_NODES_C) ? x[(size_t)n * CIN + kc0 + cl] : 0.f;
      if (BN) { int c = kc0 + cl; v = lrelu(v * sbn[c] + sbn[CIN + c], 0.01f); }
      sxT[cl * XPITCH + nl] = v;
    }
    __syncthreads();
#pragma unroll 4
    for (int k = 0; k < KC; ++k) {
      float ax[Mn], bw[Nn];
      *reinterpret_cast<float4*>(&ax[0]) =
          *reinterpret_cast<const float4*>(&sxT[k * XPITCH + ng * Mn]);
      if constexpr (Mn == 8)
        *reinterpret_cast<float4*>(&ax[4]) =
            *reinterpret_cast<const float4*>(&sxT[k * XPITCH + ng * Mn + 4]);
      *reinterpret_cast<float4*>(&bw[0]) =
          *reinterpret_cast<const float4*>(&sW[(kc0 + k) * COUT + og * Nn]);
      if constexpr (Nn == 8)
        *reinterpret_cast<float4*>(&bw[4]) =
            *reinterpret_cast<const float4*>(&sW[(kc0 + k) * COUT + og * Nn + 4]);
#pragma unroll
      for (int mi = 0; mi < Mn; ++mi)
#pragma unroll
        for (int ni = 0; ni < Nn; ++ni) acc[mi][ni] += ax[mi] * bw[ni];
    }
  }

#pragma unroll
  for (int mi = 0; mi < Mn; ++mi) {
    int n = node0 + ng * Mn + mi;
    bool act = (n < N_NODES_C);
    if (act) {
      unsigned short hv[Nn];
#pragma unroll
      for (int ni = 0; ni < Nn; ++ni) hv[ni] = f2bf(acc[mi][ni]);
      if constexpr (Nn == 4) {
        uint2 u;
        u.x = (unsigned)hv[0] | ((unsigned)hv[1] << 16);
        u.y = (unsigned)hv[2] | ((unsigned)hv[3] << 16);
        *reinterpret_cast<uint2*>(&hb[(size_t)n * COUT + og * Nn]) = u;
      } else {
        uint4 u;
        u.x = (unsigned)hv[0] | ((unsigned)hv[1] << 16);
        u.y = (unsigned)hv[2] | ((unsigned)hv[3] << 16);
        u.z = (unsigned)hv[4] | ((unsigned)hv[5] << 16);
        u.w = (unsigned)hv[6] | ((unsigned)hv[7] << 16);
        *reinterpret_cast<uint4*>(&hb[(size_t)n * COUT + og * Nn]) = u;
      }
    }
    float ps = 0.f, pd = 0.f;
#pragma unroll
    for (int ni = 0; ni < Nn; ++ni) {
      int oc = og * Nn + ni;
      ps += acc[mi][ni] * sA[oc];
      pd += acc[mi][ni] * sD[oc];
    }
#pragma unroll
    for (int off = 1; off < OCG; off <<= 1) {
      ps += __shfl_xor(ps, off, 64);
      pd += __shfl_xor(pd, off, 64);
    }
    if (act && og == 0) { es[n] = ps; ed[n] = pd; }
  }
}

// ---------- aggregate v2: segment softmax + MLP-pipelined multi-edge bf16 gather ----------
// Fast path (deg<=64): (byteoff,alpha) pairs staged in LDS; inner loop does one
// uniform ds_read_b64 + one ushort4 (4-channel) load per lane; EPW edges per
// wave-instruction; cross-subgroup shfl_xor reduce; float4 store.
template<int C>
__global__ void gat_aggregate(const int* __restrict__ rowptr, const int* __restrict__ csr_src,
                              const float* __restrict__ es, const float* __restrict__ ed,
                              const char* __restrict__ hb, float* __restrict__ agg) {
  constexpr int LPE = C / 4;    // lanes per edge (32/16/8)
  constexpr int EPW = 64 / LPE; // edges per wave-instruction (2/4/8)
  __shared__ uint2 sp[4][64];
  int t = threadIdx.x;
  int lane = t & 63;
  int wid = t >> 6;
  int node = (blockIdx.x * 256 + t) >> 6;
  if (node >= N_NODES_C) return;
  int r0 = rowptr[node];
  int deg = rowptr[node + 1] - r0;
  float edv = ed[node];

  if (deg <= 64) {
    int srcj = 0; float e = -1e30f;
    if (lane < deg) { srcj = csr_src[r0 + lane]; e = lrelu(es[srcj] + edv, 0.2f); }
    float m = e;
#pragma unroll
    for (int off = 32; off; off >>= 1) m = fmaxf(m, __shfl_xor(m, off, 64));
    float ee = (lane < deg) ? __expf(e - m) : 0.f;
    float ssum = ee;
#pragma unroll
    for (int off = 32; off; off >>= 1) ssum += __shfl_xor(ssum, off, 64);
    float alpha = ee / (ssum + 1e-16f);
    // stage (byte offset, alpha); padded lanes contribute alpha=0 reading row 0
    sp[wid][lane] = make_uint2((lane < deg) ? (unsigned)srcj * (C * 2) : 0u,
                               (lane < deg) ? __float_as_uint(alpha) : 0u);
    int sub = lane / LPE;       // edge slot within group
    int cl = lane % LPE;        // channel-lane: channels [cl*4, cl*4+4)
    int nit = (deg + EPW - 1) / EPW;
    float a0 = 0.f, a1 = 0.f, a2 = 0.f, a3 = 0.f;
#pragma unroll 4
    for (int j = 0; j < nit; ++j) {
      uint2 p = sp[wid][j * EPW + sub];
      float al = __uint_as_float(p.y);
      ushort4 u = *reinterpret_cast<const ushort4*>(hb + p.x + cl * 8);
      a0 += al * bf2f(u.x);
      a1 += al * bf2f(u.y);
      a2 += al * bf2f(u.z);
      a3 += al * bf2f(u.w);
    }
#pragma unroll
    for (int off = 32; off >= LPE; off >>= 1) {
      a0 += __shfl_xor(a0, off, 64);
      a1 += __shfl_xor(a1, off, 64);
      a2 += __shfl_xor(a2, off, 64);
      a3 += __shfl_xor(a3, off, 64);
    }
    if (lane < LPE) {
      float4 o; o.x = a0; o.y = a1; o.z = a2; o.w = a3;
      *reinterpret_cast<float4*>(&agg[(size_t)node * C + lane * 4]) = o;
    }
  } else {
    // general fallback (deg > 64), old per-edge broadcast structure
    const unsigned short* hbu = (const unsigned short*)hb;
    float m = -1e30f;
    for (int j = lane; j < deg; j += 64)
      m = fmaxf(m, lrelu(es[csr_src[r0 + j]] + edv, 0.2f));
#pragma unroll
    for (int off = 32; off; off >>= 1) m = fmaxf(m, __shfl_xor(m, off, 64));
    float ssum = 0.f;
    for (int j = lane; j < deg; j += 64)
      ssum += __expf(lrelu(es[csr_src[r0 + j]] + edv, 0.2f) - m);
#pragma unroll
    for (int off = 32; off; off >>= 1) ssum += __shfl_xor(ssum, off, 64);
    float inv = 1.f / (ssum + 1e-16f);
    float acc0 = 0.f, acc1 = 0.f;
    for (int base = 0; base < deg; base += 64) {
      int j = base + lane; int srcj = 0; float al = 0.f;
      if (j < deg) { srcj = csr_src[r0 + j]; al = __expf(lrelu(es[srcj] + edv, 0.2f) - m) * inv; }
      int cnt = min(64, deg - base);
      for (int tt = 0; tt < cnt; ++tt) {
        int sj = __shfl(srcj, tt, 64);
        float al_t = __shfl(al, tt, 64);
        if constexpr (C == 128) {
          ushort2 u = *reinterpret_cast<const ushort2*>(&hbu[(size_t)sj * 128 + lane * 2]);
          acc0 += al_t * bf2f(u.x);
          acc1 += al_t * bf2f(u.y);
        } else if constexpr (C == 64) {
          acc0 += al_t * bf2f(hbu[(size_t)sj * 64 + lane]);
        } else {
          if (lane < C) acc0 += al_t * bf2f(hbu[(size_t)sj * C + lane]);
        }
      }
    }
    if constexpr (C == 128) {
      float2 o; o.x = acc0; o.y = acc1;
      *reinterpret_cast<float2*>(&agg[(size_t)node * 128 + lane * 2]) = o;
    } else if constexpr (C == 64) {
      agg[(size_t)node * 64 + lane] = acc0;
    } else {
      if (lane < C) agg[(size_t)node * C + lane] = acc0;
    }
  }
}

// ---------- BN stats, standalone streaming (f64, SH shadows) ----------
template<int C>
__global__ void bn_stats(const float* __restrict__ x, double* __restrict__ sums, int n_nodes) {
  constexpr int TPC = 256 / C;
  constexpr int ROWS = 128;
  int c = threadIdx.x % C;
  int rs = threadIdx.x / C;
  int r0 = blockIdx.x * ROWS;
  int rend = min(r0 + ROWS, n_nodes);
  double s = 0.0, q = 0.0;
  for (int r = r0 + rs; r < rend; r += TPC) {
    float v = x[(size_t)r * C + c];
    s += v; q += (double)v * (double)v;
  }
  __shared__ double ss[256], sq[256];
  ss[threadIdx.x] = s; sq[threadIdx.x] = q;
  __syncthreads();
#pragma unroll
  for (int off = 128; off >= C; off >>= 1) {
    if (threadIdx.x < off) {
      ss[threadIdx.x] += ss[threadIdx.x + off];
      sq[threadIdx.x] += sq[threadIdx.x + off];
    }
    __syncthreads();
  }
  if (threadIdx.x < C) {
    double* dst = sums + (size_t)(blockIdx.x & (SH - 1)) * (2 * C);
    unsafeAtomicAdd(&dst[c], ss[threadIdx.x]);
    unsafeAtomicAdd(&dst[C + c], sq[threadIdx.x]);
  }
}

// ---------- fused pool (BN3+lrelu applied) + 3 FC layers: one block per graph ----------
__global__ void poolfc_kernel(const float* __restrict__ agg3, const int* __restrict__ gptr,
                              const double* __restrict__ sums, const float* __restrict__ gamma,
                              const float* __restrict__ beta,
                              const float* __restrict__ fc1w, const float* __restrict__ fc1b,
                              const float* __restrict__ fc2w, const float* __restrict__ fc2b,
                              const float* __restrict__ fc3w, const float* __restrict__ fc3b,
                              float* __restrict__ out) {
  __shared__ float sc[128], sh[128];
  __shared__ float row[128], buf[128];
  int t = threadIdx.x;  // 128
  {
    double s = 0.0, q = 0.0;
    for (int k = 0; k < SH; ++k) { s += sums[k * 256 + t]; q += sums[k * 256 + 128 + t]; }
    double mu = s / N_NODES_C;
    double var = q / N_NODES_C - mu * mu;
    float scale = gamma[t] * rsqrtf((float)var + EPS_C);
    sc[t] = scale;
    sh[t] = beta[t] - (float)mu * scale;
  }
  __syncthreads();
  int g = blockIdx.x;
  int n0 = gptr[g], n1 = gptr[g + 1];
  float acc = 0.f;
  float scale = sc[t], shift = sh[t];
  for (int n = n0; n < n1; ++n)
    acc += lrelu(agg3[(size_t)n * 128 + t] * scale + shift, 0.01f);
  row[t] = acc;
  __syncthreads();
  {
    float s = fc1b[t];
#pragma unroll 8
    for (int k = 0; k < 128; ++k) s += row[k] * fc1w[k * 128 + t];
    buf[t] = lrelu(s, 0.01f);
  }
  __syncthreads();
  if (t < 64) {
    float s = fc2b[t];
#pragma unroll 8
    for (int k = 0; k < 128; ++k) s += buf[k] * fc2w[k * 64 + t];
    row[t] = lrelu(s, 0.01f);
  }
  __syncthreads();
  if (t < 2) {
    float s = fc3b[t];
#pragma unroll 8
    for (int k = 0; k < 64; ++k) s += row[k] * fc3w[k * 2 + t];
    out[(size_t)g * 2 + t] = lrelu(s, 0.01f);
  }
}

extern "C" void kernel_launch(void* const* d_in, const int* in_sizes, int n_in,
                              void* d_out, int out_size, void* d_ws, size_t ws_size,
                              hipStream_t stream) {
  const float* x    = (const float*)d_in[0];
  const int* ei     = (const int*)d_in[2];
  const int* batch  = (const int*)d_in[3];
  const float* W1   = (const float*)d_in[4];
  const float* as1  = (const float*)d_in[5];
  const float* ad1  = (const float*)d_in[6];
  const float* W2   = (const float*)d_in[8];
  const float* as2  = (const float*)d_in[9];
  const float* ad2  = (const float*)d_in[10];
  const float* W3   = (const float*)d_in[12];
  const float* as3  = (const float*)d_in[13];
  const float* ad3  = (const float*)d_in[14];
  const float* g1   = (const float*)d_in[16];
  const float* be1  = (const float*)d_in[17];
  const float* g2   = (const float*)d_in[18];
  const float* be2  = (const float*)d_in[19];
  const float* g3   = (const float*)d_in[20];
  const float* be3  = (const float*)d_in[21];
  const float* fc1w = (const float*)d_in[22];
  const float* fc1b = (const float*)d_in[23];
  const float* fc2w = (const float*)d_in[24];
  const float* fc2b = (const float*)d_in[25];
  const float* fc3w = (const float*)d_in[26];
  const float* fc3b = (const float*)d_in[27];
  float* out = (float*)d_out;

  char* ws = (char*)d_ws;
  size_t off = 0;
  auto alloc = [&](size_t bytes) { size_t o = off; off += (bytes + 255) & ~(size_t)255; return o; };

  // --- zero-init region ---
  size_t o_deg   = alloc((size_t)N_NODES_C * 4);
  size_t o_cur   = alloc((size_t)N_NODES_C * 4);
  size_t o_gdeg  = alloc((size_t)NUM_GRAPHS_C * 4);
  size_t o_sum1  = alloc((size_t)SH * 2 * 32 * 8);
  size_t o_sum2  = alloc((size_t)SH * 2 * 64 * 8);
  size_t o_sum3  = alloc((size_t)SH * 2 * 128 * 8);
  size_t zero_end = off;
  // --- written-before-read region ---
  size_t o_rowp  = alloc((size_t)(N_NODES_C + 1) * 4);
  size_t o_gptr  = alloc((size_t)(NUM_GRAPHS_C + 1) * 4);
  size_t o_bsum  = alloc((size_t)NB_SCAN * 4);
  size_t o_boff  = alloc((size_t)NB_SCAN * 4);
  size_t o_csr   = alloc((size_t)E_TOT * 4);
  size_t o_hb    = alloc((size_t)N_NODES_C * 128 * 2);
  size_t o_es    = alloc((size_t)N_NODES_C * 4);
  size_t o_ed    = alloc((size_t)N_NODES_C * 4);
  size_t o_agg1  = alloc((size_t)N_NODES_C * 32 * 4);
  size_t o_agg2  = alloc((size_t)N_NODES_C * 64 * 4);
  size_t o_agg3  = alloc((size_t)N_NODES_C * 128 * 4);

  hipMemsetAsync(ws, 0, zero_end, stream);

  int* deg     = (int*)(ws + o_deg);
  int* cursor  = (int*)(ws + o_cur);
  int* gdeg    = (int*)(ws + o_gdeg);
  int* rowptr  = (int*)(ws + o_rowp);
  int* gptr    = (int*)(ws + o_gptr);
  int* bsum    = (int*)(ws + o_bsum);
  int* boff    = (int*)(ws + o_boff);
  int* csr     = (int*)(ws + o_csr);
  __hip_bfloat16* hb = (__hip_bfloat16*)(ws + o_hb);
  const char* hbc = (const char*)(ws + o_hb);
  float* es    = (float*)(ws + o_es);
  float* ed    = (float*)(ws + o_ed);
  float* agg1  = (float*)(ws + o_agg1);
  float* agg2  = (float*)(ws + o_agg2);
  float* agg3  = (float*)(ws + o_agg3);
  double* sum1 = (double*)(ws + o_sum1);
  double* sum2 = (double*)(ws + o_sum2);
  double* sum3 = (double*)(ws + o_sum3);

  const int GB = (N_NODES_C + TILE_M - 1) / TILE_M;  // 391

  // CSR + graph ranges
  counts_kernel<<<(E_TOT + 255) / 256, 256, 0, stream>>>(ei, batch, deg, gdeg);
  scan_partial<<<NB_SCAN, 256, 0, stream>>>(deg, bsum, N_NODES_C);
  scan_mid<<<1, 1024, 0, stream>>>(bsum, gdeg, boff, gptr, rowptr);
  scan_final<<<NB_SCAN, 1024, 0, stream>>>(deg, boff, rowptr, N_NODES_C);
  fill_csr<<<(E_TOT + 255) / 256, 256, 0, stream>>>(ei, rowptr, cursor, csr);

  // layer 1
  gemm_tiled<128, 32, 8, false><<<GB, 256, 0, stream>>>(
      x, W1, as1, ad1, nullptr, nullptr, nullptr, hb, es, ed);
  gat_aggregate<32><<<N_NODES_C / 4, 256, 0, stream>>>(rowptr, csr, es, ed, hbc, agg1);
  bn_stats<32><<<(N_NODES_C + 127) / 128, 256, 0, stream>>>(agg1, sum1, N_NODES_C);

  // layer 2
  gemm_tiled<32, 64, 16, true><<<GB, 256, 0, stream>>>(
      agg1, W2, as2, ad2, sum1, g1, be1, hb, es, ed);
  gat_aggregate<64><<<N_NODES_C / 4, 256, 0, stream>>>(rowptr, csr, es, ed, hbc, agg2);
  bn_stats<64><<<(N_NODES_C + 127) / 128, 256, 0, stream>>>(agg2, sum2, N_NODES_C);

  // layer 3
  gemm_tiled<64, 128, 16, true><<<GB, 256, 0, stream>>>(
      agg2, W3, as3, ad3, sum2, g2, be2, hb, es, ed);
  gat_aggregate<128><<<N_NODES_C / 4, 256, 0, stream>>>(rowptr, csr, es, ed, hbc, agg3);
  bn_stats<128><<<(N_NODES_C + 127) / 128, 256, 0, stream>>>(agg3, sum3, N_NODES_C);

  // pool (bn3+lrelu fused) + fc1/fc2/fc3
  poolfc_kernel<<<NUM_GRAPHS_C, 128, 0, stream>>>(agg3, gptr, sum3, g3, be3,
                                                  fc1w, fc1b, fc2w, fc2b, fc3w, fc3b, out);
}

// Round 7
// 260.192 us; speedup vs baseline: 11.9474x; 1.2251x over previous
//
#include <hip/hip_runtime.h>
#include <hip/hip_bf16.h>

#define N_NODES_C 50000
#define N_EDGES_C 800000
#define E_TOT (N_EDGES_C + N_NODES_C)
#define NUM_GRAPHS_C 1000
#define EPS_C 1e-5f
#define SH 8        // shadow copies for BN-sum atomics
#define TILE_M 128  // nodes per GEMM block
#define KC 32       // K-chunk staged in LDS
#define NB_BUCK ((N_NODES_C + 127) / 128)  // 391 dst-buckets of 128 nodes
#define CAPB 4096   // per-bucket capacity (mean 2176, sigma ~45 -> huge margin)
#define EPB 2048    // edges per bucket_scatter block
#define EPT 8       // edges per thread

static __device__ __forceinline__ float lrelu(float v, float slope) {
  return v >= 0.f ? v : slope * v;
}
static __device__ __forceinline__ float bf2f(unsigned short u) {
  return __uint_as_float((unsigned)u << 16);
}
static __device__ __forceinline__ unsigned short f2bf(float f) {
  __hip_bfloat16 b = __float2bfloat16(f);
  return *reinterpret_cast<unsigned short*>(&b);
}

// ---------- CSR build, stage 1: bin edges by dst>>7 with LDS histograms ----------
__global__ void bucket_scatter(const int* __restrict__ ei, const int* __restrict__ batch,
                               unsigned* __restrict__ temp, int* __restrict__ gcnt,
                               int* __restrict__ gdeg) {
  __shared__ int cnt[NB_BUCK], base[NB_BUCK];
  int t = threadIdx.x;
  for (int b = t; b < NB_BUCK; b += 256) cnt[b] = 0;
  __syncthreads();
  int e0 = blockIdx.x * EPB;
  int bks[EPT], rks[EPT];
  unsigned pks[EPT];
#pragma unroll
  for (int k = 0; k < EPT; ++k) {
    int i = e0 + k * 256 + t;
    bks[k] = -1;
    if (i < E_TOT) {
      int s, d;
      if (i < N_EDGES_C) { s = ei[i]; d = ei[N_EDGES_C + i]; }
      else { s = d = i - N_EDGES_C; }
      int b = d >> 7;
      bks[k] = b;
      pks[k] = ((unsigned)s << 7) | (unsigned)(d & 127);  // src<50000 fits 16 bits
      rks[k] = atomicAdd(&cnt[b], 1);
    }
  }
  __syncthreads();
  for (int b = t; b < NB_BUCK; b += 256) {
    int c = cnt[b];
    base[b] = c ? atomicAdd(&gcnt[b], c) : 0;
  }
  // batch histogram piggyback
  int gid = blockIdx.x * 256 + t;
  if (gid < N_NODES_C) atomicAdd(&gdeg[batch[gid]], 1);
  __syncthreads();
#pragma unroll
  for (int k = 0; k < EPT; ++k) {
    if (bks[k] >= 0)
      temp[(size_t)bks[k] * CAPB + base[bks[k]] + rks[k]] = pks[k];
  }
}

// ---------- exclusive scan helper across 1024 threads ----------
static __device__ __forceinline__ int block_excl_scan_1024(int v, int* wsum) {
  int t = threadIdx.x, lane = t & 63, wid = t >> 6;
  int x = v;
#pragma unroll
  for (int off = 1; off < 64; off <<= 1) {
    int y = __shfl_up(x, off, 64);
    if (lane >= off) x += y;
  }
  if (lane == 63) wsum[wid] = x;
  __syncthreads();
  if (t < 16) {
    int w = wsum[t];
#pragma unroll
    for (int off = 1; off < 16; off <<= 1) {
      int y = __shfl_up(w, off, 64);
      if (t >= off) w += y;
    }
    wsum[t] = w;
  }
  __syncthreads();
  return (wid ? wsum[wid - 1] : 0) + (x - v);
}

// ---------- CSR build, stage 2: scan bucket counts + graph counts ----------
__global__ void tiny_scan(const int* __restrict__ gcnt, int* __restrict__ gbase,
                          const int* __restrict__ gdeg, int* __restrict__ gptr,
                          int* __restrict__ rowptr) {
  __shared__ int wsum[16];
  int t = threadIdx.x;
  int v1 = (t < NB_BUCK) ? gcnt[t] : 0;
  int e1 = block_excl_scan_1024(v1, wsum);
  if (t < NB_BUCK) gbase[t] = e1;
  __syncthreads();
  int v2 = (t < NUM_GRAPHS_C) ? gdeg[t] : 0;
  int e2 = block_excl_scan_1024(v2, wsum);
  if (t < NUM_GRAPHS_C) gptr[t] = e2;
  if (t == 0) { gptr[NUM_GRAPHS_C] = N_NODES_C; rowptr[N_NODES_C] = E_TOT; }
}

// ---------- CSR build, stage 3: per-bucket local counting sort ----------
__global__ void bucket_build(const unsigned* __restrict__ temp, const int* __restrict__ gcnt,
                             const int* __restrict__ gbase, int* __restrict__ rowptr,
                             int* __restrict__ csr_src) {
  __shared__ int hist[128], lscan[128], cur[128];
  __shared__ int stage[CAPB];
  int b = blockIdx.x, t = threadIdx.x;
  int cnt = gcnt[b], gb = gbase[b];
  int nloc = min(128, N_NODES_C - b * 128);
  if (t < 128) hist[t] = 0;
  __syncthreads();
  const unsigned* tp = temp + (size_t)b * CAPB;
  for (int i = t; i < cnt; i += 256) atomicAdd(&hist[tp[i] & 127], 1);
  __syncthreads();
  // inclusive Hillis-Steele over 128 entries (full-block barriers)
  if (t < 128) lscan[t] = hist[t];
  __syncthreads();
  for (int off = 1; off < 128; off <<= 1) {
    int add = (t < 128 && t >= off) ? lscan[t - off] : 0;
    __syncthreads();
    if (t < 128) lscan[t] += add;
    __syncthreads();
  }
  if (t < 128) {
    int excl = lscan[t] - hist[t];
    if (t < nloc) rowptr[b * 128 + t] = gb + excl;
    hist[t] = excl;  // reuse as segment base
    cur[t] = 0;
  }
  __syncthreads();
  for (int i = t; i < cnt; i += 256) {
    unsigned w = tp[i];
    int dl = w & 127;
    int pos = hist[dl] + atomicAdd(&cur[dl], 1);
    stage[pos] = (int)(w >> 7);
  }
  __syncthreads();
  for (int i = t; i < cnt; i += 256) csr_src[gb + i] = stage[i];
}

// ---------- tiled register-blocked GEMM + BN-input + bf16 h + attn logits ----------
template<int CIN, int COUT, int OCG, bool BN>
__global__ __launch_bounds__(256) void gemm_tiled(
    const float* __restrict__ x, const float* __restrict__ W,
    const float* __restrict__ a_s, const float* __restrict__ a_d,
    const double* __restrict__ sums, const float* __restrict__ gamma,
    const float* __restrict__ beta,
    __hip_bfloat16* __restrict__ hb, float* __restrict__ es, float* __restrict__ ed) {
  constexpr int NG = 256 / OCG;
  constexpr int Nn = COUT / OCG;
  constexpr int Mn = TILE_M / NG;
  constexpr int XPITCH = TILE_M + 4;
  static_assert(Mn == 4 || Mn == 8, "");
  static_assert(Nn == 4 || Nn == 8, "");

  __shared__ float sW[CIN * COUT];
  __shared__ float sxT[KC * XPITCH];
  __shared__ float sA[COUT], sD[COUT];
  __shared__ float sbn[BN ? 2 * CIN : 1];

  int t = threadIdx.x;
  if (BN && t < CIN) {
    double s = 0.0, q = 0.0;
    for (int k = 0; k < SH; ++k) { s += sums[k * 2 * CIN + t]; q += sums[k * 2 * CIN + CIN + t]; }
    double mu = s / N_NODES_C;
    double var = q / N_NODES_C - mu * mu;
    float sc = gamma[t] * rsqrtf((float)var + EPS_C);
    sbn[t] = sc;
    sbn[CIN + t] = beta[t] - (float)mu * sc;
  }
  if (t < COUT) { sA[t] = a_s[t]; sD[t] = a_d[t]; }
  for (int i = t; i < CIN * COUT; i += 256) sW[i] = W[i];

  int og = t % OCG;
  int ng = t / OCG;
  int node0 = blockIdx.x * TILE_M;

  float acc[Mn][Nn];
#pragma unroll
  for (int mi = 0; mi < Mn; ++mi)
#pragma unroll
    for (int ni = 0; ni < Nn; ++ni) acc[mi][ni] = 0.f;

  for (int kc0 = 0; kc0 < CIN; kc0 += KC) {
    __syncthreads();
    for (int idx = t; idx < TILE_M * KC; idx += 256) {
      int nl = idx / KC, cl = idx % KC;
      int n = node0 + nl;
      float v = (n < N_NODES_C) ? x[(size_t)n * CIN + kc0 + cl] : 0.f;
      if (BN) { int c = kc0 + cl; v = lrelu(v * sbn[c] + sbn[CIN + c], 0.01f); }
      sxT[cl * XPITCH + nl] = v;
    }
    __syncthreads();
#pragma unroll 4
    for (int k = 0; k < KC; ++k) {
      float ax[Mn], bw[Nn];
      *reinterpret_cast<float4*>(&ax[0]) =
          *reinterpret_cast<const float4*>(&sxT[k * XPITCH + ng * Mn]);
      if constexpr (Mn == 8)
        *reinterpret_cast<float4*>(&ax[4]) =
            *reinterpret_cast<const float4*>(&sxT[k * XPITCH + ng * Mn + 4]);
      *reinterpret_cast<float4*>(&bw[0]) =
          *reinterpret_cast<const float4*>(&sW[(kc0 + k) * COUT + og * Nn]);
      if constexpr (Nn == 8)
        *reinterpret_cast<float4*>(&bw[4]) =
            *reinterpret_cast<const float4*>(&sW[(kc0 + k) * COUT + og * Nn + 4]);
#pragma unroll
      for (int mi = 0; mi < Mn; ++mi)
#pragma unroll
        for (int ni = 0; ni < Nn; ++ni) acc[mi][ni] += ax[mi] * bw[ni];
    }
  }

#pragma unroll
  for (int mi = 0; mi < Mn; ++mi) {
    int n = node0 + ng * Mn + mi;
    bool act = (n < N_NODES_C);
    if (act) {
      unsigned short hv[Nn];
#pragma unroll
      for (int ni = 0; ni < Nn; ++ni) hv[ni] = f2bf(acc[mi][ni]);
      if constexpr (Nn == 4) {
        uint2 u;
        u.x = (unsigned)hv[0] | ((unsigned)hv[1] << 16);
        u.y = (unsigned)hv[2] | ((unsigned)hv[3] << 16);
        *reinterpret_cast<uint2*>(&hb[(size_t)n * COUT + og * Nn]) = u;
      } else {
        uint4 u;
        u.x = (unsigned)hv[0] | ((unsigned)hv[1] << 16);
        u.y = (unsigned)hv[2] | ((unsigned)hv[3] << 16);
        u.z = (unsigned)hv[4] | ((unsigned)hv[5] << 16);
        u.w = (unsigned)hv[6] | ((unsigned)hv[7] << 16);
        *reinterpret_cast<uint4*>(&hb[(size_t)n * COUT + og * Nn]) = u;
      }
    }
    float ps = 0.f, pd = 0.f;
#pragma unroll
    for (int ni = 0; ni < Nn; ++ni) {
      int oc = og * Nn + ni;
      ps += acc[mi][ni] * sA[oc];
      pd += acc[mi][ni] * sD[oc];
    }
#pragma unroll
    for (int off = 1; off < OCG; off <<= 1) {
      ps += __shfl_xor(ps, off, 64);
      pd += __shfl_xor(pd, off, 64);
    }
    if (act && og == 0) { es[n] = ps; ed[n] = pd; }
  }
}

// ---------- aggregate: segment softmax + MLP-pipelined multi-edge bf16 gather ----------
template<int C>
__global__ void gat_aggregate(const int* __restrict__ rowptr, const int* __restrict__ csr_src,
                              const float* __restrict__ es, const float* __restrict__ ed,
                              const char* __restrict__ hb, float* __restrict__ agg) {
  constexpr int LPE = C / 4;    // lanes per edge (32/16/8)
  constexpr int EPW = 64 / LPE; // edges per wave-instruction (2/4/8)
  __shared__ uint2 sp[4][64];
  int t = threadIdx.x;
  int lane = t & 63;
  int wid = t >> 6;
  int node = (blockIdx.x * 256 + t) >> 6;
  if (node >= N_NODES_C) return;
  int r0 = rowptr[node];
  int deg = rowptr[node + 1] - r0;
  float edv = ed[node];

  if (deg <= 64) {
    int srcj = 0; float e = -1e30f;
    if (lane < deg) { srcj = csr_src[r0 + lane]; e = lrelu(es[srcj] + edv, 0.2f); }
    float m = e;
#pragma unroll
    for (int off = 32; off; off >>= 1) m = fmaxf(m, __shfl_xor(m, off, 64));
    float ee = (lane < deg) ? __expf(e - m) : 0.f;
    float ssum = ee;
#pragma unroll
    for (int off = 32; off; off >>= 1) ssum += __shfl_xor(ssum, off, 64);
    float alpha = ee / (ssum + 1e-16f);
    sp[wid][lane] = make_uint2((lane < deg) ? (unsigned)srcj * (C * 2) : 0u,
                               (lane < deg) ? __float_as_uint(alpha) : 0u);
    int sub = lane / LPE;
    int cl = lane % LPE;
    int nit = (deg + EPW - 1) / EPW;
    float a0 = 0.f, a1 = 0.f, a2 = 0.f, a3 = 0.f;
#pragma unroll 4
    for (int j = 0; j < nit; ++j) {
      uint2 p = sp[wid][j * EPW + sub];
      float al = __uint_as_float(p.y);
      ushort4 u = *reinterpret_cast<const ushort4*>(hb + p.x + cl * 8);
      a0 += al * bf2f(u.x);
      a1 += al * bf2f(u.y);
      a2 += al * bf2f(u.z);
      a3 += al * bf2f(u.w);
    }
#pragma unroll
    for (int off = 32; off >= LPE; off >>= 1) {
      a0 += __shfl_xor(a0, off, 64);
      a1 += __shfl_xor(a1, off, 64);
      a2 += __shfl_xor(a2, off, 64);
      a3 += __shfl_xor(a3, off, 64);
    }
    if (lane < LPE) {
      float4 o; o.x = a0; o.y = a1; o.z = a2; o.w = a3;
      *reinterpret_cast<float4*>(&agg[(size_t)node * C + lane * 4]) = o;
    }
  } else {
    const unsigned short* hbu = (const unsigned short*)hb;
    float m = -1e30f;
    for (int j = lane; j < deg; j += 64)
      m = fmaxf(m, lrelu(es[csr_src[r0 + j]] + edv, 0.2f));
#pragma unroll
    for (int off = 32; off; off >>= 1) m = fmaxf(m, __shfl_xor(m, off, 64));
    float ssum = 0.f;
    for (int j = lane; j < deg; j += 64)
      ssum += __expf(lrelu(es[csr_src[r0 + j]] + edv, 0.2f) - m);
#pragma unroll
    for (int off = 32; off; off >>= 1) ssum += __shfl_xor(ssum, off, 64);
    float inv = 1.f / (ssum + 1e-16f);
    float acc0 = 0.f, acc1 = 0.f;
    for (int base = 0; base < deg; base += 64) {
      int j = base + lane; int srcj = 0; float al = 0.f;
      if (j < deg) { srcj = csr_src[r0 + j]; al = __expf(lrelu(es[srcj] + edv, 0.2f) - m) * inv; }
      int cnt = min(64, deg - base);
      for (int tt = 0; tt < cnt; ++tt) {
        int sj = __shfl(srcj, tt, 64);
        float al_t = __shfl(al, tt, 64);
        if constexpr (C == 128) {
          ushort2 u = *reinterpret_cast<const ushort2*>(&hbu[(size_t)sj * 128 + lane * 2]);
          acc0 += al_t * bf2f(u.x);
          acc1 += al_t * bf2f(u.y);
        } else if constexpr (C == 64) {
          acc0 += al_t * bf2f(hbu[(size_t)sj * 64 + lane]);
        } else {
          if (lane < C) acc0 += al_t * bf2f(hbu[(size_t)sj * C + lane]);
        }
      }
    }
    if constexpr (C == 128) {
      float2 o; o.x = acc0; o.y = acc1;
      *reinterpret_cast<float2*>(&agg[(size_t)node * 128 + lane * 2]) = o;
    } else if constexpr (C == 64) {
      agg[(size_t)node * 64 + lane] = acc0;
    } else {
      if (lane < C) agg[(size_t)node * C + lane] = acc0;
    }
  }
}

// ---------- BN stats, standalone streaming (f64, SH shadows) ----------
template<int C>
__global__ void bn_stats(const float* __restrict__ x, double* __restrict__ sums, int n_nodes) {
  constexpr int TPC = 256 / C;
  constexpr int ROWS = 128;
  int c = threadIdx.x % C;
  int rs = threadIdx.x / C;
  int r0 = blockIdx.x * ROWS;
  int rend = min(r0 + ROWS, n_nodes);
  double s = 0.0, q = 0.0;
  for (int r = r0 + rs; r < rend; r += TPC) {
    float v = x[(size_t)r * C + c];
    s += v; q += (double)v * (double)v;
  }
  __shared__ double ss[256], sq[256];
  ss[threadIdx.x] = s; sq[threadIdx.x] = q;
  __syncthreads();
#pragma unroll
  for (int off = 128; off >= C; off >>= 1) {
    if (threadIdx.x < off) {
      ss[threadIdx.x] += ss[threadIdx.x + off];
      sq[threadIdx.x] += sq[threadIdx.x + off];
    }
    __syncthreads();
  }
  if (threadIdx.x < C) {
    double* dst = sums + (size_t)(blockIdx.x & (SH - 1)) * (2 * C);
    unsafeAtomicAdd(&dst[c], ss[threadIdx.x]);
    unsafeAtomicAdd(&dst[C + c], sq[threadIdx.x]);
  }
}

// ---------- fused pool (BN3+lrelu applied) + 3 FC layers: one block per graph ----------
__global__ void poolfc_kernel(const float* __restrict__ agg3, const int* __restrict__ gptr,
                              const double* __restrict__ sums, const float* __restrict__ gamma,
                              const float* __restrict__ beta,
                              const float* __restrict__ fc1w, const float* __restrict__ fc1b,
                              const float* __restrict__ fc2w, const float* __restrict__ fc2b,
                              const float* __restrict__ fc3w, const float* __restrict__ fc3b,
                              float* __restrict__ out) {
  __shared__ float sc[128], sh[128];
  __shared__ float row[128], buf[128];
  int t = threadIdx.x;  // 128
  {
    double s = 0.0, q = 0.0;
    for (int k = 0; k < SH; ++k) { s += sums[k * 256 + t]; q += sums[k * 256 + 128 + t]; }
    double mu = s / N_NODES_C;
    double var = q / N_NODES_C - mu * mu;
    float scale = gamma[t] * rsqrtf((float)var + EPS_C);
    sc[t] = scale;
    sh[t] = beta[t] - (float)mu * scale;
  }
  __syncthreads();
  int g = blockIdx.x;
  int n0 = gptr[g], n1 = gptr[g + 1];
  float acc = 0.f;
  float scale = sc[t], shift = sh[t];
  for (int n = n0; n < n1; ++n)
    acc += lrelu(agg3[(size_t)n * 128 + t] * scale + shift, 0.01f);
  row[t] = acc;
  __syncthreads();
  {
    float s = fc1b[t];
#pragma unroll 8
    for (int k = 0; k < 128; ++k) s += row[k] * fc1w[k * 128 + t];
    buf[t] = lrelu(s, 0.01f);
  }
  __syncthreads();
  if (t < 64) {
    float s = fc2b[t];
#pragma unroll 8
    for (int k = 0; k < 128; ++k) s += buf[k] * fc2w[k * 64 + t];
    row[t] = lrelu(s, 0.01f);
  }
  __syncthreads();
  if (t < 2) {
    float s = fc3b[t];
#pragma unroll 8
    for (int k = 0; k < 64; ++k) s += row[k] * fc3w[k * 2 + t];
    out[(size_t)g * 2 + t] = lrelu(s, 0.01f);
  }
}

extern "C" void kernel_launch(void* const* d_in, const int* in_sizes, int n_in,
                              void* d_out, int out_size, void* d_ws, size_t ws_size,
                              hipStream_t stream) {
  const float* x    = (const float*)d_in[0];
  const int* ei     = (const int*)d_in[2];
  const int* batch  = (const int*)d_in[3];
  const float* W1   = (const float*)d_in[4];
  const float* as1  = (const float*)d_in[5];
  const float* ad1  = (const float*)d_in[6];
  const float* W2   = (const float*)d_in[8];
  const float* as2  = (const float*)d_in[9];
  const float* ad2  = (const float*)d_in[10];
  const float* W3   = (const float*)d_in[12];
  const float* as3  = (const float*)d_in[13];
  const float* ad3  = (const float*)d_in[14];
  const float* g1   = (const float*)d_in[16];
  const float* be1  = (const float*)d_in[17];
  const float* g2   = (const float*)d_in[18];
  const float* be2  = (const float*)d_in[19];
  const float* g3   = (const float*)d_in[20];
  const float* be3  = (const float*)d_in[21];
  const float* fc1w = (const float*)d_in[22];
  const float* fc1b = (const float*)d_in[23];
  const float* fc2w = (const float*)d_in[24];
  const float* fc2b = (const float*)d_in[25];
  const float* fc3w = (const float*)d_in[26];
  const float* fc3b = (const float*)d_in[27];
  float* out = (float*)d_out;

  char* ws = (char*)d_ws;
  size_t off = 0;
  auto alloc = [&](size_t bytes) { size_t o = off; off += (bytes + 255) & ~(size_t)255; return o; };

  // --- zero-init region (small) ---
  size_t o_gcnt  = alloc((size_t)NB_BUCK * 4);
  size_t o_gdeg  = alloc((size_t)NUM_GRAPHS_C * 4);
  size_t o_sum1  = alloc((size_t)SH * 2 * 32 * 8);
  size_t o_sum2  = alloc((size_t)SH * 2 * 64 * 8);
  size_t o_sum3  = alloc((size_t)SH * 2 * 128 * 8);
  size_t zero_end = off;
  // --- written-before-read region ---
  size_t o_gbase = alloc((size_t)NB_BUCK * 4);
  size_t o_gptr  = alloc((size_t)(NUM_GRAPHS_C + 1) * 4);
  size_t o_rowp  = alloc((size_t)(N_NODES_C + 1) * 4);
  size_t o_temp  = alloc((size_t)NB_BUCK * CAPB * 4);
  size_t o_csr   = alloc((size_t)E_TOT * 4);
  size_t o_hb    = alloc((size_t)N_NODES_C * 128 * 2);
  size_t o_es    = alloc((size_t)N_NODES_C * 4);
  size_t o_ed    = alloc((size_t)N_NODES_C * 4);
  size_t o_agg1  = alloc((size_t)N_NODES_C * 32 * 4);
  size_t o_agg2  = alloc((size_t)N_NODES_C * 64 * 4);
  size_t o_agg3  = alloc((size_t)N_NODES_C * 128 * 4);

  hipMemsetAsync(ws, 0, zero_end, stream);

  int* gcnt    = (int*)(ws + o_gcnt);
  int* gdeg    = (int*)(ws + o_gdeg);
  int* gbase   = (int*)(ws + o_gbase);
  int* gptr    = (int*)(ws + o_gptr);
  int* rowptr  = (int*)(ws + o_rowp);
  unsigned* temp = (unsigned*)(ws + o_temp);
  int* csr     = (int*)(ws + o_csr);
  __hip_bfloat16* hb = (__hip_bfloat16*)(ws + o_hb);
  const char* hbc = (const char*)(ws + o_hb);
  float* es    = (float*)(ws + o_es);
  float* ed    = (float*)(ws + o_ed);
  float* agg1  = (float*)(ws + o_agg1);
  float* agg2  = (float*)(ws + o_agg2);
  float* agg3  = (float*)(ws + o_agg3);
  double* sum1 = (double*)(ws + o_sum1);
  double* sum2 = (double*)(ws + o_sum2);
  double* sum3 = (double*)(ws + o_sum3);

  const int GB = (N_NODES_C + TILE_M - 1) / TILE_M;  // 391

  // CSR + graph ranges (bucketed counting sort)
  bucket_scatter<<<(E_TOT + EPB - 1) / EPB, 256, 0, stream>>>(ei, batch, temp, gcnt, gdeg);
  tiny_scan<<<1, 1024, 0, stream>>>(gcnt, gbase, gdeg, gptr, rowptr);
  bucket_build<<<NB_BUCK, 256, 0, stream>>>(temp, gcnt, gbase, rowptr, csr);

  // layer 1
  gemm_tiled<128, 32, 8, false><<<GB, 256, 0, stream>>>(
      x, W1, as1, ad1, nullptr, nullptr, nullptr, hb, es, ed);
  gat_aggregate<32><<<N_NODES_C / 4, 256, 0, stream>>>(rowptr, csr, es, ed, hbc, agg1);
  bn_stats<32><<<(N_NODES_C + 127) / 128, 256, 0, stream>>>(agg1, sum1, N_NODES_C);

  // layer 2
  gemm_tiled<32, 64, 16, true><<<GB, 256, 0, stream>>>(
      agg1, W2, as2, ad2, sum1, g1, be1, hb, es, ed);
  gat_aggregate<64><<<N_NODES_C / 4, 256, 0, stream>>>(rowptr, csr, es, ed, hbc, agg2);
  bn_stats<64><<<(N_NODES_C + 127) / 128, 256, 0, stream>>>(agg2, sum2, N_NODES_C);

  // layer 3
  gemm_tiled<64, 128, 16, true><<<GB, 256, 0, stream>>>(
      agg2, W3, as3, ad3, sum2, g2, be2, hb, es, ed);
  gat_aggregate<128><<<N_NODES_C / 4, 256, 0, stream>>>(rowptr, csr, es, ed, hbc, agg3);
  bn_stats<128><<<(N_NODES_C + 127) / 128, 256, 0, stream>>>(agg3, sum3, N_NODES_C);

  // pool (bn3+lrelu fused) + fc1/fc2/fc3
  poolfc_kernel<<<NUM_GRAPHS_C, 128, 0, stream>>>(agg3, gptr, sum3, g3, be3,
                                                  fc1w, fc1b, fc2w, fc2b, fc3w, fc3b, out);
}

// Round 8
// 239.163 us; speedup vs baseline: 12.9980x; 1.0879x over previous
//
#include <hip/hip_runtime.h>
#include <hip/hip_bf16.h>

#define N_NODES_C 50000
#define N_EDGES_C 800000
#define E_TOT (N_EDGES_C + N_NODES_C)
#define NUM_GRAPHS_C 1000
#define EPS_C 1e-5f
#define SH 8        // shadow copies for BN-sum atomics
#define TILE_M 128  // nodes per GEMM block
#define NB_BUCK ((N_NODES_C + 127) / 128)  // 391 dst-buckets of 128 nodes
#define CAPB 4096   // per-bucket capacity
#define EPB 2048    // edges per bucket_scatter block
#define EPT 8       // edges per thread

static __device__ __forceinline__ float lrelu(float v, float slope) {
  return v >= 0.f ? v : slope * v;
}
static __device__ __forceinline__ float bf2f(unsigned short u) {
  return __uint_as_float((unsigned)u << 16);
}
static __device__ __forceinline__ unsigned short f2bf(float f) {
  __hip_bfloat16 b = __float2bfloat16(f);
  return *reinterpret_cast<unsigned short*>(&b);
}

// ---------- CSR build, stage 1: bin edges by dst>>7 with LDS histograms ----------
__global__ void bucket_scatter(const int* __restrict__ ei, const int* __restrict__ batch,
                               unsigned* __restrict__ temp, int* __restrict__ gcnt,
                               int* __restrict__ gdeg) {
  __shared__ int cnt[NB_BUCK], base[NB_BUCK];
  int t = threadIdx.x;
  for (int b = t; b < NB_BUCK; b += 256) cnt[b] = 0;
  __syncthreads();
  int e0 = blockIdx.x * EPB;
  int bks[EPT], rks[EPT];
  unsigned pks[EPT];
#pragma unroll
  for (int k = 0; k < EPT; ++k) {
    int i = e0 + k * 256 + t;
    bks[k] = -1;
    if (i < E_TOT) {
      int s, d;
      if (i < N_EDGES_C) { s = ei[i]; d = ei[N_EDGES_C + i]; }
      else { s = d = i - N_EDGES_C; }
      int b = d >> 7;
      bks[k] = b;
      pks[k] = ((unsigned)s << 7) | (unsigned)(d & 127);
      rks[k] = atomicAdd(&cnt[b], 1);
    }
  }
  __syncthreads();
  for (int b = t; b < NB_BUCK; b += 256) {
    int c = cnt[b];
    base[b] = c ? atomicAdd(&gcnt[b], c) : 0;
  }
  int gid = blockIdx.x * 256 + t;
  if (gid < N_NODES_C) atomicAdd(&gdeg[batch[gid]], 1);
  __syncthreads();
#pragma unroll
  for (int k = 0; k < EPT; ++k) {
    if (bks[k] >= 0)
      temp[(size_t)bks[k] * CAPB + base[bks[k]] + rks[k]] = pks[k];
  }
}

// ---------- exclusive scan helper across 1024 threads ----------
static __device__ __forceinline__ int block_excl_scan_1024(int v, int* wsum) {
  int t = threadIdx.x, lane = t & 63, wid = t >> 6;
  int x = v;
#pragma unroll
  for (int off = 1; off < 64; off <<= 1) {
    int y = __shfl_up(x, off, 64);
    if (lane >= off) x += y;
  }
  if (lane == 63) wsum[wid] = x;
  __syncthreads();
  if (t < 16) {
    int w = wsum[t];
#pragma unroll
    for (int off = 1; off < 16; off <<= 1) {
      int y = __shfl_up(w, off, 64);
      if (t >= off) w += y;
    }
    wsum[t] = w;
  }
  __syncthreads();
  return (wid ? wsum[wid - 1] : 0) + (x - v);
}

// ---------- CSR build, stage 2 ----------
__global__ void tiny_scan(const int* __restrict__ gcnt, int* __restrict__ gbase,
                          const int* __restrict__ gdeg, int* __restrict__ gptr,
                          int* __restrict__ rowptr) {
  __shared__ int wsum[16];
  int t = threadIdx.x;
  int v1 = (t < NB_BUCK) ? gcnt[t] : 0;
  int e1 = block_excl_scan_1024(v1, wsum);
  if (t < NB_BUCK) gbase[t] = e1;
  __syncthreads();
  int v2 = (t < NUM_GRAPHS_C) ? gdeg[t] : 0;
  int e2 = block_excl_scan_1024(v2, wsum);
  if (t < NUM_GRAPHS_C) gptr[t] = e2;
  if (t == 0) { gptr[NUM_GRAPHS_C] = N_NODES_C; rowptr[N_NODES_C] = E_TOT; }
}

// ---------- CSR build, stage 3: per-bucket local counting sort ----------
__global__ void bucket_build(const unsigned* __restrict__ temp, const int* __restrict__ gcnt,
                             const int* __restrict__ gbase, int* __restrict__ rowptr,
                             int* __restrict__ csr_src) {
  __shared__ int hist[128], lscan[128], cur[128];
  __shared__ int stage[CAPB];
  int b = blockIdx.x, t = threadIdx.x;
  int cnt = gcnt[b], gb = gbase[b];
  int nloc = min(128, N_NODES_C - b * 128);
  if (t < 128) hist[t] = 0;
  __syncthreads();
  const unsigned* tp = temp + (size_t)b * CAPB;
  for (int i = t; i < cnt; i += 256) atomicAdd(&hist[tp[i] & 127], 1);
  __syncthreads();
  if (t < 128) lscan[t] = hist[t];
  __syncthreads();
  for (int off = 1; off < 128; off <<= 1) {
    int add = (t < 128 && t >= off) ? lscan[t - off] : 0;
    __syncthreads();
    if (t < 128) lscan[t] += add;
    __syncthreads();
  }
  if (t < 128) {
    int excl = lscan[t] - hist[t];
    if (t < nloc) rowptr[b * 128 + t] = gb + excl;
    hist[t] = excl;
    cur[t] = 0;
  }
  __syncthreads();
  for (int i = t; i < cnt; i += 256) {
    unsigned w = tp[i];
    int dl = w & 127;
    int pos = hist[dl] + atomicAdd(&cur[dl], 1);
    stage[pos] = (int)(w >> 7);
  }
  __syncthreads();
  for (int i = t; i < cnt; i += 256) csr_src[gb + i] = stage[i];
}

// ---------- tiled GEMM, reg-prefetch double-buffered staging ----------
// KCT: K-chunk size; pipeline: [load regs kc+1][compute kc][write buf^1][bar]
template<int CIN, int COUT, int OCG, int KCT, bool BN>
__global__ __launch_bounds__(256) void gemm_tiled(
    const float* __restrict__ x, const float* __restrict__ W,
    const float* __restrict__ a_s, const float* __restrict__ a_d,
    const double* __restrict__ sums, const float* __restrict__ gamma,
    const float* __restrict__ beta,
    __hip_bfloat16* __restrict__ hb, float* __restrict__ es, float* __restrict__ ed) {
  constexpr int NG = 256 / OCG;
  constexpr int Nn = COUT / OCG;
  constexpr int Mn = TILE_M / NG;
  constexpr int XPITCH = TILE_M + 4;
  constexpr int NCH = CIN / KCT;
  constexpr int PFN = TILE_M * KCT / 256;   // loads per thread per chunk
  constexpr int NLS = 256 / KCT;            // node stride per j
  static_assert(Mn == 4 || Mn == 8, "");
  static_assert(Nn == 4 || Nn == 8, "");

  __shared__ float sW[CIN * COUT];
  __shared__ float sxT[2][KCT * XPITCH];
  __shared__ float sA[COUT], sD[COUT];
  __shared__ float sbn[BN ? 2 * CIN : 1];

  int t = threadIdx.x;
  if (BN && t < CIN) {
    double s = 0.0, q = 0.0;
    for (int k = 0; k < SH; ++k) { s += sums[k * 2 * CIN + t]; q += sums[k * 2 * CIN + CIN + t]; }
    double mu = s / N_NODES_C;
    double var = q / N_NODES_C - mu * mu;
    float sc = gamma[t] * rsqrtf((float)var + EPS_C);
    sbn[t] = sc;
    sbn[CIN + t] = beta[t] - (float)mu * sc;
  }
  if (t < COUT) { sA[t] = a_s[t]; sD[t] = a_d[t]; }
  // reg-batched W staging (independent loads, then writes)
  {
    constexpr int WTOT = CIN * COUT / 256;
#pragma unroll
    for (int b0 = 0; b0 < WTOT; b0 += 16) {
      constexpr int B = (WTOT < 16) ? WTOT : 16;
      float wt[B];
#pragma unroll
      for (int j = 0; j < B; ++j) wt[j] = W[(b0 + j) * 256 + t];
#pragma unroll
      for (int j = 0; j < B; ++j) sW[(b0 + j) * 256 + t] = wt[j];
    }
  }

  int og = t % OCG;
  int ng = t / OCG;
  int node0 = blockIdx.x * TILE_M;
  int cl = t % KCT;
  int nlb = t / KCT;

  float pf[PFN];
  auto load_regs = [&](int kc0) {
#pragma unroll
    for (int j = 0; j < PFN; ++j) {
      int n = node0 + nlb + NLS * j;
      pf[j] = (n < N_NODES_C) ? x[(size_t)n * CIN + kc0 + cl] : 0.f;
    }
  };
  auto write_regs = [&](float* dst, int kc0) {
    float scl = 1.f, shf = 0.f;
    if (BN) { scl = sbn[kc0 + cl]; shf = sbn[CIN + kc0 + cl]; }
#pragma unroll
    for (int j = 0; j < PFN; ++j) {
      float v = pf[j];
      if (BN) v = lrelu(v * scl + shf, 0.01f);
      dst[cl * XPITCH + nlb + NLS * j];
      dst[cl * XPITCH + nlb + NLS * j] = v;
    }
  };

  float acc[Mn][Nn];
#pragma unroll
  for (int mi = 0; mi < Mn; ++mi)
#pragma unroll
    for (int ni = 0; ni < Nn; ++ni) acc[mi][ni] = 0.f;

  load_regs(0);
  __syncthreads();  // params (sW/sbn) ready; pf independent
  write_regs(sxT[0], 0);
  __syncthreads();

  for (int c = 0; c < NCH; ++c) {
    const float* cur = sxT[c & 1];
    int kcn = (c + 1) * KCT;
    if (kcn < CIN) load_regs(kcn);  // issue early; hides under compute
#pragma unroll 4
    for (int k = 0; k < KCT; ++k) {
      float ax[Mn], bw[Nn];
      *reinterpret_cast<float4*>(&ax[0]) =
          *reinterpret_cast<const float4*>(&cur[k * XPITCH + ng * Mn]);
      if constexpr (Mn == 8)
        *reinterpret_cast<float4*>(&ax[4]) =
            *reinterpret_cast<const float4*>(&cur[k * XPITCH + ng * Mn + 4]);
      *reinterpret_cast<float4*>(&bw[0]) =
          *reinterpret_cast<const float4*>(&sW[(c * KCT + k) * COUT + og * Nn]);
      if constexpr (Nn == 8)
        *reinterpret_cast<float4*>(&bw[4]) =
            *reinterpret_cast<const float4*>(&sW[(c * KCT + k) * COUT + og * Nn + 4]);
#pragma unroll
      for (int mi = 0; mi < Mn; ++mi)
#pragma unroll
        for (int ni = 0; ni < Nn; ++ni) acc[mi][ni] += ax[mi] * bw[ni];
    }
    if (kcn < CIN) {
      write_regs((float*)sxT[(c + 1) & 1], kcn);  // other buffer; safe pre-barrier
      __syncthreads();
    }
  }

  // epilogue: bf16 h store + attention logits
#pragma unroll
  for (int mi = 0; mi < Mn; ++mi) {
    int n = node0 + ng * Mn + mi;
    bool act = (n < N_NODES_C);
    if (act) {
      unsigned short hv[Nn];
#pragma unroll
      for (int ni = 0; ni < Nn; ++ni) hv[ni] = f2bf(acc[mi][ni]);
      if constexpr (Nn == 4) {
        uint2 u;
        u.x = (unsigned)hv[0] | ((unsigned)hv[1] << 16);
        u.y = (unsigned)hv[2] | ((unsigned)hv[3] << 16);
        *reinterpret_cast<uint2*>(&hb[(size_t)n * COUT + og * Nn]) = u;
      } else {
        uint4 u;
        u.x = (unsigned)hv[0] | ((unsigned)hv[1] << 16);
        u.y = (unsigned)hv[2] | ((unsigned)hv[3] << 16);
        u.z = (unsigned)hv[4] | ((unsigned)hv[5] << 16);
        u.w = (unsigned)hv[6] | ((unsigned)hv[7] << 16);
        *reinterpret_cast<uint4*>(&hb[(size_t)n * COUT + og * Nn]) = u;
      }
    }
    float ps = 0.f, pd = 0.f;
#pragma unroll
    for (int ni = 0; ni < Nn; ++ni) {
      int oc = og * Nn + ni;
      ps += acc[mi][ni] * sA[oc];
      pd += acc[mi][ni] * sD[oc];
    }
#pragma unroll
    for (int off = 1; off < OCG; off <<= 1) {
      ps += __shfl_xor(ps, off, 64);
      pd += __shfl_xor(pd, off, 64);
    }
    if (act && og == 0) { es[n] = ps; ed[n] = pd; }
  }
}

// ---------- aggregate: segment softmax + MLP-pipelined multi-edge bf16 gather ----------
template<int C>
__global__ void gat_aggregate(const int* __restrict__ rowptr, const int* __restrict__ csr_src,
                              const float* __restrict__ es, const float* __restrict__ ed,
                              const char* __restrict__ hb, float* __restrict__ agg) {
  constexpr int LPE = C / 4;
  constexpr int EPW = 64 / LPE;
  __shared__ uint2 sp[4][64];
  int t = threadIdx.x;
  int lane = t & 63;
  int wid = t >> 6;
  int node = (blockIdx.x * 256 + t) >> 6;
  if (node >= N_NODES_C) return;
  int r0 = rowptr[node];
  int deg = rowptr[node + 1] - r0;
  float edv = ed[node];

  if (deg <= 64) {
    int srcj = 0; float e = -1e30f;
    if (lane < deg) { srcj = csr_src[r0 + lane]; e = lrelu(es[srcj] + edv, 0.2f); }
    float m = e;
#pragma unroll
    for (int off = 32; off; off >>= 1) m = fmaxf(m, __shfl_xor(m, off, 64));
    float ee = (lane < deg) ? __expf(e - m) : 0.f;
    float ssum = ee;
#pragma unroll
    for (int off = 32; off; off >>= 1) ssum += __shfl_xor(ssum, off, 64);
    float alpha = ee / (ssum + 1e-16f);
    sp[wid][lane] = make_uint2((lane < deg) ? (unsigned)srcj * (C * 2) : 0u,
                               (lane < deg) ? __float_as_uint(alpha) : 0u);
    int sub = lane / LPE;
    int cl = lane % LPE;
    int nit = (deg + EPW - 1) / EPW;
    float a0 = 0.f, a1 = 0.f, a2 = 0.f, a3 = 0.f;
#pragma unroll 4
    for (int j = 0; j < nit; ++j) {
      uint2 p = sp[wid][j * EPW + sub];
      float al = __uint_as_float(p.y);
      ushort4 u = *reinterpret_cast<const ushort4*>(hb + p.x + cl * 8);
      a0 += al * bf2f(u.x);
      a1 += al * bf2f(u.y);
      a2 += al * bf2f(u.z);
      a3 += al * bf2f(u.w);
    }
#pragma unroll
    for (int off = 32; off >= LPE; off >>= 1) {
      a0 += __shfl_xor(a0, off, 64);
      a1 += __shfl_xor(a1, off, 64);
      a2 += __shfl_xor(a2, off, 64);
      a3 += __shfl_xor(a3, off, 64);
    }
    if (lane < LPE) {
      float4 o; o.x = a0; o.y = a1; o.z = a2; o.w = a3;
      *reinterpret_cast<float4*>(&agg[(size_t)node * C + lane * 4]) = o;
    }
  } else {
    const unsigned short* hbu = (const unsigned short*)hb;
    float m = -1e30f;
    for (int j = lane; j < deg; j += 64)
      m = fmaxf(m, lrelu(es[csr_src[r0 + j]] + edv, 0.2f));
#pragma unroll
    for (int off = 32; off; off >>= 1) m = fmaxf(m, __shfl_xor(m, off, 64));
    float ssum = 0.f;
    for (int j = lane; j < deg; j += 64)
      ssum += __expf(lrelu(es[csr_src[r0 + j]] + edv, 0.2f) - m);
#pragma unroll
    for (int off = 32; off; off >>= 1) ssum += __shfl_xor(ssum, off, 64);
    float inv = 1.f / (ssum + 1e-16f);
    float acc0 = 0.f, acc1 = 0.f;
    for (int base = 0; base < deg; base += 64) {
      int j = base + lane; int srcj = 0; float al = 0.f;
      if (j < deg) { srcj = csr_src[r0 + j]; al = __expf(lrelu(es[srcj] + edv, 0.2f) - m) * inv; }
      int cnt = min(64, deg - base);
      for (int tt = 0; tt < cnt; ++tt) {
        int sj = __shfl(srcj, tt, 64);
        float al_t = __shfl(al, tt, 64);
        if constexpr (C == 128) {
          ushort2 u = *reinterpret_cast<const ushort2*>(&hbu[(size_t)sj * 128 + lane * 2]);
          acc0 += al_t * bf2f(u.x);
          acc1 += al_t * bf2f(u.y);
        } else if constexpr (C == 64) {
          acc0 += al_t * bf2f(hbu[(size_t)sj * 64 + lane]);
        } else {
          if (lane < C) acc0 += al_t * bf2f(hbu[(size_t)sj * C + lane]);
        }
      }
    }
    if constexpr (C == 128) {
      float2 o; o.x = acc0; o.y = acc1;
      *reinterpret_cast<float2*>(&agg[(size_t)node * 128 + lane * 2]) = o;
    } else if constexpr (C == 64) {
      agg[(size_t)node * 64 + lane] = acc0;
    } else {
      if (lane < C) agg[(size_t)node * C + lane] = acc0;
    }
  }
}

// ---------- BN stats ----------
template<int C>
__global__ void bn_stats(const float* __restrict__ x, double* __restrict__ sums, int n_nodes) {
  constexpr int TPC = 256 / C;
  constexpr int ROWS = 128;
  int c = threadIdx.x % C;
  int rs = threadIdx.x / C;
  int r0 = blockIdx.x * ROWS;
  int rend = min(r0 + ROWS, n_nodes);
  double s = 0.0, q = 0.0;
  for (int r = r0 + rs; r < rend; r += TPC) {
    float v = x[(size_t)r * C + c];
    s += v; q += (double)v * (double)v;
  }
  __shared__ double ss[256], sq[256];
  ss[threadIdx.x] = s; sq[threadIdx.x] = q;
  __syncthreads();
#pragma unroll
  for (int off = 128; off >= C; off >>= 1) {
    if (threadIdx.x < off) {
      ss[threadIdx.x] += ss[threadIdx.x + off];
      sq[threadIdx.x] += sq[threadIdx.x + off];
    }
    __syncthreads();
  }
  if (threadIdx.x < C) {
    double* dst = sums + (size_t)(blockIdx.x & (SH - 1)) * (2 * C);
    unsafeAtomicAdd(&dst[c], ss[threadIdx.x]);
    unsafeAtomicAdd(&dst[C + c], sq[threadIdx.x]);
  }
}

// ---------- fused pool + FC stack ----------
__global__ void poolfc_kernel(const float* __restrict__ agg3, const int* __restrict__ gptr,
                              const double* __restrict__ sums, const float* __restrict__ gamma,
                              const float* __restrict__ beta,
                              const float* __restrict__ fc1w, const float* __restrict__ fc1b,
                              const float* __restrict__ fc2w, const float* __restrict__ fc2b,
                              const float* __restrict__ fc3w, const float* __restrict__ fc3b,
                              float* __restrict__ out) {
  __shared__ float sc[128], sh[128];
  __shared__ float row[128], buf[128];
  int t = threadIdx.x;  // 128
  {
    double s = 0.0, q = 0.0;
    for (int k = 0; k < SH; ++k) { s += sums[k * 256 + t]; q += sums[k * 256 + 128 + t]; }
    double mu = s / N_NODES_C;
    double var = q / N_NODES_C - mu * mu;
    float scale = gamma[t] * rsqrtf((float)var + EPS_C);
    sc[t] = scale;
    sh[t] = beta[t] - (float)mu * scale;
  }
  __syncthreads();
  int g = blockIdx.x;
  int n0 = gptr[g], n1 = gptr[g + 1];
  float acc = 0.f;
  float scale = sc[t], shift = sh[t];
  for (int n = n0; n < n1; ++n)
    acc += lrelu(agg3[(size_t)n * 128 + t] * scale + shift, 0.01f);
  row[t] = acc;
  __syncthreads();
  {
    float s = fc1b[t];
#pragma unroll 8
    for (int k = 0; k < 128; ++k) s += row[k] * fc1w[k * 128 + t];
    buf[t] = lrelu(s, 0.01f);
  }
  __syncthreads();
  if (t < 64) {
    float s = fc2b[t];
#pragma unroll 8
    for (int k = 0; k < 128; ++k) s += buf[k] * fc2w[k * 64 + t];
    row[t] = lrelu(s, 0.01f);
  }
  __syncthreads();
  if (t < 2) {
    float s = fc3b[t];
#pragma unroll 8
    for (int k = 0; k < 64; ++k) s += row[k] * fc3w[k * 2 + t];
    out[(size_t)g * 2 + t] = lrelu(s, 0.01f);
  }
}

extern "C" void kernel_launch(void* const* d_in, const int* in_sizes, int n_in,
                              void* d_out, int out_size, void* d_ws, size_t ws_size,
                              hipStream_t stream) {
  const float* x    = (const float*)d_in[0];
  const int* ei     = (const int*)d_in[2];
  const int* batch  = (const int*)d_in[3];
  const float* W1   = (const float*)d_in[4];
  const float* as1  = (const float*)d_in[5];
  const float* ad1  = (const float*)d_in[6];
  const float* W2   = (const float*)d_in[8];
  const float* as2  = (const float*)d_in[9];
  const float* ad2  = (const float*)d_in[10];
  const float* W3   = (const float*)d_in[12];
  const float* as3  = (const float*)d_in[13];
  const float* ad3  = (const float*)d_in[14];
  const float* g1   = (const float*)d_in[16];
  const float* be1  = (const float*)d_in[17];
  const float* g2   = (const float*)d_in[18];
  const float* be2  = (const float*)d_in[19];
  const float* g3   = (const float*)d_in[20];
  const float* be3  = (const float*)d_in[21];
  const float* fc1w = (const float*)d_in[22];
  const float* fc1b = (const float*)d_in[23];
  const float* fc2w = (const float*)d_in[24];
  const float* fc2b = (const float*)d_in[25];
  const float* fc3w = (const float*)d_in[26];
  const float* fc3b = (const float*)d_in[27];
  float* out = (float*)d_out;

  char* ws = (char*)d_ws;
  size_t off = 0;
  auto alloc = [&](size_t bytes) { size_t o = off; off += (bytes + 255) & ~(size_t)255; return o; };

  // --- zero-init region (small) ---
  size_t o_gcnt  = alloc((size_t)NB_BUCK * 4);
  size_t o_gdeg  = alloc((size_t)NUM_GRAPHS_C * 4);
  size_t o_sum1  = alloc((size_t)SH * 2 * 32 * 8);
  size_t o_sum2  = alloc((size_t)SH * 2 * 64 * 8);
  size_t o_sum3  = alloc((size_t)SH * 2 * 128 * 8);
  size_t zero_end = off;
  // --- written-before-read region ---
  size_t o_gbase = alloc((size_t)NB_BUCK * 4);
  size_t o_gptr  = alloc((size_t)(NUM_GRAPHS_C + 1) * 4);
  size_t o_rowp  = alloc((size_t)(N_NODES_C + 1) * 4);
  size_t o_temp  = alloc((size_t)NB_BUCK * CAPB * 4);
  size_t o_csr   = alloc((size_t)E_TOT * 4);
  size_t o_hb    = alloc((size_t)N_NODES_C * 128 * 2);
  size_t o_es    = alloc((size_t)N_NODES_C * 4);
  size_t o_ed    = alloc((size_t)N_NODES_C * 4);
  size_t o_agg1  = alloc((size_t)N_NODES_C * 32 * 4);
  size_t o_agg2  = alloc((size_t)N_NODES_C * 64 * 4);
  size_t o_agg3  = alloc((size_t)N_NODES_C * 128 * 4);

  hipMemsetAsync(ws, 0, zero_end, stream);

  int* gcnt    = (int*)(ws + o_gcnt);
  int* gdeg    = (int*)(ws + o_gdeg);
  int* gbase   = (int*)(ws + o_gbase);
  int* gptr    = (int*)(ws + o_gptr);
  int* rowptr  = (int*)(ws + o_rowp);
  unsigned* temp = (unsigned*)(ws + o_temp);
  int* csr     = (int*)(ws + o_csr);
  __hip_bfloat16* hb = (__hip_bfloat16*)(ws + o_hb);
  const char* hbc = (const char*)(ws + o_hb);
  float* es    = (float*)(ws + o_es);
  float* ed    = (float*)(ws + o_ed);
  float* agg1  = (float*)(ws + o_agg1);
  float* agg2  = (float*)(ws + o_agg2);
  float* agg3  = (float*)(ws + o_agg3);
  double* sum1 = (double*)(ws + o_sum1);
  double* sum2 = (double*)(ws + o_sum2);
  double* sum3 = (double*)(ws + o_sum3);

  const int GB = (N_NODES_C + TILE_M - 1) / TILE_M;  // 391

  // CSR + graph ranges (bucketed counting sort)
  bucket_scatter<<<(E_TOT + EPB - 1) / EPB, 256, 0, stream>>>(ei, batch, temp, gcnt, gdeg);
  tiny_scan<<<1, 1024, 0, stream>>>(gcnt, gbase, gdeg, gptr, rowptr);
  bucket_build<<<NB_BUCK, 256, 0, stream>>>(temp, gcnt, gbase, rowptr, csr);

  // layer 1  (KC=32, 4 chunks)
  gemm_tiled<128, 32, 8, 32, false><<<GB, 256, 0, stream>>>(
      x, W1, as1, ad1, nullptr, nullptr, nullptr, hb, es, ed);
  gat_aggregate<32><<<N_NODES_C / 4, 256, 0, stream>>>(rowptr, csr, es, ed, hbc, agg1);
  bn_stats<32><<<(N_NODES_C + 127) / 128, 256, 0, stream>>>(agg1, sum1, N_NODES_C);

  // layer 2  (KC=32, 1 chunk)
  gemm_tiled<32, 64, 16, 32, true><<<GB, 256, 0, stream>>>(
      agg1, W2, as2, ad2, sum1, g1, be1, hb, es, ed);
  gat_aggregate<64><<<N_NODES_C / 4, 256, 0, stream>>>(rowptr, csr, es, ed, hbc, agg2);
  bn_stats<64><<<(N_NODES_C + 127) / 128, 256, 0, stream>>>(agg2, sum2, N_NODES_C);

  // layer 3  (KC=16, 4 chunks; keeps sW + 2*sxT under 64KB)
  gemm_tiled<64, 128, 16, 16, true><<<GB, 256, 0, stream>>>(
      agg2, W3, as3, ad3, sum2, g2, be2, hb, es, ed);
  gat_aggregate<128><<<N_NODES_C / 4, 256, 0, stream>>>(rowptr, csr, es, ed, hbc, agg3);
  bn_stats<128><<<(N_NODES_C + 127) / 128, 256, 0, stream>>>(agg3, sum3, N_NODES_C);

  // pool (bn3+lrelu fused) + fc1/fc2/fc3
  poolfc_kernel<<<NUM_GRAPHS_C, 128, 0, stream>>>(agg3, gptr, sum3, g3, be3,
                                                  fc1w, fc1b, fc2w, fc2b, fc3w, fc3b, out);
}

// Round 10
// 238.422 us; speedup vs baseline: 13.0384x; 1.0031x over previous
//
#include <hip/hip_runtime.h>
#include <hip/hip_bf16.h>

#define N_NODES_C 50000
#define N_EDGES_C 800000
#define E_TOT (N_EDGES_C + N_NODES_C)
#define NUM_GRAPHS_C 1000
#define EPS_C 1e-5f
#define SH 8        // shadow copies for BN-sum atomics
#define TILE_M 128  // nodes per GEMM block
#define NB_BUCK ((N_NODES_C + 127) / 128)  // 391 dst-buckets of 128 nodes
#define CAPB 4096   // per-bucket capacity
#define EPB 2048    // edges per bucket_scatter block
#define EPT 8       // edges per thread

static __device__ __forceinline__ float lrelu(float v, float slope) {
  return v >= 0.f ? v : slope * v;
}
static __device__ __forceinline__ float bf2f(unsigned short u) {
  return __uint_as_float((unsigned)u << 16);
}
static __device__ __forceinline__ unsigned short f2bf(float f) {
  __hip_bfloat16 b = __float2bfloat16(f);
  return *reinterpret_cast<unsigned short*>(&b);
}

// ---------- CSR build, stage 1: bin edges by dst>>7 with LDS histograms ----------
__global__ void bucket_scatter(const int* __restrict__ ei, const int* __restrict__ batch,
                               unsigned* __restrict__ temp, int* __restrict__ gcnt,
                               int* __restrict__ gdeg) {
  __shared__ int cnt[NB_BUCK], base[NB_BUCK];
  int t = threadIdx.x;
  for (int b = t; b < NB_BUCK; b += 256) cnt[b] = 0;
  __syncthreads();
  int e0 = blockIdx.x * EPB;
  int bks[EPT], rks[EPT];
  unsigned pks[EPT];
#pragma unroll
  for (int k = 0; k < EPT; ++k) {
    int i = e0 + k * 256 + t;
    bks[k] = -1;
    if (i < E_TOT) {
      int s, d;
      if (i < N_EDGES_C) { s = ei[i]; d = ei[N_EDGES_C + i]; }
      else { s = d = i - N_EDGES_C; }
      int b = d >> 7;
      bks[k] = b;
      pks[k] = ((unsigned)s << 7) | (unsigned)(d & 127);
      rks[k] = atomicAdd(&cnt[b], 1);
    }
  }
  __syncthreads();
  for (int b = t; b < NB_BUCK; b += 256) {
    int c = cnt[b];
    base[b] = c ? atomicAdd(&gcnt[b], c) : 0;
  }
  int gid = blockIdx.x * 256 + t;
  if (gid < N_NODES_C) atomicAdd(&gdeg[batch[gid]], 1);
  __syncthreads();
#pragma unroll
  for (int k = 0; k < EPT; ++k) {
    if (bks[k] >= 0)
      temp[(size_t)bks[k] * CAPB + base[bks[k]] + rks[k]] = pks[k];
  }
}

// ---------- exclusive scan helper across 1024 threads ----------
static __device__ __forceinline__ int block_excl_scan_1024(int v, int* wsum) {
  int t = threadIdx.x, lane = t & 63, wid = t >> 6;
  int x = v;
#pragma unroll
  for (int off = 1; off < 64; off <<= 1) {
    int y = __shfl_up(x, off, 64);
    if (lane >= off) x += y;
  }
  if (lane == 63) wsum[wid] = x;
  __syncthreads();
  if (t < 16) {
    int w = wsum[t];
#pragma unroll
    for (int off = 1; off < 16; off <<= 1) {
      int y = __shfl_up(w, off, 64);
      if (t >= off) w += y;
    }
    wsum[t] = w;
  }
  __syncthreads();
  return (wid ? wsum[wid - 1] : 0) + (x - v);
}

// ---------- CSR build, stage 2 ----------
__global__ void tiny_scan(const int* __restrict__ gcnt, int* __restrict__ gbase,
                          const int* __restrict__ gdeg, int* __restrict__ gptr,
                          int* __restrict__ rowptr) {
  __shared__ int wsum[16];
  int t = threadIdx.x;
  int v1 = (t < NB_BUCK) ? gcnt[t] : 0;
  int e1 = block_excl_scan_1024(v1, wsum);
  if (t < NB_BUCK) gbase[t] = e1;
  __syncthreads();
  int v2 = (t < NUM_GRAPHS_C) ? gdeg[t] : 0;
  int e2 = block_excl_scan_1024(v2, wsum);
  if (t < NUM_GRAPHS_C) gptr[t] = e2;
  if (t == 0) { gptr[NUM_GRAPHS_C] = N_NODES_C; rowptr[N_NODES_C] = E_TOT; }
}

// ---------- CSR build, stage 3: per-bucket local counting sort ----------
__global__ void bucket_build(const unsigned* __restrict__ temp, const int* __restrict__ gcnt,
                             const int* __restrict__ gbase, int* __restrict__ rowptr,
                             int* __restrict__ csr_src) {
  __shared__ int hist[128], lscan[128], cur[128];
  __shared__ int stage[CAPB];
  int b = blockIdx.x, t = threadIdx.x;
  int cnt = gcnt[b], gb = gbase[b];
  int nloc = min(128, N_NODES_C - b * 128);
  if (t < 128) hist[t] = 0;
  __syncthreads();
  const unsigned* tp = temp + (size_t)b * CAPB;
  for (int i = t; i < cnt; i += 256) atomicAdd(&hist[tp[i] & 127], 1);
  __syncthreads();
  if (t < 128) lscan[t] = hist[t];
  __syncthreads();
  for (int off = 1; off < 128; off <<= 1) {
    int add = (t < 128 && t >= off) ? lscan[t - off] : 0;
    __syncthreads();
    if (t < 128) lscan[t] += add;
    __syncthreads();
  }
  if (t < 128) {
    int excl = lscan[t] - hist[t];
    if (t < nloc) rowptr[b * 128 + t] = gb + excl;
    hist[t] = excl;
    cur[t] = 0;
  }
  __syncthreads();
  for (int i = t; i < cnt; i += 256) {
    unsigned w = tp[i];
    int dl = w & 127;
    int pos = hist[dl] + atomicAdd(&cur[dl], 1);
    stage[pos] = (int)(w >> 7);
  }
  __syncthreads();
  for (int i = t; i < cnt; i += 256) csr_src[gb + i] = stage[i];
}

// ---------- tiled GEMM, reg-prefetch double-buffered staging ----------
// KCT: K-chunk size; pipeline: [load regs kc+1][compute kc][write buf^1][bar]
template<int CIN, int COUT, int OCG, int KCT, bool BN>
__global__ __launch_bounds__(256) void gemm_tiled(
    const float* __restrict__ x, const float* __restrict__ W,
    const float* __restrict__ a_s, const float* __restrict__ a_d,
    const double* __restrict__ sums, const float* __restrict__ gamma,
    const float* __restrict__ beta,
    __hip_bfloat16* __restrict__ hb, float* __restrict__ es, float* __restrict__ ed) {
  constexpr int NG = 256 / OCG;
  constexpr int Nn = COUT / OCG;
  constexpr int Mn = TILE_M / NG;
  constexpr int XPITCH = TILE_M + 4;
  constexpr int NCH = CIN / KCT;
  constexpr int PFN = TILE_M * KCT / 256;   // loads per thread per chunk
  constexpr int NLS = 256 / KCT;            // node stride per j
  static_assert(Mn == 4 || Mn == 8, "");
  static_assert(Nn == 4 || Nn == 8, "");

  __shared__ float sW[CIN * COUT];
  __shared__ float sxT[2][KCT * XPITCH];
  __shared__ float sA[COUT], sD[COUT];
  __shared__ float sbn[BN ? 2 * CIN : 1];

  int t = threadIdx.x;
  if (BN && t < CIN) {
    double s = 0.0, q = 0.0;
    for (int k = 0; k < SH; ++k) { s += sums[k * 2 * CIN + t]; q += sums[k * 2 * CIN + CIN + t]; }
    double mu = s / N_NODES_C;
    double var = q / N_NODES_C - mu * mu;
    float sc = gamma[t] * rsqrtf((float)var + EPS_C);
    sbn[t] = sc;
    sbn[CIN + t] = beta[t] - (float)mu * sc;
  }
  if (t < COUT) { sA[t] = a_s[t]; sD[t] = a_d[t]; }
  // reg-batched W staging (independent loads, then writes)
  {
    constexpr int WTOT = CIN * COUT / 256;
#pragma unroll
    for (int b0 = 0; b0 < WTOT; b0 += 16) {
      constexpr int B = (WTOT < 16) ? WTOT : 16;
      float wt[B];
#pragma unroll
      for (int j = 0; j < B; ++j) wt[j] = W[(b0 + j) * 256 + t];
#pragma unroll
      for (int j = 0; j < B; ++j) sW[(b0 + j) * 256 + t] = wt[j];
    }
  }

  int og = t % OCG;
  int ng = t / OCG;
  int node0 = blockIdx.x * TILE_M;
  int cl = t % KCT;
  int nlb = t / KCT;

  float pf[PFN];
  auto load_regs = [&](int kc0) {
#pragma unroll
    for (int j = 0; j < PFN; ++j) {
      int n = node0 + nlb + NLS * j;
      pf[j] = (n < N_NODES_C) ? x[(size_t)n * CIN + kc0 + cl] : 0.f;
    }
  };
  auto write_regs = [&](float* dst, int kc0) {
    float scl = 1.f, shf = 0.f;
    if (BN) { scl = sbn[kc0 + cl]; shf = sbn[CIN + kc0 + cl]; }
#pragma unroll
    for (int j = 0; j < PFN; ++j) {
      float v = pf[j];
      if (BN) v = lrelu(v * scl + shf, 0.01f);
      dst[cl * XPITCH + nlb + NLS * j];
      dst[cl * XPITCH + nlb + NLS * j] = v;
    }
  };

  float acc[Mn][Nn];
#pragma unroll
  for (int mi = 0; mi < Mn; ++mi)
#pragma unroll
    for (int ni = 0; ni < Nn; ++ni) acc[mi][ni] = 0.f;

  load_regs(0);
  __syncthreads();  // params (sW/sbn) ready; pf independent
  write_regs(sxT[0], 0);
  __syncthreads();

  for (int c = 0; c < NCH; ++c) {
    const float* cur = sxT[c & 1];
    int kcn = (c + 1) * KCT;
    if (kcn < CIN) load_regs(kcn);  // issue early; hides under compute
#pragma unroll 4
    for (int k = 0; k < KCT; ++k) {
      float ax[Mn], bw[Nn];
      *reinterpret_cast<float4*>(&ax[0]) =
          *reinterpret_cast<const float4*>(&cur[k * XPITCH + ng * Mn]);
      if constexpr (Mn == 8)
        *reinterpret_cast<float4*>(&ax[4]) =
            *reinterpret_cast<const float4*>(&cur[k * XPITCH + ng * Mn + 4]);
      *reinterpret_cast<float4*>(&bw[0]) =
          *reinterpret_cast<const float4*>(&sW[(c * KCT + k) * COUT + og * Nn]);
      if constexpr (Nn == 8)
        *reinterpret_cast<float4*>(&bw[4]) =
            *reinterpret_cast<const float4*>(&sW[(c * KCT + k) * COUT + og * Nn + 4]);
#pragma unroll
      for (int mi = 0; mi < Mn; ++mi)
#pragma unroll
        for (int ni = 0; ni < Nn; ++ni) acc[mi][ni] += ax[mi] * bw[ni];
    }
    if (kcn < CIN) {
      write_regs((float*)sxT[(c + 1) & 1], kcn);  // other buffer; safe pre-barrier
      __syncthreads();
    }
  }

  // epilogue: bf16 h store + attention logits
#pragma unroll
  for (int mi = 0; mi < Mn; ++mi) {
    int n = node0 + ng * Mn + mi;
    bool act = (n < N_NODES_C);
    if (act) {
      unsigned short hv[Nn];
#pragma unroll
      for (int ni = 0; ni < Nn; ++ni) hv[ni] = f2bf(acc[mi][ni]);
      if constexpr (Nn == 4) {
        uint2 u;
        u.x = (unsigned)hv[0] | ((unsigned)hv[1] << 16);
        u.y = (unsigned)hv[2] | ((unsigned)hv[3] << 16);
        *reinterpret_cast<uint2*>(&hb[(size_t)n * COUT + og * Nn]) = u;
      } else {
        uint4 u;
        u.x = (unsigned)hv[0] | ((unsigned)hv[1] << 16);
        u.y = (unsigned)hv[2] | ((unsigned)hv[3] << 16);
        u.z = (unsigned)hv[4] | ((unsigned)hv[5] << 16);
        u.w = (unsigned)hv[6] | ((unsigned)hv[7] << 16);
        *reinterpret_cast<uint4*>(&hb[(size_t)n * COUT + og * Nn]) = u;
      }
    }
    float ps = 0.f, pd = 0.f;
#pragma unroll
    for (int ni = 0; ni < Nn; ++ni) {
      int oc = og * Nn + ni;
      ps += acc[mi][ni] * sA[oc];
      pd += acc[mi][ni] * sD[oc];
    }
#pragma unroll
    for (int off = 1; off < OCG; off <<= 1) {
      ps += __shfl_xor(ps, off, 64);
      pd += __shfl_xor(pd, off, 64);
    }
    if (act && og == 0) { es[n] = ps; ed[n] = pd; }
  }
}

// ---------- aggregate: segment softmax + MLP-pipelined multi-edge bf16 gather ----------
template<int C>
__global__ void gat_aggregate(const int* __restrict__ rowptr, const int* __restrict__ csr_src,
                              const float* __restrict__ es, const float* __restrict__ ed,
                              const char* __restrict__ hb, float* __restrict__ agg) {
  constexpr int LPE = C / 4;
  constexpr int EPW = 64 / LPE;
  __shared__ uint2 sp[4][64];
  int t = threadIdx.x;
  int lane = t & 63;
  int wid = t >> 6;
  int node = (blockIdx.x * 256 + t) >> 6;
  if (node >= N_NODES_C) return;
  int r0 = rowptr[node];
  int deg = rowptr[node + 1] - r0;
  float edv = ed[node];

  if (deg <= 64) {
    int srcj = 0; float e = -1e30f;
    if (lane < deg) { srcj = csr_src[r0 + lane]; e = lrelu(es[srcj] + edv, 0.2f); }
    float m = e;
#pragma unroll
    for (int off = 32; off; off >>= 1) m = fmaxf(m, __shfl_xor(m, off, 64));
    float ee = (lane < deg) ? __expf(e - m) : 0.f;
    float ssum = ee;
#pragma unroll
    for (int off = 32; off; off >>= 1) ssum += __shfl_xor(ssum, off, 64);
    float alpha = ee / (ssum + 1e-16f);
    sp[wid][lane] = make_uint2((lane < deg) ? (unsigned)srcj * (C * 2) : 0u,
                               (lane < deg) ? __float_as_uint(alpha) : 0u);
    int sub = lane / LPE;
    int cl = lane % LPE;
    int nit = (deg + EPW - 1) / EPW;
    float a0 = 0.f, a1 = 0.f, a2 = 0.f, a3 = 0.f;
#pragma unroll 4
    for (int j = 0; j < nit; ++j) {
      uint2 p = sp[wid][j * EPW + sub];
      float al = __uint_as_float(p.y);
      ushort4 u = *reinterpret_cast<const ushort4*>(hb + p.x + cl * 8);
      a0 += al * bf2f(u.x);
      a1 += al * bf2f(u.y);
      a2 += al * bf2f(u.z);
      a3 += al * bf2f(u.w);
    }
#pragma unroll
    for (int off = 32; off >= LPE; off >>= 1) {
      a0 += __shfl_xor(a0, off, 64);
      a1 += __shfl_xor(a1, off, 64);
      a2 += __shfl_xor(a2, off, 64);
      a3 += __shfl_xor(a3, off, 64);
    }
    if (lane < LPE) {
      float4 o; o.x = a0; o.y = a1; o.z = a2; o.w = a3;
      *reinterpret_cast<float4*>(&agg[(size_t)node * C + lane * 4]) = o;
    }
  } else {
    const unsigned short* hbu = (const unsigned short*)hb;
    float m = -1e30f;
    for (int j = lane; j < deg; j += 64)
      m = fmaxf(m, lrelu(es[csr_src[r0 + j]] + edv, 0.2f));
#pragma unroll
    for (int off = 32; off; off >>= 1) m = fmaxf(m, __shfl_xor(m, off, 64));
    float ssum = 0.f;
    for (int j = lane; j < deg; j += 64)
      ssum += __expf(lrelu(es[csr_src[r0 + j]] + edv, 0.2f) - m);
#pragma unroll
    for (int off = 32; off; off >>= 1) ssum += __shfl_xor(ssum, off, 64);
    float inv = 1.f / (ssum + 1e-16f);
    float acc0 = 0.f, acc1 = 0.f;
    for (int base = 0; base < deg; base += 64) {
      int j = base + lane; int srcj = 0; float al = 0.f;
      if (j < deg) { srcj = csr_src[r0 + j]; al = __expf(lrelu(es[srcj] + edv, 0.2f) - m) * inv; }
      int cnt = min(64, deg - base);
      for (int tt = 0; tt < cnt; ++tt) {
        int sj = __shfl(srcj, tt, 64);
        float al_t = __shfl(al, tt, 64);
        if constexpr (C == 128) {
          ushort2 u = *reinterpret_cast<const ushort2*>(&hbu[(size_t)sj * 128 + lane * 2]);
          acc0 += al_t * bf2f(u.x);
          acc1 += al_t * bf2f(u.y);
        } else if constexpr (C == 64) {
          acc0 += al_t * bf2f(hbu[(size_t)sj * 64 + lane]);
        } else {
          if (lane < C) acc0 += al_t * bf2f(hbu[(size_t)sj * C + lane]);
        }
      }
    }
    if constexpr (C == 128) {
      float2 o; o.x = acc0; o.y = acc1;
      *reinterpret_cast<float2*>(&agg[(size_t)node * 128 + lane * 2]) = o;
    } else if constexpr (C == 64) {
      agg[(size_t)node * 64 + lane] = acc0;
    } else {
      if (lane < C) agg[(size_t)node * C + lane] = acc0;
    }
  }
}

// ---------- BN stats ----------
template<int C>
__global__ void bn_stats(const float* __restrict__ x, double* __restrict__ sums, int n_nodes) {
  constexpr int TPC = 256 / C;
  constexpr int ROWS = 128;
  int c = threadIdx.x % C;
  int rs = threadIdx.x / C;
  int r0 = blockIdx.x * ROWS;
  int rend = min(r0 + ROWS, n_nodes);
  double s = 0.0, q = 0.0;
  for (int r = r0 + rs; r < rend; r += TPC) {
    float v = x[(size_t)r * C + c];
    s += v; q += (double)v * (double)v;
  }
  __shared__ double ss[256], sq[256];
  ss[threadIdx.x] = s; sq[threadIdx.x] = q;
  __syncthreads();
#pragma unroll
  for (int off = 128; off >= C; off >>= 1) {
    if (threadIdx.x < off) {
      ss[threadIdx.x] += ss[threadIdx.x + off];
      sq[threadIdx.x] += sq[threadIdx.x + off];
    }
    __syncthreads();
  }
  if (threadIdx.x < C) {
    double* dst = sums + (size_t)(blockIdx.x & (SH - 1)) * (2 * C);
    unsafeAtomicAdd(&dst[c], ss[threadIdx.x]);
    unsafeAtomicAdd(&dst[C + c], sq[threadIdx.x]);
  }
}

// ---------- fused pool + FC stack ----------
__global__ void poolfc_kernel(const float* __restrict__ agg3, const int* __restrict__ gptr,
                              const double* __restrict__ sums, const float* __restrict__ gamma,
                              const float* __restrict__ beta,
                              const float* __restrict__ fc1w, const float* __restrict__ fc1b,
                              const float* __restrict__ fc2w, const float* __restrict__ fc2b,
                              const float* __restrict__ fc3w, const float* __restrict__ fc3b,
                              float* __restrict__ out) {
  __shared__ float sc[128], sh[128];
  __shared__ float row[128], buf[128];
  int t = threadIdx.x;  // 128
  {
    double s = 0.0, q = 0.0;
    for (int k = 0; k < SH; ++k) { s += sums[k * 256 + t]; q += sums[k * 256 + 128 + t]; }
    double mu = s / N_NODES_C;
    double var = q / N_NODES_C - mu * mu;
    float scale = gamma[t] * rsqrtf((float)var + EPS_C);
    sc[t] = scale;
    sh[t] = beta[t] - (float)mu * scale;
  }
  __syncthreads();
  int g = blockIdx.x;
  int n0 = gptr[g], n1 = gptr[g + 1];
  float acc = 0.f;
  float scale = sc[t], shift = sh[t];
  for (int n = n0; n < n1; ++n)
    acc += lrelu(agg3[(size_t)n * 128 + t] * scale + shift, 0.01f);
  row[t] = acc;
  __syncthreads();
  {
    float s = fc1b[t];
#pragma unroll 8
    for (int k = 0; k < 128; ++k) s += row[k] * fc1w[k * 128 + t];
    buf[t] = lrelu(s, 0.01f);
  }
  __syncthreads();
  if (t < 64) {
    float s = fc2b[t];
#pragma unroll 8
    for (int k = 0; k < 128; ++k) s += buf[k] * fc2w[k * 64 + t];
    row[t] = lrelu(s, 0.01f);
  }
  __syncthreads();
  if (t < 2) {
    float s = fc3b[t];
#pragma unroll 8
    for (int k = 0; k < 64; ++k) s += row[k] * fc3w[k * 2 + t];
    out[(size_t)g * 2 + t] = lrelu(s, 0.01f);
  }
}

extern "C" void kernel_launch(void* const* d_in, const int* in_sizes, int n_in,
                              void* d_out, int out_size, void* d_ws, size_t ws_size,
                              hipStream_t stream) {
  const float* x    = (const float*)d_in[0];
  const int* ei     = (const int*)d_in[2];
  const int* batch  = (const int*)d_in[3];
  const float* W1   = (const float*)d_in[4];
  const float* as1  = (const float*)d_in[5];
  const float* ad1  = (const float*)d_in[6];
  const float* W2   = (const float*)d_in[8];
  const float* as2  = (const float*)d_in[9];
  const float* ad2  = (const float*)d_in[10];
  const float* W3   = (const float*)d_in[12];
  const float* as3  = (const float*)d_in[13];
  const float* ad3  = (const float*)d_in[14];
  const float* g1   = (const float*)d_in[16];
  const float* be1  = (const float*)d_in[17];
  const float* g2   = (const float*)d_in[18];
  const float* be2  = (const float*)d_in[19];
  const float* g3   = (const float*)d_in[20];
  const float* be3  = (const float*)d_in[21];
  const float* fc1w = (const float*)d_in[22];
  const float* fc1b = (const float*)d_in[23];
  const float* fc2w = (const float*)d_in[24];
  const float* fc2b = (const float*)d_in[25];
  const float* fc3w = (const float*)d_in[26];
  const float* fc3b = (const float*)d_in[27];
  float* out = (float*)d_out;

  char* ws = (char*)d_ws;
  size_t off = 0;
  auto alloc = [&](size_t bytes) { size_t o = off; off += (bytes + 255) & ~(size_t)255; return o; };

  // --- zero-init region (small) ---
  size_t o_gcnt  = alloc((size_t)NB_BUCK * 4);
  size_t o_gdeg  = alloc((size_t)NUM_GRAPHS_C * 4);
  size_t o_sum1  = alloc((size_t)SH * 2 * 32 * 8);
  size_t o_sum2  = alloc((size_t)SH * 2 * 64 * 8);
  size_t o_sum3  = alloc((size_t)SH * 2 * 128 * 8);
  size_t zero_end = off;
  // --- written-before-read region ---
  size_t o_gbase = alloc((size_t)NB_BUCK * 4);
  size_t o_gptr  = alloc((size_t)(NUM_GRAPHS_C + 1) * 4);
  size_t o_rowp  = alloc((size_t)(N_NODES_C + 1) * 4);
  size_t o_temp  = alloc((size_t)NB_BUCK * CAPB * 4);
  size_t o_csr   = alloc((size_t)E_TOT * 4);
  size_t o_hb    = alloc((size_t)N_NODES_C * 128 * 2);
  size_t o_es    = alloc((size_t)N_NODES_C * 4);
  size_t o_ed    = alloc((size_t)N_NODES_C * 4);
  size_t o_agg1  = alloc((size_t)N_NODES_C * 32 * 4);
  size_t o_agg2  = alloc((size_t)N_NODES_C * 64 * 4);
  size_t o_agg3  = alloc((size_t)N_NODES_C * 128 * 4);

  hipMemsetAsync(ws, 0, zero_end, stream);

  int* gcnt    = (int*)(ws + o_gcnt);
  int* gdeg    = (int*)(ws + o_gdeg);
  int* gbase   = (int*)(ws + o_gbase);
  int* gptr    = (int*)(ws + o_gptr);
  int* rowptr  = (int*)(ws + o_rowp);
  unsigned* temp = (unsigned*)(ws + o_temp);
  int* csr     = (int*)(ws + o_csr);
  __hip_bfloat16* hb = (__hip_bfloat16*)(ws + o_hb);
  const char* hbc = (const char*)(ws + o_hb);
  float* es    = (float*)(ws + o_es);
  float* ed    = (float*)(ws + o_ed);
  float* agg1  = (float*)(ws + o_agg1);
  float* agg2  = (float*)(ws + o_agg2);
  float* agg3  = (float*)(ws + o_agg3);
  double* sum1 = (double*)(ws + o_sum1);
  double* sum2 = (double*)(ws + o_sum2);
  double* sum3 = (double*)(ws + o_sum3);

  const int GB = (N_NODES_C + TILE_M - 1) / TILE_M;  // 391

  // CSR + graph ranges (bucketed counting sort)
  bucket_scatter<<<(E_TOT + EPB - 1) / EPB, 256, 0, stream>>>(ei, batch, temp, gcnt, gdeg);
  tiny_scan<<<1, 1024, 0, stream>>>(gcnt, gbase, gdeg, gptr, rowptr);
  bucket_build<<<NB_BUCK, 256, 0, stream>>>(temp, gcnt, gbase, rowptr, csr);

  // layer 1  (KC=32, 4 chunks)
  gemm_tiled<128, 32, 8, 32, false><<<GB, 256, 0, stream>>>(
      x, W1, as1, ad1, nullptr, nullptr, nullptr, hb, es, ed);
  gat_aggregate<32><<<N_NODES_C / 4, 256, 0, stream>>>(rowptr, csr, es, ed, hbc, agg1);
  bn_stats<32><<<(N_NODES_C + 127) / 128, 256, 0, stream>>>(agg1, sum1, N_NODES_C);

  // layer 2  (KC=32, 1 chunk)
  gemm_tiled<32, 64, 16, 32, true><<<GB, 256, 0, stream>>>(
      agg1, W2, as2, ad2, sum1, g1, be1, hb, es, ed);
  gat_aggregate<64><<<N_NODES_C / 4, 256, 0, stream>>>(rowptr, csr, es, ed, hbc, agg2);
  bn_stats<64><<<(N_NODES_C + 127) / 128, 256, 0, stream>>>(agg2, sum2, N_NODES_C);

  // layer 3  (KC=16, 4 chunks; keeps sW + 2*sxT under 64KB)
  gemm_tiled<64, 128, 16, 16, true><<<GB, 256, 0, stream>>>(
      agg2, W3, as3, ad3, sum2, g2, be2, hb, es, ed);
  gat_aggregate<128><<<N_NODES_C / 4, 256, 0, stream>>>(rowptr, csr, es, ed, hbc, agg3);
  bn_stats<128><<<(N_NODES_C + 127) / 128, 256, 0, stream>>>(agg3, sum3, N_NODES_C);

  // pool (bn3+lrelu fused) + fc1/fc2/fc3
  poolfc_kernel<<<NUM_GRAPHS_C, 128, 0, stream>>>(agg3, gptr, sum3, g3, be3,
                                                  fc1w, fc1b, fc2w, fc2b, fc3w, fc3b, out);
}